// Round 1
// baseline (1813.878 us; speedup 1.0000x reference)
//
#include <hip/hip_runtime.h>
#include <cstddef>

#define D_MODEL 1024
#define M_ROWS  4096
#define BN_EPS  1e-3f

// ---------------------------------------------------------------------------
// GEMM: C[M,N] = (relu(A @ W + bias)) or (A @ W)
// A row-major MxK, W row-major KxN. 128x128 tile, 256 threads, 8x8 microtile.
// ---------------------------------------------------------------------------
template<bool BIAS_RELU>
__global__ __launch_bounds__(256)
void gemm_kernel(const float* __restrict__ A, const float* __restrict__ W,
                 const float* __restrict__ bias, float* __restrict__ C,
                 int M, int N, int Kd) {
    __shared__ float As[16][132];   // transposed A tile: As[k][row]
    __shared__ float Bs[16][132];   // Bs[k][col]
    const int tid = threadIdx.x;
    const int tx = tid & 15, ty = tid >> 4;
    const int rowBase = blockIdx.y * 128;
    const int colBase = blockIdx.x * 128;
    float acc[8][8] = {};
    for (int k0 = 0; k0 < Kd; k0 += 16) {
        #pragma unroll
        for (int it = 0; it < 2; ++it) {
            int idx = tid + it * 256;          // 0..511
            int r = idx >> 2, c4 = (idx & 3) << 2;
            const float4 v = *reinterpret_cast<const float4*>(
                &A[(size_t)(rowBase + r) * Kd + k0 + c4]);
            As[c4 + 0][r] = v.x; As[c4 + 1][r] = v.y;
            As[c4 + 2][r] = v.z; As[c4 + 3][r] = v.w;
        }
        #pragma unroll
        for (int it = 0; it < 2; ++it) {
            int idx = tid + it * 256;          // 0..511
            int r = idx >> 5, c4 = (idx & 31) << 2;
            const float4 v = *reinterpret_cast<const float4*>(
                &W[(size_t)(k0 + r) * N + colBase + c4]);
            *reinterpret_cast<float4*>(&Bs[r][c4]) = v;
        }
        __syncthreads();
        #pragma unroll
        for (int k = 0; k < 16; ++k) {
            const float4 a0 = *reinterpret_cast<const float4*>(&As[k][ty * 8]);
            const float4 a1 = *reinterpret_cast<const float4*>(&As[k][ty * 8 + 4]);
            const float4 b0 = *reinterpret_cast<const float4*>(&Bs[k][tx * 8]);
            const float4 b1 = *reinterpret_cast<const float4*>(&Bs[k][tx * 8 + 4]);
            const float a[8] = {a0.x, a0.y, a0.z, a0.w, a1.x, a1.y, a1.z, a1.w};
            const float b[8] = {b0.x, b0.y, b0.z, b0.w, b1.x, b1.y, b1.z, b1.w};
            #pragma unroll
            for (int i = 0; i < 8; ++i)
                #pragma unroll
                for (int j = 0; j < 8; ++j)
                    acc[i][j] = fmaf(a[i], b[j], acc[i][j]);
        }
        __syncthreads();
    }
    #pragma unroll
    for (int i = 0; i < 8; ++i) {
        const int row = rowBase + ty * 8 + i;
        float o[8];
        #pragma unroll
        for (int j = 0; j < 8; ++j) {
            float v = acc[i][j];
            if (BIAS_RELU) { v += bias[colBase + tx * 8 + j]; v = fmaxf(v, 0.0f); }
            o[j] = v;
        }
        *reinterpret_cast<float4*>(&C[(size_t)row * N + colBase + tx * 8]) =
            make_float4(o[0], o[1], o[2], o[3]);
        *reinterpret_cast<float4*>(&C[(size_t)row * N + colBase + tx * 8 + 4]) =
            make_float4(o[4], o[5], o[6], o[7]);
    }
}

// ---------------------------------------------------------------------------
// Flash attention: per (qtile, head, batch). 64x64 tiles, online softmax.
// Q/K/V are (B*L, 1024) with head h in cols [h*64, h*64+64). Og may alias Qg:
// the workgroup reads only its own Q tile (into LDS, barrier) before writing.
// ---------------------------------------------------------------------------
__global__ __launch_bounds__(256)
void attn_kernel(const float* __restrict__ Qg, const float* __restrict__ Kg,
                 const float* __restrict__ Vg, float* __restrict__ Og) {
    __shared__ float Qs[64][65];
    __shared__ float KVs[64][65];
    __shared__ float Ss[64][66];
    __shared__ float m_s[64], l_s[64], al_s[64];
    const int tid = threadIdx.x;
    const int tx = tid & 15, ty = tid >> 4;
    const int qt = blockIdx.x, hh = blockIdx.y, bb = blockIdx.z;
    const int rowBase = bb * 512 + qt * 64;
    const int colBase = hh * 64;

    for (int i = tid; i < 64 * 16; i += 256) {
        int r = i >> 4, c4 = (i & 15) << 2;
        const float4 v = *reinterpret_cast<const float4*>(
            &Qg[(size_t)(rowBase + r) * D_MODEL + colBase + c4]);
        Qs[r][c4] = v.x; Qs[r][c4 + 1] = v.y; Qs[r][c4 + 2] = v.z; Qs[r][c4 + 3] = v.w;
    }
    if (tid < 64) { m_s[tid] = -1e30f; l_s[tid] = 0.0f; }
    float o[4][4] = {};

    for (int kt = 0; kt < 8; ++kt) {
        const int kBase = bb * 512 + kt * 64;
        __syncthreads();   // prev iter done with KVs (and first-iter Qs/m/l init)
        for (int i = tid; i < 64 * 16; i += 256) {
            int r = i >> 4, c4 = (i & 15) << 2;
            const float4 v = *reinterpret_cast<const float4*>(
                &Kg[(size_t)(kBase + r) * D_MODEL + colBase + c4]);
            KVs[r][c4] = v.x; KVs[r][c4 + 1] = v.y; KVs[r][c4 + 2] = v.z; KVs[r][c4 + 3] = v.w;
        }
        __syncthreads();
        float s[4][4] = {};
        #pragma unroll 8
        for (int d = 0; d < 64; ++d) {
            float a[4], b[4];
            #pragma unroll
            for (int i = 0; i < 4; ++i) a[i] = Qs[ty * 4 + i][d];
            #pragma unroll
            for (int j = 0; j < 4; ++j) b[j] = KVs[tx * 4 + j][d];
            #pragma unroll
            for (int i = 0; i < 4; ++i)
                #pragma unroll
                for (int j = 0; j < 4; ++j)
                    s[i][j] = fmaf(a[i], b[j], s[i][j]);
        }
        #pragma unroll
        for (int i = 0; i < 4; ++i)
            #pragma unroll
            for (int j = 0; j < 4; ++j)
                Ss[ty * 4 + i][tx * 4 + j] = s[i][j] * 0.125f;
        __syncthreads();   // Ss complete; all K reads of KVs done
        // load V (all threads) while 64 threads do the row softmax on Ss
        for (int i = tid; i < 64 * 16; i += 256) {
            int r = i >> 4, c4 = (i & 15) << 2;
            const float4 v = *reinterpret_cast<const float4*>(
                &Vg[(size_t)(kBase + r) * D_MODEL + colBase + c4]);
            KVs[r][c4] = v.x; KVs[r][c4 + 1] = v.y; KVs[r][c4 + 2] = v.z; KVs[r][c4 + 3] = v.w;
        }
        if (tid < 64) {
            const float m_old = m_s[tid];
            float mx = m_old;
            for (int j = 0; j < 64; ++j) mx = fmaxf(mx, Ss[tid][j]);
            float sum = 0.0f;
            for (int j = 0; j < 64; ++j) {
                const float p = __expf(Ss[tid][j] - mx);
                Ss[tid][j] = p; sum += p;
            }
            const float al = __expf(m_old - mx);
            l_s[tid] = l_s[tid] * al + sum;
            m_s[tid] = mx;
            al_s[tid] = al;
        }
        __syncthreads();   // V + softmax visible
        float alv[4];
        #pragma unroll
        for (int i = 0; i < 4; ++i) {
            alv[i] = al_s[ty * 4 + i];
            #pragma unroll
            for (int j = 0; j < 4; ++j) o[i][j] *= alv[i];
        }
        #pragma unroll 8
        for (int k2 = 0; k2 < 64; ++k2) {
            float a[4], b[4];
            #pragma unroll
            for (int i = 0; i < 4; ++i) a[i] = Ss[ty * 4 + i][k2];
            #pragma unroll
            for (int j = 0; j < 4; ++j) b[j] = KVs[k2][tx * 4 + j];
            #pragma unroll
            for (int i = 0; i < 4; ++i)
                #pragma unroll
                for (int j = 0; j < 4; ++j)
                    o[i][j] = fmaf(a[i], b[j], o[i][j]);
        }
    }
    #pragma unroll
    for (int i = 0; i < 4; ++i) {
        const float inv = 1.0f / l_s[ty * 4 + i];
        *reinterpret_cast<float4*>(
            &Og[(size_t)(rowBase + ty * 4 + i) * D_MODEL + colBase + tx * 4]) =
            make_float4(o[i][0] * inv, o[i][1] * inv, o[i][2] * inv, o[i][3] * inv);
    }
}

// ---------------------------------------------------------------------------
// BatchNorm (training stats over 4096 rows, per channel of 1024)
// ---------------------------------------------------------------------------
__global__ __launch_bounds__(256)
void bn_stats_partial_kernel(const float* __restrict__ A, const float* __restrict__ R,
                             float* __restrict__ part) {
    // grid (16, 32), block (64, 4): 64 channels x 128 rows per block
    const int tx = threadIdx.x, ty = threadIdx.y;
    const int c = blockIdx.x * 64 + tx;
    const int r0 = blockIdx.y * 128;
    float sum = 0.0f, sq = 0.0f;
    for (int r = r0 + ty; r < r0 + 128; r += 4) {
        float v = A[(size_t)r * D_MODEL + c];
        if (R) v += R[(size_t)r * D_MODEL + c];
        sum += v; sq += v * v;
    }
    __shared__ float sh[2][4][64];
    sh[0][ty][tx] = sum; sh[1][ty][tx] = sq;
    __syncthreads();
    if (ty == 0) {
        sum = sh[0][0][tx] + sh[0][1][tx] + sh[0][2][tx] + sh[0][3][tx];
        sq  = sh[1][0][tx] + sh[1][1][tx] + sh[1][2][tx] + sh[1][3][tx];
        part[blockIdx.y * 2048 + c] = sum;
        part[blockIdx.y * 2048 + 1024 + c] = sq;
    }
}

__global__ __launch_bounds__(256)
void bn_stats_final_kernel(const float* __restrict__ part, float* __restrict__ stats) {
    const int c = blockIdx.x * 256 + threadIdx.x;   // grid 4 -> 1024 channels
    float sum = 0.0f, sq = 0.0f;
    for (int g = 0; g < 32; ++g) {
        sum += part[g * 2048 + c];
        sq  += part[g * 2048 + 1024 + c];
    }
    const float mean = sum * (1.0f / 4096.0f);
    stats[c] = mean;
    stats[D_MODEL + c] = sq * (1.0f / 4096.0f) - mean * mean;
}

__global__ __launch_bounds__(256)
void bn_apply_kernel(const float* __restrict__ A, const float* __restrict__ R,
                     const float* __restrict__ stats, const float* __restrict__ gamma,
                     const float* __restrict__ beta, float* __restrict__ out) {
    const int idx = blockIdx.x * 256 + threadIdx.x;   // over 1048576 float4s
    const int c = (idx & 255) << 2;
    float4 v = reinterpret_cast<const float4*>(A)[idx];
    if (R) {
        const float4 rv = reinterpret_cast<const float4*>(R)[idx];
        v.x += rv.x; v.y += rv.y; v.z += rv.z; v.w += rv.w;
    }
    const float4 mn = *reinterpret_cast<const float4*>(&stats[c]);
    const float4 vr = *reinterpret_cast<const float4*>(&stats[D_MODEL + c]);
    const float4 g  = *reinterpret_cast<const float4*>(&gamma[c]);
    const float4 bt = *reinterpret_cast<const float4*>(&beta[c]);
    float4 r;
    r.x = g.x * (v.x - mn.x) * rsqrtf(vr.x + BN_EPS) + bt.x;
    r.y = g.y * (v.y - mn.y) * rsqrtf(vr.y + BN_EPS) + bt.y;
    r.z = g.z * (v.z - mn.z) * rsqrtf(vr.z + BN_EPS) + bt.z;
    r.w = g.w * (v.w - mn.w) * rsqrtf(vr.w + BN_EPS) + bt.w;
    reinterpret_cast<float4*>(out)[idx] = r;
}

// ---------------------------------------------------------------------------
static void run_bn(const float* A, const float* R, const float* gamma,
                   const float* beta, float* out, float* part, float* stats,
                   hipStream_t stream) {
    bn_stats_partial_kernel<<<dim3(16, 32), dim3(64, 4), 0, stream>>>(A, R, part);
    bn_stats_final_kernel<<<4, 256, 0, stream>>>(part, stats);
    bn_apply_kernel<<<4096, 256, 0, stream>>>(A, R, stats, gamma, beta, out);
}

extern "C" void kernel_launch(void* const* d_in, const int* in_sizes, int n_in,
                              void* d_out, int out_size, void* d_ws, size_t ws_size,
                              hipStream_t stream) {
    const float* x       = (const float*)d_in[0];
    const float* W_embed = (const float*)d_in[1];
    const float* bn1_g   = (const float*)d_in[2];
    const float* bn1_b   = (const float*)d_in[3];
    const float* Wq      = (const float*)d_in[4];
    const float* bq      = (const float*)d_in[5];
    const float* Wk      = (const float*)d_in[6];
    const float* bk      = (const float*)d_in[7];
    const float* Wv      = (const float*)d_in[8];
    const float* bv      = (const float*)d_in[9];
    const float* bng     = (const float*)d_in[10];
    const float* bnb     = (const float*)d_in[11];
    const float* Wc1     = (const float*)d_in[12];
    const float* bc1     = (const float*)d_in[13];
    const float* bn2g    = (const float*)d_in[14];
    const float* bn2b    = (const float*)d_in[15];
    float* out = (float*)d_out;

    const size_t NBUF = (size_t)M_ROWS * D_MODEL;   // 4194304 floats
    float* ws = (float*)d_ws;
    float* E = ws;
    float* Q = E + NBUF;
    float* K = Q + NBUF;
    float* V = K + NBUF;
    float* part  = V + NBUF;        // 32 * 2048 floats
    float* stats = part + 32 * 2048; // 2048 floats

    const dim3 gemmGrid(D_MODEL / 128, M_ROWS / 128);   // (8, 32)

    // embedding GEMM (K=64) + BN1
    gemm_kernel<false><<<gemmGrid, 256, 0, stream>>>(x, W_embed, nullptr, E,
                                                     M_ROWS, D_MODEL, 64);
    run_bn(E, nullptr, bn1_g, bn1_b, E, part, stats, stream);

    for (int i = 0; i < 2; ++i) {
        const size_t wo = (size_t)i * D_MODEL * D_MODEL;
        const size_t bo = (size_t)i * D_MODEL;
        gemm_kernel<true><<<gemmGrid, 256, 0, stream>>>(E, Wq + wo, bq + bo, Q,
                                                        M_ROWS, D_MODEL, D_MODEL);
        gemm_kernel<true><<<gemmGrid, 256, 0, stream>>>(E, Wk + wo, bk + bo, K,
                                                        M_ROWS, D_MODEL, D_MODEL);
        gemm_kernel<true><<<gemmGrid, 256, 0, stream>>>(E, Wv + wo, bv + bo, V,
                                                        M_ROWS, D_MODEL, D_MODEL);
        // attention out aliases Q (safe: each block copies its Q tile to LDS first)
        attn_kernel<<<dim3(8, 16, 8), 256, 0, stream>>>(Q, K, V, Q);
        run_bn(Q, E, bng + bo, bnb + bo, E, part, stats, stream);
        // FFN: conv1 applied twice with the same weights (faithful to reference)
        gemm_kernel<true><<<gemmGrid, 256, 0, stream>>>(E, Wc1 + wo, bc1 + bo, K,
                                                        M_ROWS, D_MODEL, D_MODEL);
        gemm_kernel<true><<<gemmGrid, 256, 0, stream>>>(K, Wc1 + wo, bc1 + bo, V,
                                                        M_ROWS, D_MODEL, D_MODEL);
        run_bn(V, E, bn2g + bo, bn2b + bo, (i == 1) ? out : E, part, stats, stream);
    }
}

// Round 2
// 716.483 us; speedup vs baseline: 2.5316x; 2.5316x over previous
//
#include <hip/hip_runtime.h>
#include <hip/hip_bf16.h>
#include <cstddef>

#define D_MODEL 1024
#define M_ROWS  4096
#define BN_EPS  1e-3f

typedef __attribute__((ext_vector_type(8))) short short8;
typedef __attribute__((ext_vector_type(8))) unsigned short ushortx8;
typedef __attribute__((ext_vector_type(4))) float f32x4;

__device__ __forceinline__ unsigned short f2bf(float f) {
    __hip_bfloat16 h = __float2bfloat16(f);
    return *reinterpret_cast<unsigned short*>(&h);
}
__device__ __forceinline__ float bf2f(unsigned short u) {
    return __uint_as_float(((unsigned)u) << 16);
}

// ---------------------------------------------------------------------------
// fp32 GEMM (embed only): C = A @ W.  A MxK, W KxN row-major.
// ---------------------------------------------------------------------------
template<bool BIAS_RELU>
__global__ __launch_bounds__(256)
void gemm_kernel(const float* __restrict__ A, const float* __restrict__ W,
                 const float* __restrict__ bias, float* __restrict__ C,
                 int M, int N, int Kd) {
    __shared__ float As[16][132];
    __shared__ float Bs[16][132];
    const int tid = threadIdx.x;
    const int tx = tid & 15, ty = tid >> 4;
    const int rowBase = blockIdx.y * 128;
    const int colBase = blockIdx.x * 128;
    float acc[8][8] = {};
    for (int k0 = 0; k0 < Kd; k0 += 16) {
        #pragma unroll
        for (int it = 0; it < 2; ++it) {
            int idx = tid + it * 256;
            int r = idx >> 2, c4 = (idx & 3) << 2;
            const float4 v = *reinterpret_cast<const float4*>(
                &A[(size_t)(rowBase + r) * Kd + k0 + c4]);
            As[c4 + 0][r] = v.x; As[c4 + 1][r] = v.y;
            As[c4 + 2][r] = v.z; As[c4 + 3][r] = v.w;
        }
        #pragma unroll
        for (int it = 0; it < 2; ++it) {
            int idx = tid + it * 256;
            int r = idx >> 5, c4 = (idx & 31) << 2;
            const float4 v = *reinterpret_cast<const float4*>(
                &W[(size_t)(k0 + r) * N + colBase + c4]);
            *reinterpret_cast<float4*>(&Bs[r][c4]) = v;
        }
        __syncthreads();
        #pragma unroll
        for (int k = 0; k < 16; ++k) {
            const float4 a0 = *reinterpret_cast<const float4*>(&As[k][ty * 8]);
            const float4 a1 = *reinterpret_cast<const float4*>(&As[k][ty * 8 + 4]);
            const float4 b0 = *reinterpret_cast<const float4*>(&Bs[k][tx * 8]);
            const float4 b1 = *reinterpret_cast<const float4*>(&Bs[k][tx * 8 + 4]);
            const float a[8] = {a0.x, a0.y, a0.z, a0.w, a1.x, a1.y, a1.z, a1.w};
            const float b[8] = {b0.x, b0.y, b0.z, b0.w, b1.x, b1.y, b1.z, b1.w};
            #pragma unroll
            for (int i = 0; i < 8; ++i)
                #pragma unroll
                for (int j = 0; j < 8; ++j)
                    acc[i][j] = fmaf(a[i], b[j], acc[i][j]);
        }
        __syncthreads();
    }
    #pragma unroll
    for (int i = 0; i < 8; ++i) {
        const int row = rowBase + ty * 8 + i;
        float o[8];
        #pragma unroll
        for (int j = 0; j < 8; ++j) {
            float v = acc[i][j];
            if (BIAS_RELU) { v += bias[colBase + tx * 8 + j]; v = fmaxf(v, 0.0f); }
            o[j] = v;
        }
        *reinterpret_cast<float4*>(&C[(size_t)row * N + colBase + tx * 8]) =
            make_float4(o[0], o[1], o[2], o[3]);
        *reinterpret_cast<float4*>(&C[(size_t)row * N + colBase + tx * 8 + 4]) =
            make_float4(o[4], o[5], o[6], o[7]);
    }
}

// ---------------------------------------------------------------------------
// bf16 MFMA GEMM: C[4096,N] = relu(A @ Bt^T + bias)
// A row-major [4096][Kd] bf16; Bt row-major [N][Kd] bf16 (i.e. W^T).
// 128x128 tile, BK=32, 4 waves (2x2), wave tile 64x64 (4x4 frags 16x16).
// LDS staged via global_load_lds width 16; chunk-XOR swizzle c^=(row>>1)&3.
// ---------------------------------------------------------------------------
template<bool OUT_BF16>
__global__ __launch_bounds__(256)
void gemm_bf16_kernel(const unsigned short* __restrict__ A,
                      const unsigned short* __restrict__ Bt,
                      const float* __restrict__ bias,
                      void* __restrict__ Cout, int N, int Kd) {
    __shared__ unsigned short As[2][128 * 32];
    __shared__ unsigned short Bs[2][128 * 32];
    const int tid = threadIdx.x;
    const int lane = tid & 63;
    const int w = tid >> 6;
    const int wr = w >> 1, wc = w & 1;
    const int rowBase = blockIdx.y * 128;
    const int colBase = blockIdx.x * 128;

    // staging addresses (per-lane global, wave-uniform LDS base)
    const int chunk0 = w * 64 + lane;            // 0..255
    const int r0 = chunk0 >> 2;
    const int c0 = (chunk0 & 3) ^ ((r0 >> 1) & 3);
    const int chunk1 = 256 + chunk0;             // 256..511
    const int r1 = chunk1 >> 2;
    const int c1 = (chunk1 & 3) ^ ((r1 >> 1) & 3);
    const size_t aOff0 = (size_t)(rowBase + r0) * Kd + c0 * 8;
    const size_t aOff1 = (size_t)(rowBase + r1) * Kd + c1 * 8;
    const size_t bOff0 = (size_t)(colBase + r0) * Kd + c0 * 8;
    const size_t bOff1 = (size_t)(colBase + r1) * Kd + c1 * 8;
    const int ldsOff0 = (w * 64) * 8;            // ushort index
    const int ldsOff1 = (256 + w * 64) * 8;

    f32x4 acc[4][4];
    #pragma unroll
    for (int m = 0; m < 4; ++m)
        #pragma unroll
        for (int n = 0; n < 4; ++n)
            acc[m][n] = (f32x4){0.f, 0.f, 0.f, 0.f};

    #define STAGE(buf, kt) do {                                                   \
        const int k0_ = (kt) << 5;                                                \
        __builtin_amdgcn_global_load_lds(                                         \
            (const __attribute__((address_space(1))) void*)(A + aOff0 + k0_),     \
            (__attribute__((address_space(3))) void*)(&As[buf][ldsOff0]), 16, 0, 0);\
        __builtin_amdgcn_global_load_lds(                                         \
            (const __attribute__((address_space(1))) void*)(A + aOff1 + k0_),     \
            (__attribute__((address_space(3))) void*)(&As[buf][ldsOff1]), 16, 0, 0);\
        __builtin_amdgcn_global_load_lds(                                         \
            (const __attribute__((address_space(1))) void*)(Bt + bOff0 + k0_),    \
            (__attribute__((address_space(3))) void*)(&Bs[buf][ldsOff0]), 16, 0, 0);\
        __builtin_amdgcn_global_load_lds(                                         \
            (const __attribute__((address_space(1))) void*)(Bt + bOff1 + k0_),    \
            (__attribute__((address_space(3))) void*)(&Bs[buf][ldsOff1]), 16, 0, 0);\
    } while (0)

    const int NT = Kd >> 5;
    STAGE(0, 0);

    const int kb = lane >> 4;                    // k-block 0..3
    const int s = kb ^ ((lane >> 1) & 3);        // swizzled chunk (row-bit XOR folds to lane)
    const int rA = wr * 64 + (lane & 15);
    const int rB = wc * 64 + (lane & 15);

    for (int t = 0; t < NT; ++t) {
        __syncthreads();                          // staging of buf[t&1] complete
        if (t + 1 < NT) STAGE((t + 1) & 1, t + 1);
        const unsigned short* as = As[t & 1];
        const unsigned short* bs = Bs[t & 1];
        short8 a[4], b[4];
        #pragma unroll
        for (int m = 0; m < 4; ++m)
            a[m] = *(const short8*)&as[(rA + m * 16) * 32 + s * 8];
        #pragma unroll
        for (int n = 0; n < 4; ++n)
            b[n] = *(const short8*)&bs[(rB + n * 16) * 32 + s * 8];
        #pragma unroll
        for (int m = 0; m < 4; ++m)
            #pragma unroll
            for (int n = 0; n < 4; ++n)
                acc[m][n] = __builtin_amdgcn_mfma_f32_16x16x32_bf16(
                    a[m], b[n], acc[m][n], 0, 0, 0);
    }
    #undef STAGE

    // epilogue: C[row = (lane>>4)*4 + reg][col = lane&15] per fragment
    const int cRow0 = rowBase + wr * 64 + (lane >> 4) * 4;
    const int cCol0 = colBase + wc * 64 + (lane & 15);
    #pragma unroll
    for (int n = 0; n < 4; ++n) {
        const int col = cCol0 + n * 16;
        const float bv = bias[col];
        #pragma unroll
        for (int m = 0; m < 4; ++m)
            #pragma unroll
            for (int r = 0; r < 4; ++r) {
                const int row = cRow0 + m * 16 + r;
                const float v = fmaxf(acc[m][n][r] + bv, 0.0f);
                if (OUT_BF16)
                    ((unsigned short*)Cout)[(size_t)row * N + col] = f2bf(v);
                else
                    ((float*)Cout)[(size_t)row * N + col] = v;
            }
    }
}

// ---------------------------------------------------------------------------
// weight prep: dst[n][k] = bf16(src[k][n]); src/dst 1024x1024
// ---------------------------------------------------------------------------
__global__ __launch_bounds__(256)
void transpose_cvt_kernel(const float* __restrict__ src, unsigned short* __restrict__ dst) {
    __shared__ float T[64][65];
    const int tid = threadIdx.x;
    const int kBase = blockIdx.y * 64;
    const int nBase = blockIdx.x * 64;
    const int rr = tid >> 4;
    const int c4 = (tid & 15) * 4;
    #pragma unroll
    for (int i = 0; i < 4; ++i) {
        const int k = i * 16 + rr;
        const float4 v = *reinterpret_cast<const float4*>(
            &src[(size_t)(kBase + k) * 1024 + nBase + c4]);
        T[k][c4] = v.x; T[k][c4 + 1] = v.y; T[k][c4 + 2] = v.z; T[k][c4 + 3] = v.w;
    }
    __syncthreads();
    #pragma unroll
    for (int i = 0; i < 4; ++i) {
        const int n = i * 16 + rr;
        ushort4 o;
        o.x = f2bf(T[c4 + 0][n]); o.y = f2bf(T[c4 + 1][n]);
        o.z = f2bf(T[c4 + 2][n]); o.w = f2bf(T[c4 + 3][n]);
        *reinterpret_cast<ushort4*>(&dst[(size_t)(nBase + n) * 1024 + kBase + c4]) = o;
    }
}

__global__ __launch_bounds__(256)
void bias_concat_kernel(const float* __restrict__ bq, const float* __restrict__ bk,
                        const float* __restrict__ bv, float* __restrict__ bqkv) {
    const int j = blockIdx.x * 256 + threadIdx.x;   // 3072
    bqkv[j] = (j < 1024) ? bq[j] : (j < 2048) ? bk[j - 1024] : bv[j - 2048];
}

// ---------------------------------------------------------------------------
// Flash attention (fp32 compute, bf16 QKV input packed [4096][3072])
// ---------------------------------------------------------------------------
__global__ __launch_bounds__(256)
void attn_kernel(const unsigned short* __restrict__ QKV, float* __restrict__ Og) {
    __shared__ float Qs[64][65];
    __shared__ float KVs[64][65];
    __shared__ float Ss[64][66];
    __shared__ float m_s[64], l_s[64], al_s[64];
    const int tid = threadIdx.x;
    const int tx = tid & 15, ty = tid >> 4;
    const int qt = blockIdx.x, hh = blockIdx.y, bb = blockIdx.z;
    const int rowBase = bb * 512 + qt * 64;
    const int colBase = hh * 64;

    for (int i = tid; i < 512; i += 256) {
        int r = i >> 3, c8 = (i & 7) << 3;
        ushortx8 v = *(const ushortx8*)&QKV[(size_t)(rowBase + r) * 3072 + colBase + c8];
        #pragma unroll
        for (int j = 0; j < 8; ++j) Qs[r][c8 + j] = bf2f(v[j]);
    }
    if (tid < 64) { m_s[tid] = -1e30f; l_s[tid] = 0.0f; }
    float o[4][4] = {};

    for (int kt = 0; kt < 8; ++kt) {
        const int kBase = bb * 512 + kt * 64;
        __syncthreads();
        for (int i = tid; i < 512; i += 256) {
            int r = i >> 3, c8 = (i & 7) << 3;
            ushortx8 v = *(const ushortx8*)&QKV[(size_t)(kBase + r) * 3072 + 1024 + colBase + c8];
            #pragma unroll
            for (int j = 0; j < 8; ++j) KVs[r][c8 + j] = bf2f(v[j]);
        }
        __syncthreads();
        float s[4][4] = {};
        #pragma unroll 8
        for (int d = 0; d < 64; ++d) {
            float a[4], b[4];
            #pragma unroll
            for (int i = 0; i < 4; ++i) a[i] = Qs[ty * 4 + i][d];
            #pragma unroll
            for (int j = 0; j < 4; ++j) b[j] = KVs[tx * 4 + j][d];
            #pragma unroll
            for (int i = 0; i < 4; ++i)
                #pragma unroll
                for (int j = 0; j < 4; ++j)
                    s[i][j] = fmaf(a[i], b[j], s[i][j]);
        }
        #pragma unroll
        for (int i = 0; i < 4; ++i)
            #pragma unroll
            for (int j = 0; j < 4; ++j)
                Ss[ty * 4 + i][tx * 4 + j] = s[i][j] * 0.125f;
        __syncthreads();
        for (int i = tid; i < 512; i += 256) {
            int r = i >> 3, c8 = (i & 7) << 3;
            ushortx8 v = *(const ushortx8*)&QKV[(size_t)(kBase + r) * 3072 + 2048 + colBase + c8];
            #pragma unroll
            for (int j = 0; j < 8; ++j) KVs[r][c8 + j] = bf2f(v[j]);
        }
        if (tid < 64) {
            const float m_old = m_s[tid];
            float mx = m_old;
            for (int j = 0; j < 64; ++j) mx = fmaxf(mx, Ss[tid][j]);
            float sum = 0.0f;
            for (int j = 0; j < 64; ++j) {
                const float p = __expf(Ss[tid][j] - mx);
                Ss[tid][j] = p; sum += p;
            }
            const float al = __expf(m_old - mx);
            l_s[tid] = l_s[tid] * al + sum;
            m_s[tid] = mx;
            al_s[tid] = al;
        }
        __syncthreads();
        #pragma unroll
        for (int i = 0; i < 4; ++i) {
            const float al = al_s[ty * 4 + i];
            #pragma unroll
            for (int j = 0; j < 4; ++j) o[i][j] *= al;
        }
        #pragma unroll 8
        for (int k2 = 0; k2 < 64; ++k2) {
            float a[4], b[4];
            #pragma unroll
            for (int i = 0; i < 4; ++i) a[i] = Ss[ty * 4 + i][k2];
            #pragma unroll
            for (int j = 0; j < 4; ++j) b[j] = KVs[k2][tx * 4 + j];
            #pragma unroll
            for (int i = 0; i < 4; ++i)
                #pragma unroll
                for (int j = 0; j < 4; ++j)
                    o[i][j] = fmaf(a[i], b[j], o[i][j]);
        }
    }
    #pragma unroll
    for (int i = 0; i < 4; ++i) {
        const float inv = 1.0f / l_s[ty * 4 + i];
        *reinterpret_cast<float4*>(
            &Og[(size_t)(rowBase + ty * 4 + i) * D_MODEL + colBase + tx * 4]) =
            make_float4(o[i][0] * inv, o[i][1] * inv, o[i][2] * inv, o[i][3] * inv);
    }
}

// ---------------------------------------------------------------------------
// BatchNorm (training stats over 4096 rows, per channel of 1024)
// ---------------------------------------------------------------------------
__global__ __launch_bounds__(256)
void bn_stats_partial_kernel(const float* __restrict__ A, const float* __restrict__ R,
                             float* __restrict__ part) {
    const int tx = threadIdx.x, ty = threadIdx.y;
    const int c = blockIdx.x * 64 + tx;
    const int r0 = blockIdx.y * 128;
    float sum = 0.0f, sq = 0.0f;
    for (int r = r0 + ty; r < r0 + 128; r += 4) {
        float v = A[(size_t)r * D_MODEL + c];
        if (R) v += R[(size_t)r * D_MODEL + c];
        sum += v; sq += v * v;
    }
    __shared__ float sh[2][4][64];
    sh[0][ty][tx] = sum; sh[1][ty][tx] = sq;
    __syncthreads();
    if (ty == 0) {
        sum = sh[0][0][tx] + sh[0][1][tx] + sh[0][2][tx] + sh[0][3][tx];
        sq  = sh[1][0][tx] + sh[1][1][tx] + sh[1][2][tx] + sh[1][3][tx];
        part[blockIdx.y * 2048 + c] = sum;
        part[blockIdx.y * 2048 + 1024 + c] = sq;
    }
}

__global__ __launch_bounds__(256)
void bn_stats_final_kernel(const float* __restrict__ part, float* __restrict__ stats) {
    const int c = blockIdx.x * 256 + threadIdx.x;
    float sum = 0.0f, sq = 0.0f;
    for (int g = 0; g < 32; ++g) {
        sum += part[g * 2048 + c];
        sq  += part[g * 2048 + 1024 + c];
    }
    const float mean = sum * (1.0f / 4096.0f);
    stats[c] = mean;
    stats[D_MODEL + c] = sq * (1.0f / 4096.0f) - mean * mean;
}

__global__ __launch_bounds__(256)
void bn_apply_kernel(const float* __restrict__ A, const float* __restrict__ R,
                     const float* __restrict__ stats, const float* __restrict__ gamma,
                     const float* __restrict__ beta, float* __restrict__ out,
                     unsigned short* __restrict__ outbf) {
    const int idx = blockIdx.x * 256 + threadIdx.x;
    const int c = (idx & 255) << 2;
    float4 v = reinterpret_cast<const float4*>(A)[idx];
    if (R) {
        const float4 rv = reinterpret_cast<const float4*>(R)[idx];
        v.x += rv.x; v.y += rv.y; v.z += rv.z; v.w += rv.w;
    }
    const float4 mn = *reinterpret_cast<const float4*>(&stats[c]);
    const float4 vr = *reinterpret_cast<const float4*>(&stats[D_MODEL + c]);
    const float4 g  = *reinterpret_cast<const float4*>(&gamma[c]);
    const float4 bt = *reinterpret_cast<const float4*>(&beta[c]);
    float4 r;
    r.x = g.x * (v.x - mn.x) * rsqrtf(vr.x + BN_EPS) + bt.x;
    r.y = g.y * (v.y - mn.y) * rsqrtf(vr.y + BN_EPS) + bt.y;
    r.z = g.z * (v.z - mn.z) * rsqrtf(vr.z + BN_EPS) + bt.z;
    r.w = g.w * (v.w - mn.w) * rsqrtf(vr.w + BN_EPS) + bt.w;
    reinterpret_cast<float4*>(out)[idx] = r;
    if (outbf) {
        ushort4 o;
        o.x = f2bf(r.x); o.y = f2bf(r.y); o.z = f2bf(r.z); o.w = f2bf(r.w);
        reinterpret_cast<ushort4*>(outbf)[idx] = o;
    }
}

static void run_bn(const float* A, const float* R, const float* gamma,
                   const float* beta, float* out, unsigned short* outbf,
                   float* part, float* stats, hipStream_t stream) {
    bn_stats_partial_kernel<<<dim3(16, 32), dim3(64, 4), 0, stream>>>(A, R, part);
    bn_stats_final_kernel<<<4, 256, 0, stream>>>(part, stats);
    bn_apply_kernel<<<4096, 256, 0, stream>>>(A, R, stats, gamma, beta, out, outbf);
}

extern "C" void kernel_launch(void* const* d_in, const int* in_sizes, int n_in,
                              void* d_out, int out_size, void* d_ws, size_t ws_size,
                              hipStream_t stream) {
    const float* x       = (const float*)d_in[0];
    const float* W_embed = (const float*)d_in[1];
    const float* bn1_g   = (const float*)d_in[2];
    const float* bn1_b   = (const float*)d_in[3];
    const float* Wq      = (const float*)d_in[4];
    const float* bq      = (const float*)d_in[5];
    const float* Wk      = (const float*)d_in[6];
    const float* bk      = (const float*)d_in[7];
    const float* Wv      = (const float*)d_in[8];
    const float* bv      = (const float*)d_in[9];
    const float* bng     = (const float*)d_in[10];
    const float* bnb     = (const float*)d_in[11];
    const float* Wc1     = (const float*)d_in[12];
    const float* bc1     = (const float*)d_in[13];
    const float* bn2g    = (const float*)d_in[14];
    const float* bn2b    = (const float*)d_in[15];

    const size_t NBUF = (size_t)M_ROWS * D_MODEL;        // 4194304
    float* E = (float*)d_out;                            // master activation lives in d_out
    float* ws = (float*)d_ws;
    float* O     = ws;                                   // attn out / F2 (4194304 f)
    float* part  = O + NBUF;                             // 65536 f
    float* stats = part + 65536;                         // 2048 f
    float* bqkv  = stats + 2048;                         // 3072 f (per-layer)
    unsigned short* Ebf   = (unsigned short*)(bqkv + 3072);  // 4194304 us
    unsigned short* QKVbf = Ebf + NBUF;                  // 12582912 us
    unsigned short* F1bf  = QKVbf;                       // alias (QKV dead after attn)
    unsigned short* Wtqkv = QKVbf + (size_t)M_ROWS * 3072;   // 3145728 us
    unsigned short* Wtc1  = Wtqkv + (size_t)3072 * 1024;     // 1048576 us

    const dim3 tgrid(16, 16);
    const dim3 qkvGrid(24, 32);     // N=3072
    const dim3 ffnGrid(8, 32);      // N=1024

    // embedding GEMM (fp32, K=64) + BN1 (writes fp32 master + bf16 shadow)
    gemm_kernel<false><<<dim3(8, 32), 256, 0, stream>>>(x, W_embed, nullptr, E,
                                                        M_ROWS, D_MODEL, 64);
    run_bn(E, nullptr, bn1_g, bn1_b, E, Ebf, part, stats, stream);

    for (int i = 0; i < 2; ++i) {
        const size_t wo = (size_t)i * D_MODEL * D_MODEL;
        const size_t bo = (size_t)i * D_MODEL;
        // per-layer weight prep: W^T -> bf16
        transpose_cvt_kernel<<<tgrid, 256, 0, stream>>>(Wq + wo, Wtqkv);
        transpose_cvt_kernel<<<tgrid, 256, 0, stream>>>(Wk + wo, Wtqkv + (size_t)1024 * 1024);
        transpose_cvt_kernel<<<tgrid, 256, 0, stream>>>(Wv + wo, Wtqkv + (size_t)2048 * 1024);
        transpose_cvt_kernel<<<tgrid, 256, 0, stream>>>(Wc1 + wo, Wtc1);
        bias_concat_kernel<<<12, 256, 0, stream>>>(bq + bo, bk + bo, bv + bo, bqkv);

        // fused QKV projection (bf16 MFMA, relu, bf16 out)
        gemm_bf16_kernel<true><<<qkvGrid, 256, 0, stream>>>(Ebf, Wtqkv, bqkv,
                                                            QKVbf, 3072, 1024);
        attn_kernel<<<dim3(8, 16, 8), 256, 0, stream>>>(QKVbf, O);
        run_bn(O, E, bng + bo, bnb + bo, E, Ebf, part, stats, stream);

        // FFN: conv1 applied twice with the same weights (faithful to reference)
        gemm_bf16_kernel<true><<<ffnGrid, 256, 0, stream>>>(Ebf, Wtc1, bc1 + bo,
                                                            F1bf, 1024, 1024);
        gemm_bf16_kernel<false><<<ffnGrid, 256, 0, stream>>>(F1bf, Wtc1, bc1 + bo,
                                                             O, 1024, 1024);
        run_bn(O, E, bn2g + bo, bn2b + bo, E, (i == 0) ? Ebf : nullptr,
               part, stats, stream);
    }
}

// Round 3
// 383.464 us; speedup vs baseline: 4.7302x; 1.8684x over previous
//
#include <hip/hip_runtime.h>
#include <hip/hip_bf16.h>
#include <cstddef>

#define D_MODEL 1024
#define M_ROWS  4096
#define BN_EPS  1e-3f

typedef __attribute__((ext_vector_type(8))) short short8;
typedef __attribute__((ext_vector_type(4))) short short4v;
typedef __attribute__((ext_vector_type(8))) unsigned short ushortx8;
typedef __attribute__((ext_vector_type(4))) float f32x4;

__device__ __forceinline__ unsigned short f2bf(float f) {
    __hip_bfloat16 h = __float2bfloat16(f);
    return *reinterpret_cast<unsigned short*>(&h);
}
__device__ __forceinline__ float bf2f(unsigned short u) {
    return __uint_as_float(((unsigned)u) << 16);
}

// ---------------------------------------------------------------------------
// fp32 GEMM (embed only): C = A @ W.  A MxK, W KxN row-major.
// ---------------------------------------------------------------------------
template<bool BIAS_RELU>
__global__ __launch_bounds__(256)
void gemm_kernel(const float* __restrict__ A, const float* __restrict__ W,
                 const float* __restrict__ bias, float* __restrict__ C,
                 int M, int N, int Kd) {
    __shared__ float As[16][132];
    __shared__ float Bs[16][132];
    const int tid = threadIdx.x;
    const int tx = tid & 15, ty = tid >> 4;
    const int rowBase = blockIdx.y * 128;
    const int colBase = blockIdx.x * 128;
    float acc[8][8] = {};
    for (int k0 = 0; k0 < Kd; k0 += 16) {
        #pragma unroll
        for (int it = 0; it < 2; ++it) {
            int idx = tid + it * 256;
            int r = idx >> 2, c4 = (idx & 3) << 2;
            const float4 v = *reinterpret_cast<const float4*>(
                &A[(size_t)(rowBase + r) * Kd + k0 + c4]);
            As[c4 + 0][r] = v.x; As[c4 + 1][r] = v.y;
            As[c4 + 2][r] = v.z; As[c4 + 3][r] = v.w;
        }
        #pragma unroll
        for (int it = 0; it < 2; ++it) {
            int idx = tid + it * 256;
            int r = idx >> 5, c4 = (idx & 31) << 2;
            const float4 v = *reinterpret_cast<const float4*>(
                &W[(size_t)(k0 + r) * N + colBase + c4]);
            *reinterpret_cast<float4*>(&Bs[r][c4]) = v;
        }
        __syncthreads();
        #pragma unroll
        for (int k = 0; k < 16; ++k) {
            const float4 a0 = *reinterpret_cast<const float4*>(&As[k][ty * 8]);
            const float4 a1 = *reinterpret_cast<const float4*>(&As[k][ty * 8 + 4]);
            const float4 b0 = *reinterpret_cast<const float4*>(&Bs[k][tx * 8]);
            const float4 b1 = *reinterpret_cast<const float4*>(&Bs[k][tx * 8 + 4]);
            const float a[8] = {a0.x, a0.y, a0.z, a0.w, a1.x, a1.y, a1.z, a1.w};
            const float b[8] = {b0.x, b0.y, b0.z, b0.w, b1.x, b1.y, b1.z, b1.w};
            #pragma unroll
            for (int i = 0; i < 8; ++i)
                #pragma unroll
                for (int j = 0; j < 8; ++j)
                    acc[i][j] = fmaf(a[i], b[j], acc[i][j]);
        }
        __syncthreads();
    }
    #pragma unroll
    for (int i = 0; i < 8; ++i) {
        const int row = rowBase + ty * 8 + i;
        float o[8];
        #pragma unroll
        for (int j = 0; j < 8; ++j) {
            float v = acc[i][j];
            if (BIAS_RELU) { v += bias[colBase + tx * 8 + j]; v = fmaxf(v, 0.0f); }
            o[j] = v;
        }
        *reinterpret_cast<float4*>(&C[(size_t)row * N + colBase + tx * 8]) =
            make_float4(o[0], o[1], o[2], o[3]);
        *reinterpret_cast<float4*>(&C[(size_t)row * N + colBase + tx * 8 + 4]) =
            make_float4(o[4], o[5], o[6], o[7]);
    }
}

// ---------------------------------------------------------------------------
// bf16 MFMA GEMM: C[4096,N] = relu(A @ Bt^T + bias)
// ---------------------------------------------------------------------------
template<bool OUT_BF16>
__global__ __launch_bounds__(256)
void gemm_bf16_kernel(const unsigned short* __restrict__ A,
                      const unsigned short* __restrict__ Bt,
                      const float* __restrict__ bias,
                      void* __restrict__ Cout, int N, int Kd) {
    __shared__ unsigned short As[2][128 * 32];
    __shared__ unsigned short Bs[2][128 * 32];
    const int tid = threadIdx.x;
    const int lane = tid & 63;
    const int w = tid >> 6;
    const int wr = w >> 1, wc = w & 1;
    const int rowBase = blockIdx.y * 128;
    const int colBase = blockIdx.x * 128;

    const int chunk0 = w * 64 + lane;
    const int r0 = chunk0 >> 2;
    const int c0 = (chunk0 & 3) ^ ((r0 >> 1) & 3);
    const int chunk1 = 256 + chunk0;
    const int r1 = chunk1 >> 2;
    const int c1 = (chunk1 & 3) ^ ((r1 >> 1) & 3);
    const size_t aOff0 = (size_t)(rowBase + r0) * Kd + c0 * 8;
    const size_t aOff1 = (size_t)(rowBase + r1) * Kd + c1 * 8;
    const size_t bOff0 = (size_t)(colBase + r0) * Kd + c0 * 8;
    const size_t bOff1 = (size_t)(colBase + r1) * Kd + c1 * 8;
    const int ldsOff0 = (w * 64) * 8;
    const int ldsOff1 = (256 + w * 64) * 8;

    f32x4 acc[4][4];
    #pragma unroll
    for (int m = 0; m < 4; ++m)
        #pragma unroll
        for (int n = 0; n < 4; ++n)
            acc[m][n] = (f32x4){0.f, 0.f, 0.f, 0.f};

    #define STAGE(buf, kt) do {                                                   \
        const int k0_ = (kt) << 5;                                                \
        __builtin_amdgcn_global_load_lds(                                         \
            (const __attribute__((address_space(1))) void*)(A + aOff0 + k0_),     \
            (__attribute__((address_space(3))) void*)(&As[buf][ldsOff0]), 16, 0, 0);\
        __builtin_amdgcn_global_load_lds(                                         \
            (const __attribute__((address_space(1))) void*)(A + aOff1 + k0_),     \
            (__attribute__((address_space(3))) void*)(&As[buf][ldsOff1]), 16, 0, 0);\
        __builtin_amdgcn_global_load_lds(                                         \
            (const __attribute__((address_space(1))) void*)(Bt + bOff0 + k0_),    \
            (__attribute__((address_space(3))) void*)(&Bs[buf][ldsOff0]), 16, 0, 0);\
        __builtin_amdgcn_global_load_lds(                                         \
            (const __attribute__((address_space(1))) void*)(Bt + bOff1 + k0_),    \
            (__attribute__((address_space(3))) void*)(&Bs[buf][ldsOff1]), 16, 0, 0);\
    } while (0)

    const int NT = Kd >> 5;
    STAGE(0, 0);

    const int kb = lane >> 4;
    const int s = kb ^ ((lane >> 1) & 3);
    const int rA = wr * 64 + (lane & 15);
    const int rB = wc * 64 + (lane & 15);

    for (int t = 0; t < NT; ++t) {
        __syncthreads();
        if (t + 1 < NT) STAGE((t + 1) & 1, t + 1);
        const unsigned short* as = As[t & 1];
        const unsigned short* bs = Bs[t & 1];
        short8 a[4], b[4];
        #pragma unroll
        for (int m = 0; m < 4; ++m)
            a[m] = *(const short8*)&as[(rA + m * 16) * 32 + s * 8];
        #pragma unroll
        for (int n = 0; n < 4; ++n)
            b[n] = *(const short8*)&bs[(rB + n * 16) * 32 + s * 8];
        #pragma unroll
        for (int m = 0; m < 4; ++m)
            #pragma unroll
            for (int n = 0; n < 4; ++n)
                acc[m][n] = __builtin_amdgcn_mfma_f32_16x16x32_bf16(
                    a[m], b[n], acc[m][n], 0, 0, 0);
    }
    #undef STAGE

    const int cRow0 = rowBase + wr * 64 + (lane >> 4) * 4;
    const int cCol0 = colBase + wc * 64 + (lane & 15);
    #pragma unroll
    for (int n = 0; n < 4; ++n) {
        const int col = cCol0 + n * 16;
        const float bv = bias[col];
        #pragma unroll
        for (int m = 0; m < 4; ++m)
            #pragma unroll
            for (int r = 0; r < 4; ++r) {
                const int row = cRow0 + m * 16 + r;
                const float v = fmaxf(acc[m][n][r] + bv, 0.0f);
                if (OUT_BF16)
                    ((unsigned short*)Cout)[(size_t)row * N + col] = f2bf(v);
                else
                    ((float*)Cout)[(size_t)row * N + col] = v;
            }
    }
}

// ---------------------------------------------------------------------------
// weight prep
// ---------------------------------------------------------------------------
__global__ __launch_bounds__(256)
void transpose_cvt_kernel(const float* __restrict__ src, unsigned short* __restrict__ dst) {
    __shared__ float T[64][65];
    const int tid = threadIdx.x;
    const int kBase = blockIdx.y * 64;
    const int nBase = blockIdx.x * 64;
    const int rr = tid >> 4;
    const int c4 = (tid & 15) * 4;
    #pragma unroll
    for (int i = 0; i < 4; ++i) {
        const int k = i * 16 + rr;
        const float4 v = *reinterpret_cast<const float4*>(
            &src[(size_t)(kBase + k) * 1024 + nBase + c4]);
        T[k][c4] = v.x; T[k][c4 + 1] = v.y; T[k][c4 + 2] = v.z; T[k][c4 + 3] = v.w;
    }
    __syncthreads();
    #pragma unroll
    for (int i = 0; i < 4; ++i) {
        const int n = i * 16 + rr;
        ushort4 o;
        o.x = f2bf(T[c4 + 0][n]); o.y = f2bf(T[c4 + 1][n]);
        o.z = f2bf(T[c4 + 2][n]); o.w = f2bf(T[c4 + 3][n]);
        *reinterpret_cast<ushort4*>(&dst[(size_t)(nBase + n) * 1024 + kBase + c4]) = o;
    }
}

__global__ __launch_bounds__(256)
void bias_concat_kernel(const float* __restrict__ bq, const float* __restrict__ bk,
                        const float* __restrict__ bv, float* __restrict__ bqkv) {
    const int j = blockIdx.x * 256 + threadIdx.x;
    bqkv[j] = (j < 1024) ? bq[j] : (j < 2048) ? bk[j - 1024] : bv[j - 2048];
}

// ---------------------------------------------------------------------------
// MFMA flash attention. QKV packed [4096][3072] bf16. Output fp32 [4096][1024].
// Grid (qt=4, head=16, batch=8), 256 thr = 4 waves, each wave 32 q-rows.
// S^T = mfma(Kfrag, Qfrag): lane&15 = q-row; keys in regs across lane groups.
// PV uses permuted key order pi(8g+j)=4g+(j&3)+16(j>>2)+32ks so S^T registers
// repack lane-locally into the PV A-fragment; V read as matching b64 pairs.
// ---------------------------------------------------------------------------
__global__ __launch_bounds__(256)
void attn_kernel(const unsigned short* __restrict__ QKV, float* __restrict__ Og) {
    __shared__ unsigned short Qs[128 * 64];       // chunk-swizzled
    __shared__ unsigned short Ks[2][64 * 64];     // chunk-swizzled
    __shared__ unsigned short Vt[2][64 * 72];     // transposed [d][key], stride 72

    const int tid = threadIdx.x;
    const int lane = tid & 63;
    const int w = tid >> 6;
    const int m = lane & 15;
    const int g = lane >> 4;          // 0..3
    const int l7 = lane & 7;
    const int qt = blockIdx.x, hh = blockIdx.y, bb = blockIdx.z;
    const int colB = hh * 64;
    const size_t rowQ = (size_t)bb * 512 + qt * 128;   // q rows base
    const size_t rowKV = (size_t)bb * 512;             // key rows base

    // ---- V reg-staging addresses: thread covers keys (t&31)*2,(..)+1, chunk t>>5
    const int vk0 = (tid & 31) * 2;
    const int vcv = tid >> 5;          // 0..7

    // ---- staging helpers -------------------------------------------------
    #define STAGE_K(buf, kt) do {                                                  \
        const size_t kb_ = rowKV + (size_t)(kt) * 64;                              \
        _Pragma("unroll")                                                          \
        for (int i_ = 0; i_ < 2; ++i_) {                                           \
            const int c_ = w * 128 + i_ * 64 + lane;                               \
            const int r_ = c_ >> 3;                                                \
            const int gc_ = (c_ & 7) ^ (r_ & 7);                                   \
            __builtin_amdgcn_global_load_lds(                                      \
                (const __attribute__((address_space(1))) void*)                    \
                    (QKV + (kb_ + r_) * 3072 + 1024 + colB + gc_ * 8),             \
                (__attribute__((address_space(3))) void*)                          \
                    (&Ks[buf][(w * 128 + i_ * 64) * 8]), 16, 0, 0);                \
        }                                                                          \
    } while (0)

    #define LOAD_V(kt) do {                                                        \
        const size_t kb_ = rowKV + (size_t)(kt) * 64;                              \
        vst0 = *(const ushortx8*)(QKV + (kb_ + vk0) * 3072 + 2048 + colB + vcv * 8);\
        vst1 = *(const ushortx8*)(QKV + (kb_ + vk0 + 1) * 3072 + 2048 + colB + vcv * 8);\
    } while (0)

    #define WRITE_V(buf) do {                                                      \
        _Pragma("unroll")                                                          \
        for (int j_ = 0; j_ < 8; ++j_) {                                           \
            const int d_ = vcv * 8 + j_;                                           \
            unsigned int pk_ = (unsigned int)(unsigned short)vst0[j_] |            \
                               ((unsigned int)(unsigned short)vst1[j_] << 16);     \
            *(unsigned int*)&Vt[buf][d_ * 72 + vk0] = pk_;                         \
        }                                                                          \
    } while (0)

    ushortx8 vst0, vst1;

    // ---- prologue: stage Q tile, K[0], V[0] ------------------------------
    #pragma unroll
    for (int i = 0; i < 4; ++i) {
        const int c = w * 256 + i * 64 + lane;
        const int r = c >> 3;
        const int gc = (c & 7) ^ (r & 7);
        __builtin_amdgcn_global_load_lds(
            (const __attribute__((address_space(1))) void*)
                (QKV + (rowQ + r) * 3072 + colB + gc * 8),
            (__attribute__((address_space(3))) void*)
                (&Qs[(w * 256 + i * 64) * 8]), 16, 0, 0);
    }
    STAGE_K(0, 0);
    LOAD_V(0);
    WRITE_V(0);
    __syncthreads();

    // ---- Q fragments (held in registers for the whole kernel) ------------
    short8 qb[2][2];
    #pragma unroll
    for (int nf = 0; nf < 2; ++nf)
        #pragma unroll
        for (int ks = 0; ks < 2; ++ks)
            qb[nf][ks] = *(const short8*)&Qs[(w * 32 + 16 * nf + m) * 64 +
                                             ((g + 4 * ks) ^ l7) * 8];

    f32x4 o[2][4];
    #pragma unroll
    for (int nf = 0; nf < 2; ++nf)
        #pragma unroll
        for (int dn = 0; dn < 4; ++dn)
            o[nf][dn] = (f32x4){0.f, 0.f, 0.f, 0.f};
    float mr[2] = {-1e30f, -1e30f};
    float lsm[2] = {0.f, 0.f};

    for (int kt = 0; kt < 8; ++kt) {
        const int cur = kt & 1, nxt = cur ^ 1;
        if (kt < 7) { STAGE_K(nxt, kt + 1); LOAD_V(kt + 1); }

        // ---- QK^T: S^T tile 64 keys x 32 q per wave ----
        f32x4 st[4][2];
        #pragma unroll
        for (int mf = 0; mf < 4; ++mf)
            #pragma unroll
            for (int nf = 0; nf < 2; ++nf)
                st[mf][nf] = (f32x4){0.f, 0.f, 0.f, 0.f};
        #pragma unroll
        for (int ks = 0; ks < 2; ++ks) {
            short8 a[4];
            #pragma unroll
            for (int mf = 0; mf < 4; ++mf)
                a[mf] = *(const short8*)&Ks[cur][(m + 16 * mf) * 64 +
                                                 ((g + 4 * ks) ^ l7) * 8];
            #pragma unroll
            for (int mf = 0; mf < 4; ++mf)
                #pragma unroll
                for (int nf = 0; nf < 2; ++nf)
                    st[mf][nf] = __builtin_amdgcn_mfma_f32_16x16x32_bf16(
                        a[mf], qb[nf][ks], st[mf][nf], 0, 0, 0);
        }

        // ---- online softmax (raw units; scale 0.125 folded into exp) ----
        float pmax[2];
        #pragma unroll
        for (int nf = 0; nf < 2; ++nf) {
            float mx = st[0][nf][0];
            #pragma unroll
            for (int mf = 0; mf < 4; ++mf)
                #pragma unroll
                for (int r = 0; r < 4; ++r)
                    mx = fmaxf(mx, st[mf][nf][r]);
            mx = fmaxf(mx, __shfl_xor(mx, 16));
            mx = fmaxf(mx, __shfl_xor(mx, 32));
            pmax[nf] = mx;
        }
        const int need = (pmax[0] - mr[0] > 64.f) || (pmax[1] - mr[1] > 64.f);
        if (__any(need)) {
            #pragma unroll
            for (int nf = 0; nf < 2; ++nf) {
                const float mn = fmaxf(mr[nf], pmax[nf]);
                const float al = __expf(0.125f * (mr[nf] - mn));
                lsm[nf] *= al;
                mr[nf] = mn;
            }
            #pragma unroll
            for (int nf = 0; nf < 2; ++nf) {
                const float a0 = __expf(0.125f * (mr[nf] - mr[nf]));  // placeholder keep
                (void)a0;
            }
            // rescale O: alpha for q-row 4g+r+16nf gathered from lane 4g+r
            #pragma unroll
            for (int nf = 0; nf < 2; ++nf) {
                const float alme = __expf(0.125f * (mr[nf] - mr[nf])); (void)alme;
            }
            float alv[2];
            #pragma unroll
            for (int nf = 0; nf < 2; ++nf)
                alv[nf] = __expf(0.125f * (fminf(mr[nf], pmax[nf]) - mr[nf]) * 0.f) *
                          __expf(0.f);  // dummy to avoid double-compute below
            (void)alv;
            // (recompute alpha cleanly)
            #pragma unroll
            for (int nf = 0; nf < 2; ++nf) {
                // alpha was applied to lsm above using old mr; for O we need the
                // same alpha: exp(0.125*(old_m - new_m)). old_m = new_m unless
                // pmax raised it; reconstruct: alpha = exp(0.125*(min(mr,pmax_old_m)... 
            }
            // NOTE: alpha handled below via saved values
        }
        // --- clean rescale implementation (recomputed to keep code simple) ---
        // We recompute alphas from saved old maxima:
        // (saved before update)
        // To avoid the messy block above, alphas are computed here from pmax:
        // al[nf] = exp(0.125*(old_mr - new_mr)) which equals 1 when skipped.
        // Implemented by tracking old_mr explicitly:
        // (see al_q gather below)
        float al_q[2][4];   // per (nf, r): alpha for q = 4g+r+16nf
        {
            // old_mr was overwritten only in the rescale branch; reconstruct:
            // if rescale happened, alpha_nf = exp(0.125*(prev - mr[nf])) was the
            // value used for lsm. We saved nothing, so compute alpha directly:
            // alpha = 1 if no rescale. We recompute inside branch below instead.
        }
        // Simpler: recompute alpha fresh (branch-free correctness):
        // alpha_nf = exp(0.125*(mr_before - mr_after)). Track mr_before:
        // -- restructured: see below --

        // ---- P = exp(0.125*(s - mr)) and accumulate l ----
        float pf[2][4][4];
        #pragma unroll
        for (int nf = 0; nf < 2; ++nf) {
            float ls = 0.f;
            #pragma unroll
            for (int mf = 0; mf < 4; ++mf)
                #pragma unroll
                for (int r = 0; r < 4; ++r) {
                    const float p = __expf(0.125f * (st[mf][nf][r] - mr[nf]));
                    pf[nf][mf][r] = p;
                    ls += p;
                }
            ls += __shfl_xor(ls, 16);
            ls += __shfl_xor(ls, 32);
            lsm[nf] += ls;
        }

        // ---- write V[kt+1] into Vt[nxt] (loads have had QK+softmax to land) ----
        if (kt < 7) WRITE_V(nxt);

        // ---- pack P to bf16 A-frags (lane-local) ----
        short8 pb[2][2];
        #pragma unroll
        for (int nf = 0; nf < 2; ++nf)
            #pragma unroll
            for (int ks = 0; ks < 2; ++ks)
                #pragma unroll
                for (int j = 0; j < 8; ++j)
                    pb[nf][ks][j] = (short)f2bf(pf[nf][(j >> 2) + 2 * ks][j & 3]);

        // ---- PV ----
        #pragma unroll
        for (int ks = 0; ks < 2; ++ks) {
            short8 vb[4];
            #pragma unroll
            for (int dn = 0; dn < 4; ++dn) {
                const int d = m + 16 * dn;
                const short4v lo = *(const short4v*)&Vt[cur][d * 72 + 4 * g + 32 * ks];
                const short4v hi = *(const short4v*)&Vt[cur][d * 72 + 4 * g + 16 + 32 * ks];
                vb[dn] = __builtin_shufflevector(lo, hi, 0, 1, 2, 3, 4, 5, 6, 7);
            }
            #pragma unroll
            for (int nf = 0; nf < 2; ++nf)
                #pragma unroll
                for (int dn = 0; dn < 4; ++dn)
                    o[nf][dn] = __builtin_amdgcn_mfma_f32_16x16x32_bf16(
                        pb[nf][ks], vb[dn], o[nf][dn], 0, 0, 0);
        }
        __syncthreads();
    }

    // ---- final: O / l, store fp32 ----
    #pragma unroll
    for (int nf = 0; nf < 2; ++nf) {
        const float inv = 1.0f / lsm[nf];
        #pragma unroll
        for (int r = 0; r < 4; ++r) {
            const float sc = __shfl(inv, 4 * g + r);
            const size_t row = rowQ + w * 32 + 16 * nf + 4 * g + r;
            #pragma unroll
            for (int dn = 0; dn < 4; ++dn)
                Og[row * D_MODEL + colB + 16 * dn + m] = o[nf][dn][r] * sc;
        }
    }
    #undef STAGE_K
    #undef LOAD_V
    #undef WRITE_V
}

// NOTE on the rescale: the messy alpha code above was replaced by the design
// where O-rescale must multiply o[nf][dn][r] by alpha for q=4g+r+16nf gathered
// from lane 4g+r. That logic is required INSIDE the rescale branch. The kernel
// above as written omits it, which is WRONG. The corrected kernel is below and
// is the one actually used.

__global__ __launch_bounds__(256)
void attn_kernel_fixed(const unsigned short* __restrict__ QKV, float* __restrict__ Og) {
    __shared__ unsigned short Qs[128 * 64];
    __shared__ unsigned short Ks[2][64 * 64];
    __shared__ unsigned short Vt[2][64 * 72];

    const int tid = threadIdx.x;
    const int lane = tid & 63;
    const int w = tid >> 6;
    const int m = lane & 15;
    const int g = lane >> 4;
    const int l7 = lane & 7;
    const int qt = blockIdx.x, hh = blockIdx.y, bb = blockIdx.z;
    const int colB = hh * 64;
    const size_t rowQ = (size_t)bb * 512 + qt * 128;
    const size_t rowKV = (size_t)bb * 512;

    const int vk0 = (tid & 31) * 2;
    const int vcv = tid >> 5;

    #define STAGE_K(buf, kt) do {                                                  \
        const size_t kb_ = rowKV + (size_t)(kt) * 64;                              \
        _Pragma("unroll")                                                          \
        for (int i_ = 0; i_ < 2; ++i_) {                                           \
            const int c_ = w * 128 + i_ * 64 + lane;                               \
            const int r_ = c_ >> 3;                                                \
            const int gc_ = (c_ & 7) ^ (r_ & 7);                                   \
            __builtin_amdgcn_global_load_lds(                                      \
                (const __attribute__((address_space(1))) void*)                    \
                    (QKV + (kb_ + r_) * 3072 + 1024 + colB + gc_ * 8),             \
                (__attribute__((address_space(3))) void*)                          \
                    (&Ks[buf][(w * 128 + i_ * 64) * 8]), 16, 0, 0);                \
        }                                                                          \
    } while (0)

    #define LOAD_V(kt) do {                                                        \
        const size_t kb_ = rowKV + (size_t)(kt) * 64;                              \
        vst0 = *(const ushortx8*)(QKV + (kb_ + vk0) * 3072 + 2048 + colB + vcv * 8);\
        vst1 = *(const ushortx8*)(QKV + (kb_ + vk0 + 1) * 3072 + 2048 + colB + vcv * 8);\
    } while (0)

    #define WRITE_V(buf) do {                                                      \
        _Pragma("unroll")                                                          \
        for (int j_ = 0; j_ < 8; ++j_) {                                           \
            const int d_ = vcv * 8 + j_;                                           \
            unsigned int pk_ = (unsigned int)(unsigned short)vst0[j_] |            \
                               ((unsigned int)(unsigned short)vst1[j_] << 16);     \
            *(unsigned int*)&Vt[buf][d_ * 72 + vk0] = pk_;                         \
        }                                                                          \
    } while (0)

    ushortx8 vst0, vst1;

    #pragma unroll
    for (int i = 0; i < 4; ++i) {
        const int c = w * 256 + i * 64 + lane;
        const int r = c >> 3;
        const int gc = (c & 7) ^ (r & 7);
        __builtin_amdgcn_global_load_lds(
            (const __attribute__((address_space(1))) void*)
                (QKV + (rowQ + r) * 3072 + colB + gc * 8),
            (__attribute__((address_space(3))) void*)
                (&Qs[(w * 256 + i * 64) * 8]), 16, 0, 0);
    }
    STAGE_K(0, 0);
    LOAD_V(0);
    WRITE_V(0);
    __syncthreads();

    short8 qb[2][2];
    #pragma unroll
    for (int nf = 0; nf < 2; ++nf)
        #pragma unroll
        for (int ks = 0; ks < 2; ++ks)
            qb[nf][ks] = *(const short8*)&Qs[(w * 32 + 16 * nf + m) * 64 +
                                             ((g + 4 * ks) ^ l7) * 8];

    f32x4 o[2][4];
    #pragma unroll
    for (int nf = 0; nf < 2; ++nf)
        #pragma unroll
        for (int dn = 0; dn < 4; ++dn)
            o[nf][dn] = (f32x4){0.f, 0.f, 0.f, 0.f};
    float mr[2] = {-1e30f, -1e30f};
    float lsm[2] = {0.f, 0.f};

    for (int kt = 0; kt < 8; ++kt) {
        const int cur = kt & 1, nxt = cur ^ 1;
        if (kt < 7) { STAGE_K(nxt, kt + 1); LOAD_V(kt + 1); }

        f32x4 st[4][2];
        #pragma unroll
        for (int mf = 0; mf < 4; ++mf)
            #pragma unroll
            for (int nf = 0; nf < 2; ++nf)
                st[mf][nf] = (f32x4){0.f, 0.f, 0.f, 0.f};
        #pragma unroll
        for (int ks = 0; ks < 2; ++ks) {
            short8 a[4];
            #pragma unroll
            for (int mf = 0; mf < 4; ++mf)
                a[mf] = *(const short8*)&Ks[cur][(m + 16 * mf) * 64 +
                                                 ((g + 4 * ks) ^ l7) * 8];
            #pragma unroll
            for (int mf = 0; mf < 4; ++mf)
                #pragma unroll
                for (int nf = 0; nf < 2; ++nf)
                    st[mf][nf] = __builtin_amdgcn_mfma_f32_16x16x32_bf16(
                        a[mf], qb[nf][ks], st[mf][nf], 0, 0, 0);
        }

        float pmax[2];
        #pragma unroll
        for (int nf = 0; nf < 2; ++nf) {
            float mx = st[0][nf][0];
            #pragma unroll
            for (int mf = 0; mf < 4; ++mf)
                #pragma unroll
                for (int r = 0; r < 4; ++r)
                    mx = fmaxf(mx, st[mf][nf][r]);
            mx = fmaxf(mx, __shfl_xor(mx, 16));
            mx = fmaxf(mx, __shfl_xor(mx, 32));
            pmax[nf] = mx;
        }
        const int need = (pmax[0] - mr[0] > 64.f) || (pmax[1] - mr[1] > 64.f);
        if (__any(need)) {
            float al[2];
            #pragma unroll
            for (int nf = 0; nf < 2; ++nf) {
                const float mn = fmaxf(mr[nf], pmax[nf]);
                al[nf] = __expf(0.125f * (mr[nf] - mn));
                lsm[nf] *= al[nf];
                mr[nf] = mn;
            }
            #pragma unroll
            for (int nf = 0; nf < 2; ++nf)
                #pragma unroll
                for (int r = 0; r < 4; ++r) {
                    const float av = __shfl(al[nf], 4 * g + r);
                    #pragma unroll
                    for (int dn = 0; dn < 4; ++dn)
                        o[nf][dn][r] *= av;
                }
        }

        float pf[2][4][4];
        #pragma unroll
        for (int nf = 0; nf < 2; ++nf) {
            float ls = 0.f;
            #pragma unroll
            for (int mf = 0; mf < 4; ++mf)
                #pragma unroll
                for (int r = 0; r < 4; ++r) {
                    const float p = __expf(0.125f * (st[mf][nf][r] - mr[nf]));
                    pf[nf][mf][r] = p;
                    ls += p;
                }
            ls += __shfl_xor(ls, 16);
            ls += __shfl_xor(ls, 32);
            lsm[nf] += ls;
        }

        if (kt < 7) WRITE_V(nxt);

        short8 pb[2][2];
        #pragma unroll
        for (int nf = 0; nf < 2; ++nf)
            #pragma unroll
            for (int ks = 0; ks < 2; ++ks)
                #pragma unroll
                for (int j = 0; j < 8; ++j)
                    pb[nf][ks][j] = (short)f2bf(pf[nf][(j >> 2) + 2 * ks][j & 3]);

        #pragma unroll
        for (int ks = 0; ks < 2; ++ks) {
            short8 vb[4];
            #pragma unroll
            for (int dn = 0; dn < 4; ++dn) {
                const int d = m + 16 * dn;
                const short4v lo = *(const short4v*)&Vt[cur][d * 72 + 4 * g + 32 * ks];
                const short4v hi = *(const short4v*)&Vt[cur][d * 72 + 4 * g + 16 + 32 * ks];
                vb[dn] = __builtin_shufflevector(lo, hi, 0, 1, 2, 3, 4, 5, 6, 7);
            }
            #pragma unroll
            for (int nf = 0; nf < 2; ++nf)
                #pragma unroll
                for (int dn = 0; dn < 4; ++dn)
                    o[nf][dn] = __builtin_amdgcn_mfma_f32_16x16x32_bf16(
                        pb[nf][ks], vb[dn], o[nf][dn], 0, 0, 0);
        }
        __syncthreads();
    }

    #pragma unroll
    for (int nf = 0; nf < 2; ++nf) {
        const float inv = 1.0f / lsm[nf];
        #pragma unroll
        for (int r = 0; r < 4; ++r) {
            const float sc = __shfl(inv, 4 * g + r);
            const size_t row = rowQ + w * 32 + 16 * nf + 4 * g + r;
            #pragma unroll
            for (int dn = 0; dn < 4; ++dn)
                Og[row * D_MODEL + colB + 16 * dn + m] = o[nf][dn][r] * sc;
        }
    }
    #undef STAGE_K
    #undef LOAD_V
    #undef WRITE_V
}

// ---------------------------------------------------------------------------
// BatchNorm
// ---------------------------------------------------------------------------
__global__ __launch_bounds__(256)
void bn_stats_partial_kernel(const float* __restrict__ A, const float* __restrict__ R,
                             float* __restrict__ part) {
    const int tx = threadIdx.x, ty = threadIdx.y;
    const int c = blockIdx.x * 64 + tx;
    const int r0 = blockIdx.y * 128;
    float sum = 0.0f, sq = 0.0f;
    for (int r = r0 + ty; r < r0 + 128; r += 4) {
        float v = A[(size_t)r * D_MODEL + c];
        if (R) v += R[(size_t)r * D_MODEL + c];
        sum += v; sq += v * v;
    }
    __shared__ float sh[2][4][64];
    sh[0][ty][tx] = sum; sh[1][ty][tx] = sq;
    __syncthreads();
    if (ty == 0) {
        sum = sh[0][0][tx] + sh[0][1][tx] + sh[0][2][tx] + sh[0][3][tx];
        sq  = sh[1][0][tx] + sh[1][1][tx] + sh[1][2][tx] + sh[1][3][tx];
        part[blockIdx.y * 2048 + c] = sum;
        part[blockIdx.y * 2048 + 1024 + c] = sq;
    }
}

__global__ __launch_bounds__(256)
void bn_stats_final_kernel(const float* __restrict__ part, float* __restrict__ stats) {
    const int c = blockIdx.x * 256 + threadIdx.x;
    float sum = 0.0f, sq = 0.0f;
    for (int g = 0; g < 32; ++g) {
        sum += part[g * 2048 + c];
        sq  += part[g * 2048 + 1024 + c];
    }
    const float mean = sum * (1.0f / 4096.0f);
    stats[c] = mean;
    stats[D_MODEL + c] = sq * (1.0f / 4096.0f) - mean * mean;
}

__global__ __launch_bounds__(256)
void bn_apply_kernel(const float* __restrict__ A, const float* __restrict__ R,
                     const float* __restrict__ stats, const float* __restrict__ gamma,
                     const float* __restrict__ beta, float* __restrict__ out,
                     unsigned short* __restrict__ outbf) {
    const int idx = blockIdx.x * 256 + threadIdx.x;
    const int c = (idx & 255) << 2;
    float4 v = reinterpret_cast<const float4*>(A)[idx];
    if (R) {
        const float4 rv = reinterpret_cast<const float4*>(R)[idx];
        v.x += rv.x; v.y += rv.y; v.z += rv.z; v.w += rv.w;
    }
    const float4 mn = *reinterpret_cast<const float4*>(&stats[c]);
    const float4 vr = *reinterpret_cast<const float4*>(&stats[D_MODEL + c]);
    const float4 g  = *reinterpret_cast<const float4*>(&gamma[c]);
    const float4 bt = *reinterpret_cast<const float4*>(&beta[c]);
    float4 r;
    r.x = g.x * (v.x - mn.x) * rsqrtf(vr.x + BN_EPS) + bt.x;
    r.y = g.y * (v.y - mn.y) * rsqrtf(vr.y + BN_EPS) + bt.y;
    r.z = g.z * (v.z - mn.z) * rsqrtf(vr.z + BN_EPS) + bt.z;
    r.w = g.w * (v.w - mn.w) * rsqrtf(vr.w + BN_EPS) + bt.w;
    reinterpret_cast<float4*>(out)[idx] = r;
    if (outbf) {
        ushort4 o;
        o.x = f2bf(r.x); o.y = f2bf(r.y); o.z = f2bf(r.z); o.w = f2bf(r.w);
        reinterpret_cast<ushort4*>(outbf)[idx] = o;
    }
}

static void run_bn(const float* A, const float* R, const float* gamma,
                   const float* beta, float* out, unsigned short* outbf,
                   float* part, float* stats, hipStream_t stream) {
    bn_stats_partial_kernel<<<dim3(16, 32), dim3(64, 4), 0, stream>>>(A, R, part);
    bn_stats_final_kernel<<<4, 256, 0, stream>>>(part, stats);
    bn_apply_kernel<<<4096, 256, 0, stream>>>(A, R, stats, gamma, beta, out, outbf);
}

extern "C" void kernel_launch(void* const* d_in, const int* in_sizes, int n_in,
                              void* d_out, int out_size, void* d_ws, size_t ws_size,
                              hipStream_t stream) {
    const float* x       = (const float*)d_in[0];
    const float* W_embed = (const float*)d_in[1];
    const float* bn1_g   = (const float*)d_in[2];
    const float* bn1_b   = (const float*)d_in[3];
    const float* Wq      = (const float*)d_in[4];
    const float* bq      = (const float*)d_in[5];
    const float* Wk      = (const float*)d_in[6];
    const float* bk      = (const float*)d_in[7];
    const float* Wv      = (const float*)d_in[8];
    const float* bv      = (const float*)d_in[9];
    const float* bng     = (const float*)d_in[10];
    const float* bnb     = (const float*)d_in[11];
    const float* Wc1     = (const float*)d_in[12];
    const float* bc1     = (const float*)d_in[13];
    const float* bn2g    = (const float*)d_in[14];
    const float* bn2b    = (const float*)d_in[15];

    const size_t NBUF = (size_t)M_ROWS * D_MODEL;
    float* E = (float*)d_out;
    float* ws = (float*)d_ws;
    float* O     = ws;
    float* part  = O + NBUF;
    float* stats = part + 65536;
    float* bqkv  = stats + 2048;
    unsigned short* Ebf   = (unsigned short*)(bqkv + 3072);
    unsigned short* QKVbf = Ebf + NBUF;
    unsigned short* F1bf  = QKVbf;
    unsigned short* Wtqkv = QKVbf + (size_t)M_ROWS * 3072;
    unsigned short* Wtc1  = Wtqkv + (size_t)3072 * 1024;

    const dim3 tgrid(16, 16);
    const dim3 qkvGrid(24, 32);
    const dim3 ffnGrid(8, 32);

    gemm_kernel<false><<<dim3(8, 32), 256, 0, stream>>>(x, W_embed, nullptr, E,
                                                        M_ROWS, D_MODEL, 64);
    run_bn(E, nullptr, bn1_g, bn1_b, E, Ebf, part, stats, stream);

    for (int i = 0; i < 2; ++i) {
        const size_t wo = (size_t)i * D_MODEL * D_MODEL;
        const size_t bo = (size_t)i * D_MODEL;
        transpose_cvt_kernel<<<tgrid, 256, 0, stream>>>(Wq + wo, Wtqkv);
        transpose_cvt_kernel<<<tgrid, 256, 0, stream>>>(Wk + wo, Wtqkv + (size_t)1024 * 1024);
        transpose_cvt_kernel<<<tgrid, 256, 0, stream>>>(Wv + wo, Wtqkv + (size_t)2048 * 1024);
        transpose_cvt_kernel<<<tgrid, 256, 0, stream>>>(Wc1 + wo, Wtc1);
        bias_concat_kernel<<<12, 256, 0, stream>>>(bq + bo, bk + bo, bv + bo, bqkv);

        gemm_bf16_kernel<true><<<qkvGrid, 256, 0, stream>>>(Ebf, Wtqkv, bqkv,
                                                            QKVbf, 3072, 1024);
        attn_kernel_fixed<<<dim3(4, 16, 8), 256, 0, stream>>>(QKVbf, O);
        run_bn(O, E, bng + bo, bnb + bo, E, Ebf, part, stats, stream);

        gemm_bf16_kernel<true><<<ffnGrid, 256, 0, stream>>>(Ebf, Wtc1, bc1 + bo,
                                                            F1bf, 1024, 1024);
        gemm_bf16_kernel<false><<<ffnGrid, 256, 0, stream>>>(F1bf, Wtc1, bc1 + bo,
                                                             O, 1024, 1024);
        run_bn(O, E, bn2g + bo, bn2b + bo, E, (i == 0) ? Ebf : nullptr,
               part, stats, stream);
    }
}

// Round 4
// 318.314 us; speedup vs baseline: 5.6984x; 1.2047x over previous
//
#include <hip/hip_runtime.h>
#include <hip/hip_bf16.h>
#include <cstddef>

#define D_MODEL 1024
#define M_ROWS  4096
#define BN_EPS  1e-3f
#define C_EXP2  0.18033688011112042f   // 0.125 * log2(e)

typedef __attribute__((ext_vector_type(8))) short short8;
typedef __attribute__((ext_vector_type(4))) short short4v;
typedef __attribute__((ext_vector_type(8))) unsigned short ushortx8;
typedef __attribute__((ext_vector_type(4))) float f32x4;

__device__ __forceinline__ unsigned short f2bf(float f) {
    __hip_bfloat16 h = __float2bfloat16(f);
    return *reinterpret_cast<unsigned short*>(&h);
}
__device__ __forceinline__ float bf2f(unsigned short u) {
    return __uint_as_float(((unsigned)u) << 16);
}

// ---------------------------------------------------------------------------
// Embed GEMM (fp32, K=64): S = x @ W_embed, written bf16 + per-channel stats.
// ---------------------------------------------------------------------------
__global__ __launch_bounds__(256)
void embed_kernel(const float* __restrict__ A, const float* __restrict__ W,
                  unsigned short* __restrict__ Sbf, float* __restrict__ accp) {
    __shared__ float As[16][132];
    __shared__ float Bs[16][132];
    const int tid = threadIdx.x;
    const int lane = tid & 63;
    const int tx = tid & 15, ty = tid >> 4;
    const int rowBase = blockIdx.y * 128;
    const int colBase = blockIdx.x * 128;
    float acc[8][8] = {};
    for (int k0 = 0; k0 < 64; k0 += 16) {
        #pragma unroll
        for (int it = 0; it < 2; ++it) {
            int idx = tid + it * 256;
            int r = idx >> 2, c4 = (idx & 3) << 2;
            const float4 v = *reinterpret_cast<const float4*>(
                &A[(size_t)(rowBase + r) * 64 + k0 + c4]);
            As[c4 + 0][r] = v.x; As[c4 + 1][r] = v.y;
            As[c4 + 2][r] = v.z; As[c4 + 3][r] = v.w;
        }
        #pragma unroll
        for (int it = 0; it < 2; ++it) {
            int idx = tid + it * 256;
            int r = idx >> 5, c4 = (idx & 31) << 2;
            const float4 v = *reinterpret_cast<const float4*>(
                &W[(size_t)(k0 + r) * D_MODEL + colBase + c4]);
            *reinterpret_cast<float4*>(&Bs[r][c4]) = v;
        }
        __syncthreads();
        #pragma unroll
        for (int k = 0; k < 16; ++k) {
            const float4 a0 = *reinterpret_cast<const float4*>(&As[k][ty * 8]);
            const float4 a1 = *reinterpret_cast<const float4*>(&As[k][ty * 8 + 4]);
            const float4 b0 = *reinterpret_cast<const float4*>(&Bs[k][tx * 8]);
            const float4 b1 = *reinterpret_cast<const float4*>(&Bs[k][tx * 8 + 4]);
            const float a[8] = {a0.x, a0.y, a0.z, a0.w, a1.x, a1.y, a1.z, a1.w};
            const float b[8] = {b0.x, b0.y, b0.z, b0.w, b1.x, b1.y, b1.z, b1.w};
            #pragma unroll
            for (int i = 0; i < 8; ++i)
                #pragma unroll
                for (int j = 0; j < 8; ++j)
                    acc[i][j] = fmaf(a[i], b[j], acc[i][j]);
        }
        __syncthreads();
    }
    float cs[8] = {}, cq[8] = {};
    #pragma unroll
    for (int i = 0; i < 8; ++i) {
        const int row = rowBase + ty * 8 + i;
        ushortx8 ov;
        #pragma unroll
        for (int j = 0; j < 8; ++j) {
            const float s = acc[i][j];
            ov[j] = f2bf(s);
            cs[j] += s; cq[j] += s * s;
        }
        *reinterpret_cast<ushortx8*>(&Sbf[(size_t)row * D_MODEL + colBase + tx * 8]) = ov;
    }
    #pragma unroll
    for (int j = 0; j < 8; ++j) {
        cs[j] += __shfl_xor(cs[j], 16); cs[j] += __shfl_xor(cs[j], 32);
        cq[j] += __shfl_xor(cq[j], 16); cq[j] += __shfl_xor(cq[j], 32);
    }
    if (lane < 16) {
        #pragma unroll
        for (int j = 0; j < 8; ++j) {
            atomicAdd(&accp[colBase + lane * 8 + j], cs[j]);
            atomicAdd(&accp[D_MODEL + colBase + lane * 8 + j], cq[j]);
        }
    }
}

// ---------------------------------------------------------------------------
// bf16 MFMA GEMM. MODE 0: C = bf16(relu(A@Bt^T + bias)).
// MODE 1: S = relu(A@Bt^T + bias) + resid; write bf16 + per-channel stats.
// ---------------------------------------------------------------------------
template<int MODE>
__global__ __launch_bounds__(256)
void gemm_bf16_kernel(const unsigned short* __restrict__ A,
                      const unsigned short* __restrict__ Bt,
                      const float* __restrict__ bias,
                      unsigned short* __restrict__ Cout,
                      const unsigned short* __restrict__ resid,
                      float* __restrict__ accp, int N, int Kd) {
    __shared__ unsigned short As[2][128 * 32];
    __shared__ unsigned short Bs[2][128 * 32];
    const int tid = threadIdx.x;
    const int lane = tid & 63;
    const int w = tid >> 6;
    const int wr = w >> 1, wc = w & 1;
    const int rowBase = blockIdx.y * 128;
    const int colBase = blockIdx.x * 128;

    const int chunk0 = w * 64 + lane;
    const int r0 = chunk0 >> 2;
    const int c0 = (chunk0 & 3) ^ ((r0 >> 1) & 3);
    const int chunk1 = 256 + chunk0;
    const int r1 = chunk1 >> 2;
    const int c1 = (chunk1 & 3) ^ ((r1 >> 1) & 3);
    const size_t aOff0 = (size_t)(rowBase + r0) * Kd + c0 * 8;
    const size_t aOff1 = (size_t)(rowBase + r1) * Kd + c1 * 8;
    const size_t bOff0 = (size_t)(colBase + r0) * Kd + c0 * 8;
    const size_t bOff1 = (size_t)(colBase + r1) * Kd + c1 * 8;
    const int ldsOff0 = (w * 64) * 8;
    const int ldsOff1 = (256 + w * 64) * 8;

    f32x4 acc[4][4];
    #pragma unroll
    for (int m = 0; m < 4; ++m)
        #pragma unroll
        for (int n = 0; n < 4; ++n)
            acc[m][n] = (f32x4){0.f, 0.f, 0.f, 0.f};

    #define STAGE(buf, kt) do {                                                   \
        const int k0_ = (kt) << 5;                                                \
        __builtin_amdgcn_global_load_lds(                                         \
            (const __attribute__((address_space(1))) void*)(A + aOff0 + k0_),     \
            (__attribute__((address_space(3))) void*)(&As[buf][ldsOff0]), 16, 0, 0);\
        __builtin_amdgcn_global_load_lds(                                         \
            (const __attribute__((address_space(1))) void*)(A + aOff1 + k0_),     \
            (__attribute__((address_space(3))) void*)(&As[buf][ldsOff1]), 16, 0, 0);\
        __builtin_amdgcn_global_load_lds(                                         \
            (const __attribute__((address_space(1))) void*)(Bt + bOff0 + k0_),    \
            (__attribute__((address_space(3))) void*)(&Bs[buf][ldsOff0]), 16, 0, 0);\
        __builtin_amdgcn_global_load_lds(                                         \
            (const __attribute__((address_space(1))) void*)(Bt + bOff1 + k0_),    \
            (__attribute__((address_space(3))) void*)(&Bs[buf][ldsOff1]), 16, 0, 0);\
    } while (0)

    const int NT = Kd >> 5;
    STAGE(0, 0);

    const int kb = lane >> 4;
    const int s = kb ^ ((lane >> 1) & 3);
    const int rA = wr * 64 + (lane & 15);
    const int rB = wc * 64 + (lane & 15);

    for (int t = 0; t < NT; ++t) {
        __syncthreads();
        if (t + 1 < NT) STAGE((t + 1) & 1, t + 1);
        const unsigned short* as = As[t & 1];
        const unsigned short* bs = Bs[t & 1];
        short8 a[4], b[4];
        #pragma unroll
        for (int m = 0; m < 4; ++m)
            a[m] = *(const short8*)&as[(rA + m * 16) * 32 + s * 8];
        #pragma unroll
        for (int n = 0; n < 4; ++n)
            b[n] = *(const short8*)&bs[(rB + n * 16) * 32 + s * 8];
        #pragma unroll
        for (int m = 0; m < 4; ++m)
            #pragma unroll
            for (int n = 0; n < 4; ++n)
                acc[m][n] = __builtin_amdgcn_mfma_f32_16x16x32_bf16(
                    a[m], b[n], acc[m][n], 0, 0, 0);
    }
    #undef STAGE

    const int cRow0 = rowBase + wr * 64 + (lane >> 4) * 4;
    const int cCol0 = colBase + wc * 64 + (lane & 15);
    float cs[4] = {}, cq[4] = {};
    #pragma unroll
    for (int n = 0; n < 4; ++n) {
        const int col = cCol0 + n * 16;
        const float bv = bias[col];
        #pragma unroll
        for (int m = 0; m < 4; ++m)
            #pragma unroll
            for (int r = 0; r < 4; ++r) {
                const int row = cRow0 + m * 16 + r;
                float v = fmaxf(acc[m][n][r] + bv, 0.0f);
                if (MODE == 1) {
                    v += bf2f(resid[(size_t)row * N + col]);
                    cs[n] += v; cq[n] += v * v;
                }
                Cout[(size_t)row * N + col] = f2bf(v);
            }
    }
    if (MODE == 1) {
        #pragma unroll
        for (int n = 0; n < 4; ++n) {
            cs[n] += __shfl_xor(cs[n], 16); cs[n] += __shfl_xor(cs[n], 32);
            cq[n] += __shfl_xor(cq[n], 16); cq[n] += __shfl_xor(cq[n], 32);
        }
        if (lane < 16) {
            #pragma unroll
            for (int n = 0; n < 4; ++n) {
                const int col = colBase + wc * 64 + lane + n * 16;
                atomicAdd(&accp[col], cs[n]);
                atomicAdd(&accp[D_MODEL + col], cq[n]);
            }
        }
    }
}

// ---------------------------------------------------------------------------
// weight prep: 4 matrices transposed+converted in one launch (grid.z selects)
// ---------------------------------------------------------------------------
__global__ __launch_bounds__(256)
void transpose_cvt4_kernel(const float* __restrict__ s0, const float* __restrict__ s1,
                           const float* __restrict__ s2, const float* __restrict__ s3,
                           unsigned short* __restrict__ d0, unsigned short* __restrict__ d1,
                           unsigned short* __restrict__ d2, unsigned short* __restrict__ d3) {
    const int z = blockIdx.z;
    const float* src = (z == 0) ? s0 : (z == 1) ? s1 : (z == 2) ? s2 : s3;
    unsigned short* dst = (z == 0) ? d0 : (z == 1) ? d1 : (z == 2) ? d2 : d3;
    __shared__ float T[64][65];
    const int tid = threadIdx.x;
    const int kBase = blockIdx.y * 64;
    const int nBase = blockIdx.x * 64;
    const int rr = tid >> 4;
    const int c4 = (tid & 15) * 4;
    #pragma unroll
    for (int i = 0; i < 4; ++i) {
        const int k = i * 16 + rr;
        const float4 v = *reinterpret_cast<const float4*>(
            &src[(size_t)(kBase + k) * 1024 + nBase + c4]);
        T[k][c4] = v.x; T[k][c4 + 1] = v.y; T[k][c4 + 2] = v.z; T[k][c4 + 3] = v.w;
    }
    __syncthreads();
    #pragma unroll
    for (int i = 0; i < 4; ++i) {
        const int n = i * 16 + rr;
        ushort4 o;
        o.x = f2bf(T[c4 + 0][n]); o.y = f2bf(T[c4 + 1][n]);
        o.z = f2bf(T[c4 + 2][n]); o.w = f2bf(T[c4 + 3][n]);
        *reinterpret_cast<ushort4*>(&dst[(size_t)(nBase + n) * 1024 + kBase + c4]) = o;
    }
}

__global__ __launch_bounds__(256)
void bias_concat_kernel(const float* __restrict__ bq, const float* __restrict__ bk,
                        const float* __restrict__ bv, float* __restrict__ bqkv) {
    const int j = blockIdx.x * 256 + threadIdx.x;
    bqkv[j] = (j < 1024) ? bq[j] : (j < 2048) ? bk[j - 1024] : bv[j - 2048];
}

// ---------------------------------------------------------------------------
// MFMA flash attention + fused residual + BN stats.
// S^T = mfma(K,Q) so q-row is lane-local; PV A-frag repacked lane-locally
// under key permutation pi matched by the V LDS layout. exp via exp2 folding.
// ---------------------------------------------------------------------------
__global__ __launch_bounds__(256)
void attn_kernel(const unsigned short* __restrict__ QKV,
                 const unsigned short* __restrict__ Ebf,
                 unsigned short* __restrict__ Sbf,
                 float* __restrict__ accp) {
    __shared__ unsigned short Qs[128 * 64];
    __shared__ unsigned short Ks[2][64 * 64];
    __shared__ unsigned short Vt[2][64 * 72];

    const int tid = threadIdx.x;
    const int lane = tid & 63;
    const int w = tid >> 6;
    const int m = lane & 15;
    const int g = lane >> 4;
    const int l7 = lane & 7;
    const int qt = blockIdx.x, hh = blockIdx.y, bb = blockIdx.z;
    const int colB = hh * 64;
    const size_t rowQ = (size_t)bb * 512 + qt * 128;
    const size_t rowKV = (size_t)bb * 512;

    const int vk0 = (tid & 31) * 2;
    const int vcv = tid >> 5;

    #define STAGE_K(buf, kt) do {                                                  \
        const size_t kb_ = rowKV + (size_t)(kt) * 64;                              \
        _Pragma("unroll")                                                          \
        for (int i_ = 0; i_ < 2; ++i_) {                                           \
            const int c_ = w * 128 + i_ * 64 + lane;                               \
            const int r_ = c_ >> 3;                                                \
            const int gc_ = (c_ & 7) ^ (r_ & 7);                                   \
            __builtin_amdgcn_global_load_lds(                                      \
                (const __attribute__((address_space(1))) void*)                    \
                    (QKV + (kb_ + r_) * 3072 + 1024 + colB + gc_ * 8),             \
                (__attribute__((address_space(3))) void*)                          \
                    (&Ks[buf][(w * 128 + i_ * 64) * 8]), 16, 0, 0);                \
        }                                                                          \
    } while (0)

    #define LOAD_V(kt) do {                                                        \
        const size_t kb_ = rowKV + (size_t)(kt) * 64;                              \
        vst0 = *(const ushortx8*)(QKV + (kb_ + vk0) * 3072 + 2048 + colB + vcv * 8);\
        vst1 = *(const ushortx8*)(QKV + (kb_ + vk0 + 1) * 3072 + 2048 + colB + vcv * 8);\
    } while (0)

    #define WRITE_V(buf) do {                                                      \
        _Pragma("unroll")                                                          \
        for (int j_ = 0; j_ < 8; ++j_) {                                           \
            const int d_ = vcv * 8 + j_;                                           \
            unsigned int pk_ = (unsigned int)(unsigned short)vst0[j_] |            \
                               ((unsigned int)(unsigned short)vst1[j_] << 16);     \
            *(unsigned int*)&Vt[buf][d_ * 72 + vk0] = pk_;                         \
        }                                                                          \
    } while (0)

    ushortx8 vst0, vst1;

    #pragma unroll
    for (int i = 0; i < 4; ++i) {
        const int c = w * 256 + i * 64 + lane;
        const int r = c >> 3;
        const int gc = (c & 7) ^ (r & 7);
        __builtin_amdgcn_global_load_lds(
            (const __attribute__((address_space(1))) void*)
                (QKV + (rowQ + r) * 3072 + colB + gc * 8),
            (__attribute__((address_space(3))) void*)
                (&Qs[(w * 256 + i * 64) * 8]), 16, 0, 0);
    }
    STAGE_K(0, 0);
    LOAD_V(0);
    WRITE_V(0);
    __syncthreads();

    short8 qb[2][2];
    #pragma unroll
    for (int nf = 0; nf < 2; ++nf)
        #pragma unroll
        for (int ks = 0; ks < 2; ++ks)
            qb[nf][ks] = *(const short8*)&Qs[(w * 32 + 16 * nf + m) * 64 +
                                             ((g + 4 * ks) ^ l7) * 8];

    f32x4 o[2][4];
    #pragma unroll
    for (int nf = 0; nf < 2; ++nf)
        #pragma unroll
        for (int dn = 0; dn < 4; ++dn)
            o[nf][dn] = (f32x4){0.f, 0.f, 0.f, 0.f};
    float mr[2] = {-1e30f, -1e30f};
    float lsm[2] = {0.f, 0.f};

    for (int kt = 0; kt < 8; ++kt) {
        const int cur = kt & 1, nxt = cur ^ 1;
        if (kt < 7) { STAGE_K(nxt, kt + 1); LOAD_V(kt + 1); }

        f32x4 st[4][2];
        #pragma unroll
        for (int mf = 0; mf < 4; ++mf)
            #pragma unroll
            for (int nf = 0; nf < 2; ++nf)
                st[mf][nf] = (f32x4){0.f, 0.f, 0.f, 0.f};
        #pragma unroll
        for (int ks = 0; ks < 2; ++ks) {
            short8 a[4];
            #pragma unroll
            for (int mf = 0; mf < 4; ++mf)
                a[mf] = *(const short8*)&Ks[cur][(m + 16 * mf) * 64 +
                                                 ((g + 4 * ks) ^ l7) * 8];
            #pragma unroll
            for (int mf = 0; mf < 4; ++mf)
                #pragma unroll
                for (int nf = 0; nf < 2; ++nf)
                    st[mf][nf] = __builtin_amdgcn_mfma_f32_16x16x32_bf16(
                        a[mf], qb[nf][ks], st[mf][nf], 0, 0, 0);
        }

        float pmax[2];
        #pragma unroll
        for (int nf = 0; nf < 2; ++nf) {
            float mx = st[0][nf][0];
            #pragma unroll
            for (int mf = 0; mf < 4; ++mf)
                #pragma unroll
                for (int r = 0; r < 4; ++r)
                    mx = fmaxf(mx, st[mf][nf][r]);
            mx = fmaxf(mx, __shfl_xor(mx, 16));
            mx = fmaxf(mx, __shfl_xor(mx, 32));
            pmax[nf] = mx;
        }
        const int need = (pmax[0] - mr[0] > 64.f) || (pmax[1] - mr[1] > 64.f);
        if (__any(need)) {
            float al[2];
            #pragma unroll
            for (int nf = 0; nf < 2; ++nf) {
                const float mn = fmaxf(mr[nf], pmax[nf]);
                al[nf] = exp2f((mr[nf] - mn) * C_EXP2);
                lsm[nf] *= al[nf];
                mr[nf] = mn;
            }
            #pragma unroll
            for (int nf = 0; nf < 2; ++nf)
                #pragma unroll
                for (int r = 0; r < 4; ++r) {
                    const float av = __shfl(al[nf], 4 * g + r);
                    #pragma unroll
                    for (int dn = 0; dn < 4; ++dn)
                        o[nf][dn][r] *= av;
                }
        }

        float pf[2][4][4];
        #pragma unroll
        for (int nf = 0; nf < 2; ++nf) {
            const float mc = mr[nf] * C_EXP2;
            float ls = 0.f;
            #pragma unroll
            for (int mf = 0; mf < 4; ++mf)
                #pragma unroll
                for (int r = 0; r < 4; ++r) {
                    const float p = exp2f(fmaf(st[mf][nf][r], C_EXP2, -mc));
                    pf[nf][mf][r] = p;
                    ls += p;
                }
            ls += __shfl_xor(ls, 16);
            ls += __shfl_xor(ls, 32);
            lsm[nf] += ls;
        }

        if (kt < 7) WRITE_V(nxt);

        short8 pb[2][2];
        #pragma unroll
        for (int nf = 0; nf < 2; ++nf)
            #pragma unroll
            for (int ks = 0; ks < 2; ++ks)
                #pragma unroll
                for (int j = 0; j < 8; ++j)
                    pb[nf][ks][j] = (short)f2bf(pf[nf][(j >> 2) + 2 * ks][j & 3]);

        #pragma unroll
        for (int ks = 0; ks < 2; ++ks) {
            short8 vb[4];
            #pragma unroll
            for (int dn = 0; dn < 4; ++dn) {
                const int d = m + 16 * dn;
                const short4v lo = *(const short4v*)&Vt[cur][d * 72 + 4 * g + 32 * ks];
                const short4v hi = *(const short4v*)&Vt[cur][d * 72 + 4 * g + 16 + 32 * ks];
                vb[dn] = __builtin_shufflevector(lo, hi, 0, 1, 2, 3, 4, 5, 6, 7);
            }
            #pragma unroll
            for (int nf = 0; nf < 2; ++nf)
                #pragma unroll
                for (int dn = 0; dn < 4; ++dn)
                    o[nf][dn] = __builtin_amdgcn_mfma_f32_16x16x32_bf16(
                        pb[nf][ks], vb[dn], o[nf][dn], 0, 0, 0);
        }
        __syncthreads();
    }

    // epilogue: O/l + residual -> Sbf (bf16) + channel stats
    float cs[4] = {}, cq[4] = {};
    #pragma unroll
    for (int nf = 0; nf < 2; ++nf) {
        const float inv = 1.0f / lsm[nf];
        #pragma unroll
        for (int r = 0; r < 4; ++r) {
            const float sc = __shfl(inv, 4 * g + r);
            const size_t row = rowQ + w * 32 + 16 * nf + 4 * g + r;
            #pragma unroll
            for (int dn = 0; dn < 4; ++dn) {
                const int ch = colB + 16 * dn + m;
                const float sv = o[nf][dn][r] * sc + bf2f(Ebf[row * D_MODEL + ch]);
                Sbf[row * D_MODEL + ch] = f2bf(sv);
                cs[dn] += sv; cq[dn] += sv * sv;
            }
        }
    }
    #pragma unroll
    for (int dn = 0; dn < 4; ++dn) {
        cs[dn] += __shfl_xor(cs[dn], 16); cs[dn] += __shfl_xor(cs[dn], 32);
        cq[dn] += __shfl_xor(cq[dn], 16); cq[dn] += __shfl_xor(cq[dn], 32);
    }
    if (lane < 16) {
        #pragma unroll
        for (int dn = 0; dn < 4; ++dn) {
            atomicAdd(&accp[colB + 16 * dn + lane], cs[dn]);
            atomicAdd(&accp[D_MODEL + colB + 16 * dn + lane], cq[dn]);
        }
    }
    #undef STAGE_K
    #undef LOAD_V
    #undef WRITE_V
}

// ---------------------------------------------------------------------------
// BN: stats -> folded affine coefficients; apply = fma stream
// ---------------------------------------------------------------------------
__global__ __launch_bounds__(256)
void bn_final_kernel(const float* __restrict__ accp, const float* __restrict__ gamma,
                     const float* __restrict__ beta, float* __restrict__ coef) {
    const int c = blockIdx.x * 256 + threadIdx.x;    // grid 4
    const float mean = accp[c] * (1.0f / 4096.0f);
    const float var = accp[D_MODEL + c] * (1.0f / 4096.0f) - mean * mean;
    const float s = gamma[c] * rsqrtf(var + BN_EPS);
    coef[c] = s;
    coef[D_MODEL + c] = beta[c] - mean * s;
}

template<bool FINAL>
__global__ __launch_bounds__(256)
void bn_apply_kernel(const unsigned short* __restrict__ S, const float* __restrict__ coef,
                     unsigned short* __restrict__ Ebf, float* __restrict__ outF) {
    const int idx = blockIdx.x * 256 + threadIdx.x;   // 524288 threads, 8 ch each
    const int c8 = (idx & 127) << 3;
    const ushortx8 sv = *(const ushortx8*)&S[(size_t)idx * 8];
    const float4 a0 = *(const float4*)&coef[c8];
    const float4 a1 = *(const float4*)&coef[c8 + 4];
    const float4 b0 = *(const float4*)&coef[D_MODEL + c8];
    const float4 b1 = *(const float4*)&coef[D_MODEL + c8 + 4];
    const float a[8] = {a0.x, a0.y, a0.z, a0.w, a1.x, a1.y, a1.z, a1.w};
    const float b[8] = {b0.x, b0.y, b0.z, b0.w, b1.x, b1.y, b1.z, b1.w};
    float o[8];
    #pragma unroll
    for (int j = 0; j < 8; ++j) o[j] = fmaf(bf2f(sv[j]), a[j], b[j]);
    if (FINAL) {
        *reinterpret_cast<float4*>(&outF[(size_t)idx * 8]) =
            make_float4(o[0], o[1], o[2], o[3]);
        *reinterpret_cast<float4*>(&outF[(size_t)idx * 8 + 4]) =
            make_float4(o[4], o[5], o[6], o[7]);
    } else {
        ushortx8 e;
        #pragma unroll
        for (int j = 0; j < 8; ++j) e[j] = f2bf(o[j]);
        *reinterpret_cast<ushortx8*>(&Ebf[(size_t)idx * 8]) = e;
    }
}

// ---------------------------------------------------------------------------
extern "C" void kernel_launch(void* const* d_in, const int* in_sizes, int n_in,
                              void* d_out, int out_size, void* d_ws, size_t ws_size,
                              hipStream_t stream) {
    const float* x       = (const float*)d_in[0];
    const float* W_embed = (const float*)d_in[1];
    const float* bn1_g   = (const float*)d_in[2];
    const float* bn1_b   = (const float*)d_in[3];
    const float* Wq      = (const float*)d_in[4];
    const float* bq      = (const float*)d_in[5];
    const float* Wk      = (const float*)d_in[6];
    const float* bk      = (const float*)d_in[7];
    const float* Wv      = (const float*)d_in[8];
    const float* bv      = (const float*)d_in[9];
    const float* bng     = (const float*)d_in[10];
    const float* bnb     = (const float*)d_in[11];
    const float* Wc1     = (const float*)d_in[12];
    const float* bc1     = (const float*)d_in[13];
    const float* bn2g    = (const float*)d_in[14];
    const float* bn2b    = (const float*)d_in[15];

    const size_t NBUF = (size_t)M_ROWS * D_MODEL;
    char* ws = (char*)d_ws;
    float* accum = (float*)ws;                              // 5 * 2048 f
    float* coef  = accum + 5 * 2048;                        // 2048 f
    float* bqkv  = coef + 2048;                             // 3072 f
    unsigned short* Ebf   = (unsigned short*)(bqkv + 3072); // 4 M us
    unsigned short* Sbf   = Ebf + NBUF;                     // 4 M us
    unsigned short* QKVbf = Sbf + NBUF;                     // 12 M us
    unsigned short* F1bf  = QKVbf;                          // alias (QKV dead)
    unsigned short* Wtqkv = QKVbf + (size_t)M_ROWS * 3072;  // 3 M us
    unsigned short* Wtc1  = Wtqkv + (size_t)3072 * 1024;    // 1 M us
    float* outF = (float*)d_out;

    hipMemsetAsync(accum, 0, 5 * 2048 * sizeof(float), stream);

    // embed + BN1
    embed_kernel<<<dim3(8, 32), 256, 0, stream>>>(x, W_embed, Sbf, accum);
    bn_final_kernel<<<4, 256, 0, stream>>>(accum, bn1_g, bn1_b, coef);
    bn_apply_kernel<false><<<2048, 256, 0, stream>>>(Sbf, coef, Ebf, nullptr);

    for (int i = 0; i < 2; ++i) {
        const size_t wo = (size_t)i * D_MODEL * D_MODEL;
        const size_t bo = (size_t)i * D_MODEL;
        float* accA = accum + (1 + 2 * i) * 2048;
        float* accF = accum + (2 + 2 * i) * 2048;

        transpose_cvt4_kernel<<<dim3(16, 16, 4), 256, 0, stream>>>(
            Wq + wo, Wk + wo, Wv + wo, Wc1 + wo,
            Wtqkv, Wtqkv + (size_t)1024 * 1024, Wtqkv + (size_t)2048 * 1024, Wtc1);
        bias_concat_kernel<<<12, 256, 0, stream>>>(bq + bo, bk + bo, bv + bo, bqkv);

        gemm_bf16_kernel<0><<<dim3(24, 32), 256, 0, stream>>>(
            Ebf, Wtqkv, bqkv, QKVbf, nullptr, nullptr, 3072, 1024);
        attn_kernel<<<dim3(4, 16, 8), 256, 0, stream>>>(QKVbf, Ebf, Sbf, accA);
        bn_final_kernel<<<4, 256, 0, stream>>>(accA, bng + bo, bnb + bo, coef);
        bn_apply_kernel<false><<<2048, 256, 0, stream>>>(Sbf, coef, Ebf, nullptr);

        gemm_bf16_kernel<0><<<dim3(8, 32), 256, 0, stream>>>(
            Ebf, Wtc1, bc1 + bo, F1bf, nullptr, nullptr, 1024, 1024);
        gemm_bf16_kernel<1><<<dim3(8, 32), 256, 0, stream>>>(
            F1bf, Wtc1, bc1 + bo, Sbf, Ebf, accF, 1024, 1024);
        bn_final_kernel<<<4, 256, 0, stream>>>(accF, bn2g + bo, bn2b + bo, coef);
        if (i == 0)
            bn_apply_kernel<false><<<2048, 256, 0, stream>>>(Sbf, coef, Ebf, nullptr);
        else
            bn_apply_kernel<true><<<2048, 256, 0, stream>>>(Sbf, coef, nullptr, outF);
    }
}

// Round 5
// 275.448 us; speedup vs baseline: 6.5852x; 1.1556x over previous
//
#include <hip/hip_runtime.h>
#include <hip/hip_bf16.h>
#include <cstddef>

#define D_MODEL 1024
#define M_ROWS  4096
#define BN_EPS  1e-3f
#define C_EXP2  0.18033688011112042f   // 0.125 * log2(e)
#define INV_N   (1.0f / 4096.0f)

typedef __attribute__((ext_vector_type(8))) short short8;
typedef __attribute__((ext_vector_type(4))) short short4v;
typedef __attribute__((ext_vector_type(8))) unsigned short ushortx8;
typedef __attribute__((ext_vector_type(4))) float f32x4;

__device__ __forceinline__ unsigned short f2bf(float f) {
    __hip_bfloat16 h = __float2bfloat16(f);
    return *reinterpret_cast<unsigned short*>(&h);
}
__device__ __forceinline__ float bf2f(unsigned short u) {
    return __uint_as_float(((unsigned)u) << 16);
}
__device__ __forceinline__ unsigned int cvt_pk_bf16(float lo, float hi) {
    unsigned int r;
    asm volatile("v_cvt_pk_bf16_f32 %0, %1, %2" : "=v"(r) : "v"(lo), "v"(hi));
    return r;
}

// ---------------------------------------------------------------------------
// bf16 MFMA GEMM, 128x128 tile, BK=32, 4 waves, double-buffered global_load_lds.
// MODE 0: C = bf16(relu(A@Bt^T + bias))             (QKV, FFN1)
// MODE 1: S = relu(A@Bt^T + bias) + resid; bf16 + per-channel stats (FFN2)
// MODE 2: S = A@Bt^T (no bias/relu); bf16 + per-channel stats        (embed)
// bias selected from {b0,b1,b2} by col/1024 (QKV concat without extra kernel).
// ---------------------------------------------------------------------------
template<int MODE>
__global__ __launch_bounds__(256)
void gemm_bf16_kernel(const unsigned short* __restrict__ A,
                      const unsigned short* __restrict__ Bt,
                      const float* __restrict__ b0, const float* __restrict__ b1,
                      const float* __restrict__ b2,
                      unsigned short* __restrict__ Cout,
                      const unsigned short* __restrict__ resid,
                      float* __restrict__ accp, int N, int Kd) {
    __shared__ unsigned short As[2][128 * 32];
    __shared__ unsigned short Bs[2][128 * 32];
    const int tid = threadIdx.x;
    const int lane = tid & 63;
    const int w = tid >> 6;
    const int wr = w >> 1, wc = w & 1;
    const int rowBase = blockIdx.y * 128;
    const int colBase = blockIdx.x * 128;

    const int chunk0 = w * 64 + lane;
    const int r0 = chunk0 >> 2;
    const int c0 = (chunk0 & 3) ^ ((r0 >> 1) & 3);
    const int chunk1 = 256 + chunk0;
    const int r1 = chunk1 >> 2;
    const int c1 = (chunk1 & 3) ^ ((r1 >> 1) & 3);
    const size_t aOff0 = (size_t)(rowBase + r0) * Kd + c0 * 8;
    const size_t aOff1 = (size_t)(rowBase + r1) * Kd + c1 * 8;
    const size_t bOff0 = (size_t)(colBase + r0) * Kd + c0 * 8;
    const size_t bOff1 = (size_t)(colBase + r1) * Kd + c1 * 8;
    const int ldsOff0 = (w * 64) * 8;
    const int ldsOff1 = (256 + w * 64) * 8;

    f32x4 acc[4][4];
    #pragma unroll
    for (int m = 0; m < 4; ++m)
        #pragma unroll
        for (int n = 0; n < 4; ++n)
            acc[m][n] = (f32x4){0.f, 0.f, 0.f, 0.f};

    #define STAGE(buf, kt) do {                                                   \
        const int k0_ = (kt) << 5;                                                \
        __builtin_amdgcn_global_load_lds(                                         \
            (const __attribute__((address_space(1))) void*)(A + aOff0 + k0_),     \
            (__attribute__((address_space(3))) void*)(&As[buf][ldsOff0]), 16, 0, 0);\
        __builtin_amdgcn_global_load_lds(                                         \
            (const __attribute__((address_space(1))) void*)(A + aOff1 + k0_),     \
            (__attribute__((address_space(3))) void*)(&As[buf][ldsOff1]), 16, 0, 0);\
        __builtin_amdgcn_global_load_lds(                                         \
            (const __attribute__((address_space(1))) void*)(Bt + bOff0 + k0_),    \
            (__attribute__((address_space(3))) void*)(&Bs[buf][ldsOff0]), 16, 0, 0);\
        __builtin_amdgcn_global_load_lds(                                         \
            (const __attribute__((address_space(1))) void*)(Bt + bOff1 + k0_),    \
            (__attribute__((address_space(3))) void*)(&Bs[buf][ldsOff1]), 16, 0, 0);\
    } while (0)

    const int NT = Kd >> 5;
    STAGE(0, 0);

    const int kb = lane >> 4;
    const int s = kb ^ ((lane >> 1) & 3);
    const int rA = wr * 64 + (lane & 15);
    const int rB = wc * 64 + (lane & 15);

    for (int t = 0; t < NT; ++t) {
        __syncthreads();
        if (t + 1 < NT) STAGE((t + 1) & 1, t + 1);
        const unsigned short* as = As[t & 1];
        const unsigned short* bs = Bs[t & 1];
        short8 a[4], b[4];
        #pragma unroll
        for (int m = 0; m < 4; ++m)
            a[m] = *(const short8*)&as[(rA + m * 16) * 32 + s * 8];
        #pragma unroll
        for (int n = 0; n < 4; ++n)
            b[n] = *(const short8*)&bs[(rB + n * 16) * 32 + s * 8];
        #pragma unroll
        for (int m = 0; m < 4; ++m)
            #pragma unroll
            for (int n = 0; n < 4; ++n)
                acc[m][n] = __builtin_amdgcn_mfma_f32_16x16x32_bf16(
                    a[m], b[n], acc[m][n], 0, 0, 0);
    }
    #undef STAGE

    const int cRow0 = rowBase + wr * 64 + (lane >> 4) * 4;
    const int cCol0 = colBase + wc * 64 + (lane & 15);
    float cs[4] = {}, cq[4] = {};
    #pragma unroll
    for (int n = 0; n < 4; ++n) {
        const int col = cCol0 + n * 16;
        float bv = 0.0f;
        if (MODE != 2) {
            const float* bp = (col < 1024) ? b0 : (col < 2048) ? b1 : b2;
            bv = bp[col & 1023];
        }
        #pragma unroll
        for (int m = 0; m < 4; ++m)
            #pragma unroll
            for (int r = 0; r < 4; ++r) {
                const int row = cRow0 + m * 16 + r;
                float v = acc[m][n][r];
                if (MODE != 2) v = fmaxf(v + bv, 0.0f);
                if (MODE == 1) v += bf2f(resid[(size_t)row * N + col]);
                if (MODE != 0) { cs[n] += v; cq[n] += v * v; }
                Cout[(size_t)row * N + col] = f2bf(v);
            }
    }
    if (MODE != 0) {
        #pragma unroll
        for (int n = 0; n < 4; ++n) {
            cs[n] += __shfl_xor(cs[n], 16); cs[n] += __shfl_xor(cs[n], 32);
            cq[n] += __shfl_xor(cq[n], 16); cq[n] += __shfl_xor(cq[n], 32);
        }
        if (lane < 16) {
            #pragma unroll
            for (int n = 0; n < 4; ++n) {
                const int col = colBase + wc * 64 + lane + n * 16;
                atomicAdd(&accp[col], cs[n]);
                atomicAdd(&accp[D_MODEL + col], cq[n]);
            }
        }
    }
}

// ---------------------------------------------------------------------------
// weight prep: all 8 square matrices (2 layers x {Wq,Wk,Wv,Wc1}), one launch
// ---------------------------------------------------------------------------
__global__ __launch_bounds__(256)
void prep_weights_kernel(const float* __restrict__ Wq, const float* __restrict__ Wk,
                         const float* __restrict__ Wv, const float* __restrict__ Wc1,
                         unsigned short* __restrict__ Wtqkv,
                         unsigned short* __restrict__ Wtc1) {
    const int z = blockIdx.z;
    const int layer = z >> 2, typ = z & 3;
    const size_t wo = (size_t)layer * 1048576;
    const float* src;
    unsigned short* dst;
    if (typ == 0)      { src = Wq + wo;  dst = Wtqkv + layer * 3145728; }
    else if (typ == 1) { src = Wk + wo;  dst = Wtqkv + layer * 3145728 + 1048576; }
    else if (typ == 2) { src = Wv + wo;  dst = Wtqkv + layer * 3145728 + 2097152; }
    else               { src = Wc1 + wo; dst = Wtc1 + layer * 1048576; }
    __shared__ float T[64][65];
    const int tid = threadIdx.x;
    const int kBase = blockIdx.y * 64;
    const int nBase = blockIdx.x * 64;
    const int rr = tid >> 4;
    const int c4 = (tid & 15) * 4;
    #pragma unroll
    for (int i = 0; i < 4; ++i) {
        const int k = i * 16 + rr;
        const float4 v = *reinterpret_cast<const float4*>(
            &src[(size_t)(kBase + k) * 1024 + nBase + c4]);
        T[k][c4] = v.x; T[k][c4 + 1] = v.y; T[k][c4 + 2] = v.z; T[k][c4 + 3] = v.w;
    }
    __syncthreads();
    #pragma unroll
    for (int i = 0; i < 4; ++i) {
        const int n = i * 16 + rr;
        ushort4 o;
        o.x = f2bf(T[c4 + 0][n]); o.y = f2bf(T[c4 + 1][n]);
        o.z = f2bf(T[c4 + 2][n]); o.w = f2bf(T[c4 + 3][n]);
        *reinterpret_cast<ushort4*>(&dst[(size_t)(nBase + n) * 1024 + kBase + c4]) = o;
    }
}

// ---------------------------------------------------------------------------
// misc prep: x -> bf16 (blocks 0..127), W_embed^T -> bf16 (blocks 128..143),
// zero the 5 stat accumulators (block 144)
// ---------------------------------------------------------------------------
__global__ __launch_bounds__(256)
void prep_misc_kernel(const float* __restrict__ x, const float* __restrict__ Wemb,
                      unsigned short* __restrict__ xbf,
                      unsigned short* __restrict__ Wembt,
                      float* __restrict__ accum) {
    const int b = blockIdx.x;
    const int tid = threadIdx.x;
    if (b < 128) {
        const size_t base = (size_t)b * 2048 + tid * 8;
        const float4 v0 = *reinterpret_cast<const float4*>(&x[base]);
        const float4 v1 = *reinterpret_cast<const float4*>(&x[base + 4]);
        ushortx8 o;
        o[0] = f2bf(v0.x); o[1] = f2bf(v0.y); o[2] = f2bf(v0.z); o[3] = f2bf(v0.w);
        o[4] = f2bf(v1.x); o[5] = f2bf(v1.y); o[6] = f2bf(v1.z); o[7] = f2bf(v1.w);
        *reinterpret_cast<ushortx8*>(&xbf[base]) = o;
    } else if (b < 144) {
        __shared__ float T[64][65];
        const int nBase = (b - 128) * 64;
        const int rr = tid >> 4;
        const int c4 = (tid & 15) * 4;
        #pragma unroll
        for (int i = 0; i < 4; ++i) {
            const int k = i * 16 + rr;
            const float4 v = *reinterpret_cast<const float4*>(
                &Wemb[(size_t)k * 1024 + nBase + c4]);
            T[k][c4] = v.x; T[k][c4 + 1] = v.y; T[k][c4 + 2] = v.z; T[k][c4 + 3] = v.w;
        }
        __syncthreads();
        #pragma unroll
        for (int i = 0; i < 4; ++i) {
            const int n = i * 16 + rr;
            ushort4 o;
            o.x = f2bf(T[c4 + 0][n]); o.y = f2bf(T[c4 + 1][n]);
            o.z = f2bf(T[c4 + 2][n]); o.w = f2bf(T[c4 + 3][n]);
            *reinterpret_cast<ushort4*>(&Wembt[(size_t)(nBase + n) * 64 + c4]) = o;
        }
    } else {
        for (int j = tid; j < 5 * 2048; j += 256) accum[j] = 0.0f;
    }
}

// ---------------------------------------------------------------------------
// MFMA flash attention + fused residual + BN stats.
// S^T = mfma(K,Q) so q-row is lane-local; PV A-frag repacked lane-locally via
// v_cvt_pk_bf16_f32 under key permutation pi matched by the V LDS layout.
// ---------------------------------------------------------------------------
__global__ __launch_bounds__(256)
void attn_kernel(const unsigned short* __restrict__ QKV,
                 const unsigned short* __restrict__ Ebf,
                 unsigned short* __restrict__ Sbf,
                 float* __restrict__ accp) {
    __shared__ unsigned short Qs[128 * 64];
    __shared__ unsigned short Ks[2][64 * 64];
    __shared__ unsigned short Vt[2][64 * 72];

    const int tid = threadIdx.x;
    const int lane = tid & 63;
    const int w = tid >> 6;
    const int m = lane & 15;
    const int g = lane >> 4;
    const int l7 = lane & 7;
    const int qt = blockIdx.x, hh = blockIdx.y, bb = blockIdx.z;
    const int colB = hh * 64;
    const size_t rowQ = (size_t)bb * 512 + qt * 128;
    const size_t rowKV = (size_t)bb * 512;

    const int vk0 = (tid & 31) * 2;
    const int vcv = tid >> 5;

    #define STAGE_K(buf, kt) do {                                                  \
        const size_t kb_ = rowKV + (size_t)(kt) * 64;                              \
        _Pragma("unroll")                                                          \
        for (int i_ = 0; i_ < 2; ++i_) {                                           \
            const int c_ = w * 128 + i_ * 64 + lane;                               \
            const int r_ = c_ >> 3;                                                \
            const int gc_ = (c_ & 7) ^ (r_ & 7);                                   \
            __builtin_amdgcn_global_load_lds(                                      \
                (const __attribute__((address_space(1))) void*)                    \
                    (QKV + (kb_ + r_) * 3072 + 1024 + colB + gc_ * 8),             \
                (__attribute__((address_space(3))) void*)                          \
                    (&Ks[buf][(w * 128 + i_ * 64) * 8]), 16, 0, 0);                \
        }                                                                          \
    } while (0)

    #define LOAD_V(kt) do {                                                        \
        const size_t kb_ = rowKV + (size_t)(kt) * 64;                              \
        vst0 = *(const ushortx8*)(QKV + (kb_ + vk0) * 3072 + 2048 + colB + vcv * 8);\
        vst1 = *(const ushortx8*)(QKV + (kb_ + vk0 + 1) * 3072 + 2048 + colB + vcv * 8);\
    } while (0)

    #define WRITE_V(buf) do {                                                      \
        _Pragma("unroll")                                                          \
        for (int j_ = 0; j_ < 8; ++j_) {                                           \
            const int d_ = vcv * 8 + j_;                                           \
            unsigned int pk_ = (unsigned int)(unsigned short)vst0[j_] |            \
                               ((unsigned int)(unsigned short)vst1[j_] << 16);     \
            *(unsigned int*)&Vt[buf][d_ * 72 + vk0] = pk_;                         \
        }                                                                          \
    } while (0)

    ushortx8 vst0, vst1;

    #pragma unroll
    for (int i = 0; i < 4; ++i) {
        const int c = w * 256 + i * 64 + lane;
        const int r = c >> 3;
        const int gc = (c & 7) ^ (r & 7);
        __builtin_amdgcn_global_load_lds(
            (const __attribute__((address_space(1))) void*)
                (QKV + (rowQ + r) * 3072 + colB + gc * 8),
            (__attribute__((address_space(3))) void*)
                (&Qs[(w * 256 + i * 64) * 8]), 16, 0, 0);
    }
    STAGE_K(0, 0);
    LOAD_V(0);
    WRITE_V(0);
    __syncthreads();

    short8 qb[2][2];
    #pragma unroll
    for (int nf = 0; nf < 2; ++nf)
        #pragma unroll
        for (int ks = 0; ks < 2; ++ks)
            qb[nf][ks] = *(const short8*)&Qs[(w * 32 + 16 * nf + m) * 64 +
                                             ((g + 4 * ks) ^ l7) * 8];

    f32x4 o[2][4];
    #pragma unroll
    for (int nf = 0; nf < 2; ++nf)
        #pragma unroll
        for (int dn = 0; dn < 4; ++dn)
            o[nf][dn] = (f32x4){0.f, 0.f, 0.f, 0.f};
    float mr[2] = {-1e30f, -1e30f};
    float lsm[2] = {0.f, 0.f};

    for (int kt = 0; kt < 8; ++kt) {
        const int cur = kt & 1, nxt = cur ^ 1;
        if (kt < 7) { STAGE_K(nxt, kt + 1); LOAD_V(kt + 1); }

        f32x4 st[4][2];
        #pragma unroll
        for (int mf = 0; mf < 4; ++mf)
            #pragma unroll
            for (int nf = 0; nf < 2; ++nf)
                st[mf][nf] = (f32x4){0.f, 0.f, 0.f, 0.f};
        #pragma unroll
        for (int ks = 0; ks < 2; ++ks) {
            short8 a[4];
            #pragma unroll
            for (int mf = 0; mf < 4; ++mf)
                a[mf] = *(const short8*)&Ks[cur][(m + 16 * mf) * 64 +
                                                 ((g + 4 * ks) ^ l7) * 8];
            __builtin_amdgcn_s_setprio(1);
            #pragma unroll
            for (int mf = 0; mf < 4; ++mf)
                #pragma unroll
                for (int nf = 0; nf < 2; ++nf)
                    st[mf][nf] = __builtin_amdgcn_mfma_f32_16x16x32_bf16(
                        a[mf], qb[nf][ks], st[mf][nf], 0, 0, 0);
            __builtin_amdgcn_s_setprio(0);
        }

        // tree max over 16 regs, then cross-group shuffles
        float pmax[2];
        #pragma unroll
        for (int nf = 0; nf < 2; ++nf) {
            float a0 = fmaxf(fmaxf(st[0][nf][0], st[0][nf][1]),
                             fmaxf(st[0][nf][2], st[0][nf][3]));
            float a1 = fmaxf(fmaxf(st[1][nf][0], st[1][nf][1]),
                             fmaxf(st[1][nf][2], st[1][nf][3]));
            float a2 = fmaxf(fmaxf(st[2][nf][0], st[2][nf][1]),
                             fmaxf(st[2][nf][2], st[2][nf][3]));
            float a3 = fmaxf(fmaxf(st[3][nf][0], st[3][nf][1]),
                             fmaxf(st[3][nf][2], st[3][nf][3]));
            float mx = fmaxf(fmaxf(a0, a1), fmaxf(a2, a3));
            mx = fmaxf(mx, __shfl_xor(mx, 16));
            mx = fmaxf(mx, __shfl_xor(mx, 32));
            pmax[nf] = mx;
        }
        const int need = (pmax[0] - mr[0] > 64.f) || (pmax[1] - mr[1] > 64.f);
        if (__any(need)) {
            float al[2];
            #pragma unroll
            for (int nf = 0; nf < 2; ++nf) {
                const float mn = fmaxf(mr[nf], pmax[nf]);
                al[nf] = exp2f((mr[nf] - mn) * C_EXP2);
                lsm[nf] *= al[nf];
                mr[nf] = mn;
            }
            #pragma unroll
            for (int nf = 0; nf < 2; ++nf)
                #pragma unroll
                for (int r = 0; r < 4; ++r) {
                    const float av = __shfl(al[nf], 4 * g + r);
                    #pragma unroll
                    for (int dn = 0; dn < 4; ++dn)
                        o[nf][dn][r] *= av;
                }
        }

        float pf[2][4][4];
        #pragma unroll
        for (int nf = 0; nf < 2; ++nf) {
            const float mc = mr[nf] * C_EXP2;
            float s0 = 0.f, s1 = 0.f, s2 = 0.f, s3 = 0.f;
            #pragma unroll
            for (int mf = 0; mf < 4; ++mf) {
                float p0 = exp2f(fmaf(st[mf][nf][0], C_EXP2, -mc));
                float p1 = exp2f(fmaf(st[mf][nf][1], C_EXP2, -mc));
                float p2 = exp2f(fmaf(st[mf][nf][2], C_EXP2, -mc));
                float p3 = exp2f(fmaf(st[mf][nf][3], C_EXP2, -mc));
                pf[nf][mf][0] = p0; pf[nf][mf][1] = p1;
                pf[nf][mf][2] = p2; pf[nf][mf][3] = p3;
                s0 += p0; s1 += p1; s2 += p2; s3 += p3;
            }
            float ls = (s0 + s1) + (s2 + s3);
            ls += __shfl_xor(ls, 16);
            ls += __shfl_xor(ls, 32);
            lsm[nf] += ls;
        }

        if (kt < 7) WRITE_V(nxt);

        // pack P to bf16 A-frags: packed RNE convert (lane-local)
        short8 pb[2][2];
        #pragma unroll
        for (int nf = 0; nf < 2; ++nf)
            #pragma unroll
            for (int ks = 0; ks < 2; ++ks) {
                union { unsigned int u[4]; short8 s; } cv;
                cv.u[0] = cvt_pk_bf16(pf[nf][2 * ks][0], pf[nf][2 * ks][1]);
                cv.u[1] = cvt_pk_bf16(pf[nf][2 * ks][2], pf[nf][2 * ks][3]);
                cv.u[2] = cvt_pk_bf16(pf[nf][2 * ks + 1][0], pf[nf][2 * ks + 1][1]);
                cv.u[3] = cvt_pk_bf16(pf[nf][2 * ks + 1][2], pf[nf][2 * ks + 1][3]);
                pb[nf][ks] = cv.s;
            }

        #pragma unroll
        for (int ks = 0; ks < 2; ++ks) {
            short8 vb[4];
            #pragma unroll
            for (int dn = 0; dn < 4; ++dn) {
                const int d = m + 16 * dn;
                const short4v lo = *(const short4v*)&Vt[cur][d * 72 + 4 * g + 32 * ks];
                const short4v hi = *(const short4v*)&Vt[cur][d * 72 + 4 * g + 16 + 32 * ks];
                vb[dn] = __builtin_shufflevector(lo, hi, 0, 1, 2, 3, 4, 5, 6, 7);
            }
            __builtin_amdgcn_s_setprio(1);
            #pragma unroll
            for (int nf = 0; nf < 2; ++nf)
                #pragma unroll
                for (int dn = 0; dn < 4; ++dn)
                    o[nf][dn] = __builtin_amdgcn_mfma_f32_16x16x32_bf16(
                        pb[nf][ks], vb[dn], o[nf][dn], 0, 0, 0);
            __builtin_amdgcn_s_setprio(0);
        }
        __syncthreads();
    }

    // epilogue: O/l + residual -> Sbf (bf16) + channel stats
    float cs[4] = {}, cq[4] = {};
    #pragma unroll
    for (int nf = 0; nf < 2; ++nf) {
        const float inv = 1.0f / lsm[nf];
        #pragma unroll
        for (int r = 0; r < 4; ++r) {
            const float sc = __shfl(inv, 4 * g + r);
            const size_t row = rowQ + w * 32 + 16 * nf + 4 * g + r;
            #pragma unroll
            for (int dn = 0; dn < 4; ++dn) {
                const int ch = colB + 16 * dn + m;
                const float sv = o[nf][dn][r] * sc + bf2f(Ebf[row * D_MODEL + ch]);
                Sbf[row * D_MODEL + ch] = f2bf(sv);
                cs[dn] += sv; cq[dn] += sv * sv;
            }
        }
    }
    #pragma unroll
    for (int dn = 0; dn < 4; ++dn) {
        cs[dn] += __shfl_xor(cs[dn], 16); cs[dn] += __shfl_xor(cs[dn], 32);
        cq[dn] += __shfl_xor(cq[dn], 16); cq[dn] += __shfl_xor(cq[dn], 32);
    }
    if (lane < 16) {
        #pragma unroll
        for (int dn = 0; dn < 4; ++dn) {
            atomicAdd(&accp[colB + 16 * dn + lane], cs[dn]);
            atomicAdd(&accp[D_MODEL + colB + 16 * dn + lane], cq[dn]);
        }
    }
    #undef STAGE_K
    #undef LOAD_V
    #undef WRITE_V
}

// ---------------------------------------------------------------------------
// BN apply with inlined stats->coef (accum is L2-hot; redundant per-thread
// coef computation beats a separate 4-block kernel launch)
// ---------------------------------------------------------------------------
template<bool FINAL>
__global__ __launch_bounds__(256)
void bn_apply_kernel(const unsigned short* __restrict__ S,
                     const float* __restrict__ accum,
                     const float* __restrict__ gamma,
                     const float* __restrict__ beta,
                     unsigned short* __restrict__ Ebf,
                     float* __restrict__ outF) {
    const int idx = blockIdx.x * 256 + threadIdx.x;
    const int c8 = (idx & 127) << 3;
    const ushortx8 sv = *(const ushortx8*)&S[(size_t)idx * 8];
    const float4 s0 = *(const float4*)&accum[c8];
    const float4 s1 = *(const float4*)&accum[c8 + 4];
    const float4 q0 = *(const float4*)&accum[D_MODEL + c8];
    const float4 q1 = *(const float4*)&accum[D_MODEL + c8 + 4];
    const float4 g0 = *(const float4*)&gamma[c8];
    const float4 g1 = *(const float4*)&gamma[c8 + 4];
    const float4 t0 = *(const float4*)&beta[c8];
    const float4 t1 = *(const float4*)&beta[c8 + 4];
    const float ss[8] = {s0.x, s0.y, s0.z, s0.w, s1.x, s1.y, s1.z, s1.w};
    const float qq[8] = {q0.x, q0.y, q0.z, q0.w, q1.x, q1.y, q1.z, q1.w};
    const float gg[8] = {g0.x, g0.y, g0.z, g0.w, g1.x, g1.y, g1.z, g1.w};
    const float tt[8] = {t0.x, t0.y, t0.z, t0.w, t1.x, t1.y, t1.z, t1.w};
    float o[8];
    #pragma unroll
    for (int j = 0; j < 8; ++j) {
        const float mean = ss[j] * INV_N;
        const float var = qq[j] * INV_N - mean * mean;
        const float a = gg[j] * rsqrtf(var + BN_EPS);
        o[j] = fmaf(bf2f(sv[j]), a, tt[j] - mean * a);
    }
    if (FINAL) {
        *reinterpret_cast<float4*>(&outF[(size_t)idx * 8]) =
            make_float4(o[0], o[1], o[2], o[3]);
        *reinterpret_cast<float4*>(&outF[(size_t)idx * 8 + 4]) =
            make_float4(o[4], o[5], o[6], o[7]);
    } else {
        union { unsigned int u[4]; ushortx8 s; } cv;
        cv.u[0] = cvt_pk_bf16(o[0], o[1]);
        cv.u[1] = cvt_pk_bf16(o[2], o[3]);
        cv.u[2] = cvt_pk_bf16(o[4], o[5]);
        cv.u[3] = cvt_pk_bf16(o[6], o[7]);
        *reinterpret_cast<ushortx8*>(&Ebf[(size_t)idx * 8]) = cv.s;
    }
}

// ---------------------------------------------------------------------------
extern "C" void kernel_launch(void* const* d_in, const int* in_sizes, int n_in,
                              void* d_out, int out_size, void* d_ws, size_t ws_size,
                              hipStream_t stream) {
    const float* x       = (const float*)d_in[0];
    const float* W_embed = (const float*)d_in[1];
    const float* bn1_g   = (const float*)d_in[2];
    const float* bn1_b   = (const float*)d_in[3];
    const float* Wq      = (const float*)d_in[4];
    const float* bq      = (const float*)d_in[5];
    const float* Wk      = (const float*)d_in[6];
    const float* bk      = (const float*)d_in[7];
    const float* Wv      = (const float*)d_in[8];
    const float* bv      = (const float*)d_in[9];
    const float* bng     = (const float*)d_in[10];
    const float* bnb     = (const float*)d_in[11];
    const float* Wc1     = (const float*)d_in[12];
    const float* bc1     = (const float*)d_in[13];
    const float* bn2g    = (const float*)d_in[14];
    const float* bn2b    = (const float*)d_in[15];

    const size_t NBUF = (size_t)M_ROWS * D_MODEL;
    char* ws = (char*)d_ws;
    float* accum = (float*)ws;                                   // 5*2048 f
    unsigned short* xbf   = (unsigned short*)(accum + 5 * 2048); // 262144 us
    unsigned short* Wembt = xbf + 262144;                        // 65536 us
    unsigned short* Ebf   = Wembt + 65536;                       // 4M us
    unsigned short* Sbf   = Ebf + NBUF;                          // 4M us
    unsigned short* QKVbf = Sbf + NBUF;                          // 12M us
    unsigned short* F1bf  = QKVbf;                               // alias (QKV dead)
    unsigned short* Wtqkv = QKVbf + (size_t)M_ROWS * 3072;       // 2 x 3M us
    unsigned short* Wtc1  = Wtqkv + 2 * (size_t)3145728;         // 2 x 1M us
    float* outF = (float*)d_out;

    prep_misc_kernel<<<145, 256, 0, stream>>>(x, W_embed, xbf, Wembt, accum);
    prep_weights_kernel<<<dim3(16, 16, 8), 256, 0, stream>>>(Wq, Wk, Wv, Wc1,
                                                             Wtqkv, Wtc1);

    // embed (bf16 MFMA, K=64) + BN1
    gemm_bf16_kernel<2><<<dim3(8, 32), 256, 0, stream>>>(
        xbf, Wembt, nullptr, nullptr, nullptr, Sbf, nullptr, accum, 1024, 64);
    bn_apply_kernel<false><<<2048, 256, 0, stream>>>(Sbf, accum, bn1_g, bn1_b,
                                                     Ebf, nullptr);

    for (int i = 0; i < 2; ++i) {
        const size_t bo = (size_t)i * D_MODEL;
        float* accA = accum + (1 + 2 * i) * 2048;
        float* accF = accum + (2 + 2 * i) * 2048;
        const unsigned short* WtqkvL = Wtqkv + (size_t)i * 3145728;
        const unsigned short* Wtc1L  = Wtc1 + (size_t)i * 1048576;

        gemm_bf16_kernel<0><<<dim3(24, 32), 256, 0, stream>>>(
            Ebf, WtqkvL, bq + bo, bk + bo, bv + bo, QKVbf, nullptr, nullptr,
            3072, 1024);
        attn_kernel<<<dim3(4, 16, 8), 256, 0, stream>>>(QKVbf, Ebf, Sbf, accA);
        bn_apply_kernel<false><<<2048, 256, 0, stream>>>(Sbf, accA, bng + bo,
                                                         bnb + bo, Ebf, nullptr);

        gemm_bf16_kernel<0><<<dim3(8, 32), 256, 0, stream>>>(
            Ebf, Wtc1L, bc1 + bo, bc1 + bo, bc1 + bo, F1bf, nullptr, nullptr,
            1024, 1024);
        gemm_bf16_kernel<1><<<dim3(8, 32), 256, 0, stream>>>(
            F1bf, Wtc1L, bc1 + bo, bc1 + bo, bc1 + bo, Sbf, Ebf, accF,
            1024, 1024);
        if (i == 0)
            bn_apply_kernel<false><<<2048, 256, 0, stream>>>(Sbf, accF, bn2g + bo,
                                                             bn2b + bo, Ebf, nullptr);
        else
            bn_apply_kernel<true><<<2048, 256, 0, stream>>>(Sbf, accF, bn2g + bo,
                                                            bn2b + bo, nullptr, outF);
    }
}

// Round 11
// 275.204 us; speedup vs baseline: 6.5910x; 1.0009x over previous
//
#include <hip/hip_runtime.h>
#include <hip/hip_bf16.h>
#include <cstddef>

#define D_MODEL 1024
#define M_ROWS  4096
#define BN_EPS  1e-3f
#define C_EXP2  0.18033688011112042f   // 0.125 * log2(e)
#define INV_N   (1.0f / 4096.0f)

typedef __attribute__((ext_vector_type(8))) short short8;
typedef __attribute__((ext_vector_type(4))) short short4v;
typedef __attribute__((ext_vector_type(8))) unsigned short ushortx8;
typedef __attribute__((ext_vector_type(4))) float f32x4;

__device__ __forceinline__ unsigned short f2bf(float f) {
    __hip_bfloat16 h = __float2bfloat16(f);
    return *reinterpret_cast<unsigned short*>(&h);
}
__device__ __forceinline__ float bf2f(unsigned short u) {
    return __uint_as_float(((unsigned)u) << 16);
}
__device__ __forceinline__ unsigned int cvt_pk_bf16(float lo, float hi) {
    unsigned int r;
    asm volatile("v_cvt_pk_bf16_f32 %0, %1, %2" : "=v"(r) : "v"(lo), "v"(hi));
    return r;
}

// ---------------------------------------------------------------------------
// bf16 MFMA GEMM, 128x128 tile, BK=32, 4 waves, double-buffered global_load_lds.
// MODE 0: C = bf16(relu(A@Bt^T + bias))             (QKV, FFN1)
// MODE 1: S = relu(A@Bt^T + bias) + resid; bf16 + per-channel stats (FFN2)
// MODE 2: S = A@Bt^T (no bias/relu); bf16 + per-channel stats        (embed)
// bias selected from {b0,b1,b2} by col/1024 (QKV concat without extra kernel).
// ---------------------------------------------------------------------------
template<int MODE>
__global__ __launch_bounds__(256)
void gemm_bf16_kernel(const unsigned short* __restrict__ A,
                      const unsigned short* __restrict__ Bt,
                      const float* __restrict__ b0, const float* __restrict__ b1,
                      const float* __restrict__ b2,
                      unsigned short* __restrict__ Cout,
                      const unsigned short* __restrict__ resid,
                      float* __restrict__ accp, int N, int Kd) {
    __shared__ unsigned short As[2][128 * 32];
    __shared__ unsigned short Bs[2][128 * 32];
    const int tid = threadIdx.x;
    const int lane = tid & 63;
    const int w = tid >> 6;
    const int wr = w >> 1, wc = w & 1;
    const int rowBase = blockIdx.y * 128;
    const int colBase = blockIdx.x * 128;

    const int chunk0 = w * 64 + lane;
    const int r0 = chunk0 >> 2;
    const int c0 = (chunk0 & 3) ^ ((r0 >> 1) & 3);
    const int chunk1 = 256 + chunk0;
    const int r1 = chunk1 >> 2;
    const int c1 = (chunk1 & 3) ^ ((r1 >> 1) & 3);
    const size_t aOff0 = (size_t)(rowBase + r0) * Kd + c0 * 8;
    const size_t aOff1 = (size_t)(rowBase + r1) * Kd + c1 * 8;
    const size_t bOff0 = (size_t)(colBase + r0) * Kd + c0 * 8;
    const size_t bOff1 = (size_t)(colBase + r1) * Kd + c1 * 8;
    const int ldsOff0 = (w * 64) * 8;
    const int ldsOff1 = (256 + w * 64) * 8;

    f32x4 acc[4][4];
    #pragma unroll
    for (int m = 0; m < 4; ++m)
        #pragma unroll
        for (int n = 0; n < 4; ++n)
            acc[m][n] = (f32x4){0.f, 0.f, 0.f, 0.f};

    #define STAGE(buf, kt) do {                                                   \
        const int k0_ = (kt) << 5;                                                \
        __builtin_amdgcn_global_load_lds(                                         \
            (const __attribute__((address_space(1))) void*)(A + aOff0 + k0_),     \
            (__attribute__((address_space(3))) void*)(&As[buf][ldsOff0]), 16, 0, 0);\
        __builtin_amdgcn_global_load_lds(                                         \
            (const __attribute__((address_space(1))) void*)(A + aOff1 + k0_),     \
            (__attribute__((address_space(3))) void*)(&As[buf][ldsOff1]), 16, 0, 0);\
        __builtin_amdgcn_global_load_lds(                                         \
            (const __attribute__((address_space(1))) void*)(Bt + bOff0 + k0_),    \
            (__attribute__((address_space(3))) void*)(&Bs[buf][ldsOff0]), 16, 0, 0);\
        __builtin_amdgcn_global_load_lds(                                         \
            (const __attribute__((address_space(1))) void*)(Bt + bOff1 + k0_),    \
            (__attribute__((address_space(3))) void*)(&Bs[buf][ldsOff1]), 16, 0, 0);\
    } while (0)

    const int NT = Kd >> 5;
    STAGE(0, 0);

    const int kb = lane >> 4;
    const int s = kb ^ ((lane >> 1) & 3);
    const int rA = wr * 64 + (lane & 15);
    const int rB = wc * 64 + (lane & 15);

    for (int t = 0; t < NT; ++t) {
        __syncthreads();
        if (t + 1 < NT) STAGE((t + 1) & 1, t + 1);
        const unsigned short* as = As[t & 1];
        const unsigned short* bs = Bs[t & 1];
        short8 a[4], b[4];
        #pragma unroll
        for (int m = 0; m < 4; ++m)
            a[m] = *(const short8*)&as[(rA + m * 16) * 32 + s * 8];
        #pragma unroll
        for (int n = 0; n < 4; ++n)
            b[n] = *(const short8*)&bs[(rB + n * 16) * 32 + s * 8];
        #pragma unroll
        for (int m = 0; m < 4; ++m)
            #pragma unroll
            for (int n = 0; n < 4; ++n)
                acc[m][n] = __builtin_amdgcn_mfma_f32_16x16x32_bf16(
                    a[m], b[n], acc[m][n], 0, 0, 0);
    }
    #undef STAGE

    const int cRow0 = rowBase + wr * 64 + (lane >> 4) * 4;
    const int cCol0 = colBase + wc * 64 + (lane & 15);
    float cs[4] = {}, cq[4] = {};
    #pragma unroll
    for (int n = 0; n < 4; ++n) {
        const int col = cCol0 + n * 16;
        float bv = 0.0f;
        if (MODE != 2) {
            const float* bp = (col < 1024) ? b0 : (col < 2048) ? b1 : b2;
            bv = bp[col & 1023];
        }
        #pragma unroll
        for (int m = 0; m < 4; ++m)
            #pragma unroll
            for (int r = 0; r < 4; ++r) {
                const int row = cRow0 + m * 16 + r;
                float v = acc[m][n][r];
                if (MODE != 2) v = fmaxf(v + bv, 0.0f);
                if (MODE == 1) v += bf2f(resid[(size_t)row * N + col]);
                if (MODE != 0) { cs[n] += v; cq[n] += v * v; }
                Cout[(size_t)row * N + col] = f2bf(v);
            }
    }
    if (MODE != 0) {
        #pragma unroll
        for (int n = 0; n < 4; ++n) {
            cs[n] += __shfl_xor(cs[n], 16); cs[n] += __shfl_xor(cs[n], 32);
            cq[n] += __shfl_xor(cq[n], 16); cq[n] += __shfl_xor(cq[n], 32);
        }
        if (lane < 16) {
            #pragma unroll
            for (int n = 0; n < 4; ++n) {
                const int col = colBase + wc * 64 + lane + n * 16;
                atomicAdd(&accp[col], cs[n]);
                atomicAdd(&accp[D_MODEL + col], cq[n]);
            }
        }
    }
}

// ---------------------------------------------------------------------------
// weight prep: all 8 square matrices (2 layers x {Wq,Wk,Wv,Wc1}), one launch
// ---------------------------------------------------------------------------
__global__ __launch_bounds__(256)
void prep_weights_kernel(const float* __restrict__ Wq, const float* __restrict__ Wk,
                         const float* __restrict__ Wv, const float* __restrict__ Wc1,
                         unsigned short* __restrict__ Wtqkv,
                         unsigned short* __restrict__ Wtc1) {
    const int z = blockIdx.z;
    const int layer = z >> 2, typ = z & 3;
    const size_t wo = (size_t)layer * 1048576;
    const float* src;
    unsigned short* dst;
    if (typ == 0)      { src = Wq + wo;  dst = Wtqkv + layer * 3145728; }
    else if (typ == 1) { src = Wk + wo;  dst = Wtqkv + layer * 3145728 + 1048576; }
    else if (typ == 2) { src = Wv + wo;  dst = Wtqkv + layer * 3145728 + 2097152; }
    else               { src = Wc1 + wo; dst = Wtc1 + layer * 1048576; }
    __shared__ float T[64][65];
    const int tid = threadIdx.x;
    const int kBase = blockIdx.y * 64;
    const int nBase = blockIdx.x * 64;
    const int rr = tid >> 4;
    const int c4 = (tid & 15) * 4;
    #pragma unroll
    for (int i = 0; i < 4; ++i) {
        const int k = i * 16 + rr;
        const float4 v = *reinterpret_cast<const float4*>(
            &src[(size_t)(kBase + k) * 1024 + nBase + c4]);
        T[k][c4] = v.x; T[k][c4 + 1] = v.y; T[k][c4 + 2] = v.z; T[k][c4 + 3] = v.w;
    }
    __syncthreads();
    #pragma unroll
    for (int i = 0; i < 4; ++i) {
        const int n = i * 16 + rr;
        ushort4 o;
        o.x = f2bf(T[c4 + 0][n]); o.y = f2bf(T[c4 + 1][n]);
        o.z = f2bf(T[c4 + 2][n]); o.w = f2bf(T[c4 + 3][n]);
        *reinterpret_cast<ushort4*>(&dst[(size_t)(nBase + n) * 1024 + kBase + c4]) = o;
    }
}

// ---------------------------------------------------------------------------
// misc prep: x -> bf16 (blocks 0..127), W_embed^T -> bf16 (blocks 128..143),
// zero the 5 stat accumulators (block 144)
// ---------------------------------------------------------------------------
__global__ __launch_bounds__(256)
void prep_misc_kernel(const float* __restrict__ x, const float* __restrict__ Wemb,
                      unsigned short* __restrict__ xbf,
                      unsigned short* __restrict__ Wembt,
                      float* __restrict__ accum) {
    const int b = blockIdx.x;
    const int tid = threadIdx.x;
    if (b < 128) {
        const size_t base = (size_t)b * 2048 + tid * 8;
        const float4 v0 = *reinterpret_cast<const float4*>(&x[base]);
        const float4 v1 = *reinterpret_cast<const float4*>(&x[base + 4]);
        ushortx8 o;
        o[0] = f2bf(v0.x); o[1] = f2bf(v0.y); o[2] = f2bf(v0.z); o[3] = f2bf(v0.w);
        o[4] = f2bf(v1.x); o[5] = f2bf(v1.y); o[6] = f2bf(v1.z); o[7] = f2bf(v1.w);
        *reinterpret_cast<ushortx8*>(&xbf[base]) = o;
    } else if (b < 144) {
        __shared__ float T[64][65];
        const int nBase = (b - 128) * 64;
        const int rr = tid >> 4;
        const int c4 = (tid & 15) * 4;
        #pragma unroll
        for (int i = 0; i < 4; ++i) {
            const int k = i * 16 + rr;
            const float4 v = *reinterpret_cast<const float4*>(
                &Wemb[(size_t)k * 1024 + nBase + c4]);
            T[k][c4] = v.x; T[k][c4 + 1] = v.y; T[k][c4 + 2] = v.z; T[k][c4 + 3] = v.w;
        }
        __syncthreads();
        #pragma unroll
        for (int i = 0; i < 4; ++i) {
            const int n = i * 16 + rr;
            ushort4 o;
            o.x = f2bf(T[c4 + 0][n]); o.y = f2bf(T[c4 + 1][n]);
            o.z = f2bf(T[c4 + 2][n]); o.w = f2bf(T[c4 + 3][n]);
            *reinterpret_cast<ushort4*>(&Wembt[(size_t)(nBase + n) * 64 + c4]) = o;
        }
    } else {
        for (int j = tid; j < 5 * 2048; j += 256) accum[j] = 0.0f;
    }
}

// ---------------------------------------------------------------------------
// MFMA flash attention + fused residual + BN stats.
// S^T = mfma(K,Q) so q-row is lane-local; PV A-frag repacked lane-locally via
// v_cvt_pk_bf16_f32 under key permutation pi matched by the V LDS layout.
// ---------------------------------------------------------------------------
__global__ __launch_bounds__(256)
void attn_kernel(const unsigned short* __restrict__ QKV,
                 const unsigned short* __restrict__ Ebf,
                 unsigned short* __restrict__ Sbf,
                 float* __restrict__ accp) {
    __shared__ unsigned short Qs[128 * 64];
    __shared__ unsigned short Ks[2][64 * 64];
    __shared__ unsigned short Vt[2][64 * 72];

    const int tid = threadIdx.x;
    const int lane = tid & 63;
    const int w = tid >> 6;
    const int m = lane & 15;
    const int g = lane >> 4;
    const int l7 = lane & 7;
    const int qt = blockIdx.x, hh = blockIdx.y, bb = blockIdx.z;
    const int colB = hh * 64;
    const size_t rowQ = (size_t)bb * 512 + qt * 128;
    const size_t rowKV = (size_t)bb * 512;

    const int vk0 = (tid & 31) * 2;
    const int vcv = tid >> 5;

    #define STAGE_K(buf, kt) do {                                                  \
        const size_t kb_ = rowKV + (size_t)(kt) * 64;                              \
        _Pragma("unroll")                                                          \
        for (int i_ = 0; i_ < 2; ++i_) {                                           \
            const int c_ = w * 128 + i_ * 64 + lane;                               \
            const int r_ = c_ >> 3;                                                \
            const int gc_ = (c_ & 7) ^ (r_ & 7);                                   \
            __builtin_amdgcn_global_load_lds(                                      \
                (const __attribute__((address_space(1))) void*)                    \
                    (QKV + (kb_ + r_) * 3072 + 1024 + colB + gc_ * 8),             \
                (__attribute__((address_space(3))) void*)                          \
                    (&Ks[buf][(w * 128 + i_ * 64) * 8]), 16, 0, 0);                \
        }                                                                          \
    } while (0)

    #define LOAD_V(kt) do {                                                        \
        const size_t kb_ = rowKV + (size_t)(kt) * 64;                              \
        vst0 = *(const ushortx8*)(QKV + (kb_ + vk0) * 3072 + 2048 + colB + vcv * 8);\
        vst1 = *(const ushortx8*)(QKV + (kb_ + vk0 + 1) * 3072 + 2048 + colB + vcv * 8);\
    } while (0)

    #define WRITE_V(buf) do {                                                      \
        _Pragma("unroll")                                                          \
        for (int j_ = 0; j_ < 8; ++j_) {                                           \
            const int d_ = vcv * 8 + j_;                                           \
            unsigned int pk_ = (unsigned int)(unsigned short)vst0[j_] |            \
                               ((unsigned int)(unsigned short)vst1[j_] << 16);     \
            *(unsigned int*)&Vt[buf][d_ * 72 + vk0] = pk_;                         \
        }                                                                          \
    } while (0)

    ushortx8 vst0, vst1;

    #pragma unroll
    for (int i = 0; i < 4; ++i) {
        const int c = w * 256 + i * 64 + lane;
        const int r = c >> 3;
        const int gc = (c & 7) ^ (r & 7);
        __builtin_amdgcn_global_load_lds(
            (const __attribute__((address_space(1))) void*)
                (QKV + (rowQ + r) * 3072 + colB + gc * 8),
            (__attribute__((address_space(3))) void*)
                (&Qs[(w * 256 + i * 64) * 8]), 16, 0, 0);
    }
    STAGE_K(0, 0);
    LOAD_V(0);
    WRITE_V(0);
    __syncthreads();

    short8 qb[2][2];
    #pragma unroll
    for (int nf = 0; nf < 2; ++nf)
        #pragma unroll
        for (int ks = 0; ks < 2; ++ks)
            qb[nf][ks] = *(const short8*)&Qs[(w * 32 + 16 * nf + m) * 64 +
                                             ((g + 4 * ks) ^ l7) * 8];

    f32x4 o[2][4];
    #pragma unroll
    for (int nf = 0; nf < 2; ++nf)
        #pragma unroll
        for (int dn = 0; dn < 4; ++dn)
            o[nf][dn] = (f32x4){0.f, 0.f, 0.f, 0.f};
    float mr[2] = {-1e30f, -1e30f};
    float lsm[2] = {0.f, 0.f};

    for (int kt = 0; kt < 8; ++kt) {
        const int cur = kt & 1, nxt = cur ^ 1;
        if (kt < 7) { STAGE_K(nxt, kt + 1); LOAD_V(kt + 1); }

        f32x4 st[4][2];
        #pragma unroll
        for (int mf = 0; mf < 4; ++mf)
            #pragma unroll
            for (int nf = 0; nf < 2; ++nf)
                st[mf][nf] = (f32x4){0.f, 0.f, 0.f, 0.f};
        #pragma unroll
        for (int ks = 0; ks < 2; ++ks) {
            short8 a[4];
            #pragma unroll
            for (int mf = 0; mf < 4; ++mf)
                a[mf] = *(const short8*)&Ks[cur][(m + 16 * mf) * 64 +
                                                 ((g + 4 * ks) ^ l7) * 8];
            __builtin_amdgcn_s_setprio(1);
            #pragma unroll
            for (int mf = 0; mf < 4; ++mf)
                #pragma unroll
                for (int nf = 0; nf < 2; ++nf)
                    st[mf][nf] = __builtin_amdgcn_mfma_f32_16x16x32_bf16(
                        a[mf], qb[nf][ks], st[mf][nf], 0, 0, 0);
            __builtin_amdgcn_s_setprio(0);
        }

        // tree max over 16 regs, then cross-group shuffles
        float pmax[2];
        #pragma unroll
        for (int nf = 0; nf < 2; ++nf) {
            float a0 = fmaxf(fmaxf(st[0][nf][0], st[0][nf][1]),
                             fmaxf(st[0][nf][2], st[0][nf][3]));
            float a1 = fmaxf(fmaxf(st[1][nf][0], st[1][nf][1]),
                             fmaxf(st[1][nf][2], st[1][nf][3]));
            float a2 = fmaxf(fmaxf(st[2][nf][0], st[2][nf][1]),
                             fmaxf(st[2][nf][2], st[2][nf][3]));
            float a3 = fmaxf(fmaxf(st[3][nf][0], st[3][nf][1]),
                             fmaxf(st[3][nf][2], st[3][nf][3]));
            float mx = fmaxf(fmaxf(a0, a1), fmaxf(a2, a3));
            mx = fmaxf(mx, __shfl_xor(mx, 16));
            mx = fmaxf(mx, __shfl_xor(mx, 32));
            pmax[nf] = mx;
        }
        const int need = (pmax[0] - mr[0] > 64.f) || (pmax[1] - mr[1] > 64.f);
        if (__any(need)) {
            float al[2];
            #pragma unroll
            for (int nf = 0; nf < 2; ++nf) {
                const float mn = fmaxf(mr[nf], pmax[nf]);
                al[nf] = exp2f((mr[nf] - mn) * C_EXP2);
                lsm[nf] *= al[nf];
                mr[nf] = mn;
            }
            #pragma unroll
            for (int nf = 0; nf < 2; ++nf)
                #pragma unroll
                for (int r = 0; r < 4; ++r) {
                    const float av = __shfl(al[nf], 4 * g + r);
                    #pragma unroll
                    for (int dn = 0; dn < 4; ++dn)
                        o[nf][dn][r] *= av;
                }
        }

        float pf[2][4][4];
        #pragma unroll
        for (int nf = 0; nf < 2; ++nf) {
            const float mc = mr[nf] * C_EXP2;
            float s0 = 0.f, s1 = 0.f, s2 = 0.f, s3 = 0.f;
            #pragma unroll
            for (int mf = 0; mf < 4; ++mf) {
                float p0 = exp2f(fmaf(st[mf][nf][0], C_EXP2, -mc));
                float p1 = exp2f(fmaf(st[mf][nf][1], C_EXP2, -mc));
                float p2 = exp2f(fmaf(st[mf][nf][2], C_EXP2, -mc));
                float p3 = exp2f(fmaf(st[mf][nf][3], C_EXP2, -mc));
                pf[nf][mf][0] = p0; pf[nf][mf][1] = p1;
                pf[nf][mf][2] = p2; pf[nf][mf][3] = p3;
                s0 += p0; s1 += p1; s2 += p2; s3 += p3;
            }
            float ls = (s0 + s1) + (s2 + s3);
            ls += __shfl_xor(ls, 16);
            ls += __shfl_xor(ls, 32);
            lsm[nf] += ls;
        }

        if (kt < 7) WRITE_V(nxt);

        // pack P to bf16 A-frags: packed RNE convert (lane-local)
        short8 pb[2][2];
        #pragma unroll
        for (int nf = 0; nf < 2; ++nf)
            #pragma unroll
            for (int ks = 0; ks < 2; ++ks) {
                union { unsigned int u[4]; short8 s; } cv;
                cv.u[0] = cvt_pk_bf16(pf[nf][2 * ks][0], pf[nf][2 * ks][1]);
                cv.u[1] = cvt_pk_bf16(pf[nf][2 * ks][2], pf[nf][2 * ks][3]);
                cv.u[2] = cvt_pk_bf16(pf[nf][2 * ks + 1][0], pf[nf][2 * ks + 1][1]);
                cv.u[3] = cvt_pk_bf16(pf[nf][2 * ks + 1][2], pf[nf][2 * ks + 1][3]);
                pb[nf][ks] = cv.s;
            }

        #pragma unroll
        for (int ks = 0; ks < 2; ++ks) {
            short8 vb[4];
            #pragma unroll
            for (int dn = 0; dn < 4; ++dn) {
                const int d = m + 16 * dn;
                const short4v lo = *(const short4v*)&Vt[cur][d * 72 + 4 * g + 32 * ks];
                const short4v hi = *(const short4v*)&Vt[cur][d * 72 + 4 * g + 16 + 32 * ks];
                vb[dn] = __builtin_shufflevector(lo, hi, 0, 1, 2, 3, 4, 5, 6, 7);
            }
            __builtin_amdgcn_s_setprio(1);
            #pragma unroll
            for (int nf = 0; nf < 2; ++nf)
                #pragma unroll
                for (int dn = 0; dn < 4; ++dn)
                    o[nf][dn] = __builtin_amdgcn_mfma_f32_16x16x32_bf16(
                        pb[nf][ks], vb[dn], o[nf][dn], 0, 0, 0);
            __builtin_amdgcn_s_setprio(0);
        }
        __syncthreads();
    }

    // epilogue: O/l + residual -> Sbf (bf16) + channel stats
    float cs[4] = {}, cq[4] = {};
    #pragma unroll
    for (int nf = 0; nf < 2; ++nf) {
        const float inv = 1.0f / lsm[nf];
        #pragma unroll
        for (int r = 0; r < 4; ++r) {
            const float sc = __shfl(inv, 4 * g + r);
            const size_t row = rowQ + w * 32 + 16 * nf + 4 * g + r;
            #pragma unroll
            for (int dn = 0; dn < 4; ++dn) {
                const int ch = colB + 16 * dn + m;
                const float sv = o[nf][dn][r] * sc + bf2f(Ebf[row * D_MODEL + ch]);
                Sbf[row * D_MODEL + ch] = f2bf(sv);
                cs[dn] += sv; cq[dn] += sv * sv;
            }
        }
    }
    #pragma unroll
    for (int dn = 0; dn < 4; ++dn) {
        cs[dn] += __shfl_xor(cs[dn], 16); cs[dn] += __shfl_xor(cs[dn], 32);
        cq[dn] += __shfl_xor(cq[dn], 16); cq[dn] += __shfl_xor(cq[dn], 32);
    }
    if (lane < 16) {
        #pragma unroll
        for (int dn = 0; dn < 4; ++dn) {
            atomicAdd(&accp[colB + 16 * dn + lane], cs[dn]);
            atomicAdd(&accp[D_MODEL + colB + 16 * dn + lane], cq[dn]);
        }
    }
    #undef STAGE_K
    #undef LOAD_V
    #undef WRITE_V
}

// ---------------------------------------------------------------------------
// BN apply with inlined stats->coef (accum is L2-hot; redundant per-thread
// coef computation beats a separate 4-block kernel launch)
// ---------------------------------------------------------------------------
template<bool FINAL>
__global__ __launch_bounds__(256)
void bn_apply_kernel(const unsigned short* __restrict__ S,
                     const float* __restrict__ accum,
                     const float* __restrict__ gamma,
                     const float* __restrict__ beta,
                     unsigned short* __restrict__ Ebf,
                     float* __restrict__ outF) {
    const int idx = blockIdx.x * 256 + threadIdx.x;
    const int c8 = (idx & 127) << 3;
    const ushortx8 sv = *(const ushortx8*)&S[(size_t)idx * 8];
    const float4 s0 = *(const float4*)&accum[c8];
    const float4 s1 = *(const float4*)&accum[c8 + 4];
    const float4 q0 = *(const float4*)&accum[D_MODEL + c8];
    const float4 q1 = *(const float4*)&accum[D_MODEL + c8 + 4];
    const float4 g0 = *(const float4*)&gamma[c8];
    const float4 g1 = *(const float4*)&gamma[c8 + 4];
    const float4 t0 = *(const float4*)&beta[c8];
    const float4 t1 = *(const float4*)&beta[c8 + 4];
    const float ss[8] = {s0.x, s0.y, s0.z, s0.w, s1.x, s1.y, s1.z, s1.w};
    const float qq[8] = {q0.x, q0.y, q0.z, q0.w, q1.x, q1.y, q1.z, q1.w};
    const float gg[8] = {g0.x, g0.y, g0.z, g0.w, g1.x, g1.y, g1.z, g1.w};
    const float tt[8] = {t0.x, t0.y, t0.z, t0.w, t1.x, t1.y, t1.z, t1.w};
    float o[8];
    #pragma unroll
    for (int j = 0; j < 8; ++j) {
        const float mean = ss[j] * INV_N;
        const float var = qq[j] * INV_N - mean * mean;
        const float a = gg[j] * rsqrtf(var + BN_EPS);
        o[j] = fmaf(bf2f(sv[j]), a, tt[j] - mean * a);
    }
    if (FINAL) {
        *reinterpret_cast<float4*>(&outF[(size_t)idx * 8]) =
            make_float4(o[0], o[1], o[2], o[3]);
        *reinterpret_cast<float4*>(&outF[(size_t)idx * 8 + 4]) =
            make_float4(o[4], o[5], o[6], o[7]);
    } else {
        union { unsigned int u[4]; ushortx8 s; } cv;
        cv.u[0] = cvt_pk_bf16(o[0], o[1]);
        cv.u[1] = cvt_pk_bf16(o[2], o[3]);
        cv.u[2] = cvt_pk_bf16(o[4], o[5]);
        cv.u[3] = cvt_pk_bf16(o[6], o[7]);
        *reinterpret_cast<ushortx8*>(&Ebf[(size_t)idx * 8]) = cv.s;
    }
}

// ---------------------------------------------------------------------------
extern "C" void kernel_launch(void* const* d_in, const int* in_sizes, int n_in,
                              void* d_out, int out_size, void* d_ws, size_t ws_size,
                              hipStream_t stream) {
    const float* x       = (const float*)d_in[0];
    const float* W_embed = (const float*)d_in[1];
    const float* bn1_g   = (const float*)d_in[2];
    const float* bn1_b   = (const float*)d_in[3];
    const float* Wq      = (const float*)d_in[4];
    const float* bq      = (const float*)d_in[5];
    const float* Wk      = (const float*)d_in[6];
    const float* bk      = (const float*)d_in[7];
    const float* Wv      = (const float*)d_in[8];
    const float* bv      = (const float*)d_in[9];
    const float* bng     = (const float*)d_in[10];
    const float* bnb     = (const float*)d_in[11];
    const float* Wc1     = (const float*)d_in[12];
    const float* bc1     = (const float*)d_in[13];
    const float* bn2g    = (const float*)d_in[14];
    const float* bn2b    = (const float*)d_in[15];

    const size_t NBUF = (size_t)M_ROWS * D_MODEL;
    char* ws = (char*)d_ws;
    float* accum = (float*)ws;                                   // 5*2048 f
    unsigned short* xbf   = (unsigned short*)(accum + 5 * 2048); // 262144 us
    unsigned short* Wembt = xbf + 262144;                        // 65536 us
    unsigned short* Ebf   = Wembt + 65536;                       // 4M us
    unsigned short* Sbf   = Ebf + NBUF;                          // 4M us
    unsigned short* QKVbf = Sbf + NBUF;                          // 12M us
    unsigned short* F1bf  = QKVbf;                               // alias (QKV dead)
    unsigned short* Wtqkv = QKVbf + (size_t)M_ROWS * 3072;       // 2 x 3M us
    unsigned short* Wtc1  = Wtqkv + 2 * (size_t)3145728;         // 2 x 1M us
    float* outF = (float*)d_out;

    prep_misc_kernel<<<145, 256, 0, stream>>>(x, W_embed, xbf, Wembt, accum);
    prep_weights_kernel<<<dim3(16, 16, 8), 256, 0, stream>>>(Wq, Wk, Wv, Wc1,
                                                             Wtqkv, Wtc1);

    // embed (bf16 MFMA, K=64) + BN1
    gemm_bf16_kernel<2><<<dim3(8, 32), 256, 0, stream>>>(
        xbf, Wembt, nullptr, nullptr, nullptr, Sbf, nullptr, accum, 1024, 64);
    bn_apply_kernel<false><<<2048, 256, 0, stream>>>(Sbf, accum, bn1_g, bn1_b,
                                                     Ebf, nullptr);

    for (int i = 0; i < 2; ++i) {
        const size_t bo = (size_t)i * D_MODEL;
        float* accA = accum + (1 + 2 * i) * 2048;
        float* accF = accum + (2 + 2 * i) * 2048;
        const unsigned short* WtqkvL = Wtqkv + (size_t)i * 3145728;
        const unsigned short* Wtc1L  = Wtc1 + (size_t)i * 1048576;

        gemm_bf16_kernel<0><<<dim3(24, 32), 256, 0, stream>>>(
            Ebf, WtqkvL, bq + bo, bk + bo, bv + bo, QKVbf, nullptr, nullptr,
            3072, 1024);
        attn_kernel<<<dim3(4, 16, 8), 256, 0, stream>>>(QKVbf, Ebf, Sbf, accA);
        bn_apply_kernel<false><<<2048, 256, 0, stream>>>(Sbf, accA, bng + bo,
                                                         bnb + bo, Ebf, nullptr);

        gemm_bf16_kernel<0><<<dim3(8, 32), 256, 0, stream>>>(
            Ebf, Wtc1L, bc1 + bo, bc1 + bo, bc1 + bo, F1bf, nullptr, nullptr,
            1024, 1024);
        gemm_bf16_kernel<1><<<dim3(8, 32), 256, 0, stream>>>(
            F1bf, Wtc1L, bc1 + bo, bc1 + bo, bc1 + bo, Sbf, Ebf, accF,
            1024, 1024);
        if (i == 0)
            bn_apply_kernel<false><<<2048, 256, 0, stream>>>(Sbf, accF, bn2g + bo,
                                                             bn2b + bo, Ebf, nullptr);
        else
            bn_apply_kernel<true><<<2048, 256, 0, stream>>>(Sbf, accF, bn2g + bo,
                                                            bn2b + bo, nullptr, outF);
    }
}

// Round 12
// 260.485 us; speedup vs baseline: 6.9635x; 1.0565x over previous
//
#include <hip/hip_runtime.h>
#include <hip/hip_bf16.h>
#include <cstddef>

#define D_MODEL 1024
#define M_ROWS  4096
#define BN_EPS  1e-3f
#define C_EXP2  0.18033688011112042f   // 0.125 * log2(e)
#define INV_N   (1.0f / 4096.0f)

typedef __attribute__((ext_vector_type(8))) short short8;
typedef __attribute__((ext_vector_type(4))) short short4v;
typedef __attribute__((ext_vector_type(8))) unsigned short ushortx8;
typedef __attribute__((ext_vector_type(4))) float f32x4;

__device__ __forceinline__ unsigned short f2bf(float f) {
    __hip_bfloat16 h = __float2bfloat16(f);
    return *reinterpret_cast<unsigned short*>(&h);
}
__device__ __forceinline__ float bf2f(unsigned short u) {
    return __uint_as_float(((unsigned)u) << 16);
}
__device__ __forceinline__ unsigned int cvt_pk_bf16(float lo, float hi) {
    unsigned int r;
    asm volatile("v_cvt_pk_bf16_f32 %0, %1, %2" : "=v"(r) : "v"(lo), "v"(hi));
    return r;
}

// ---------------------------------------------------------------------------
// bf16 MFMA GEMM, 128x128 tile, BK=32, 4 waves (used for QKV: 768 blocks).
// MODE 0: C = bf16(relu(A@Bt^T + bias)); bias from {b0,b1,b2} by col/1024.
// ---------------------------------------------------------------------------
template<int MODE>
__global__ __launch_bounds__(256)
void gemm_bf16_kernel(const unsigned short* __restrict__ A,
                      const unsigned short* __restrict__ Bt,
                      const float* __restrict__ b0, const float* __restrict__ b1,
                      const float* __restrict__ b2,
                      unsigned short* __restrict__ Cout,
                      const unsigned short* __restrict__ resid,
                      float* __restrict__ accp, int N, int Kd) {
    __shared__ unsigned short As[2][128 * 32];
    __shared__ unsigned short Bs[2][128 * 32];
    const int tid = threadIdx.x;
    const int lane = tid & 63;
    const int w = tid >> 6;
    const int wr = w >> 1, wc = w & 1;
    const int rowBase = blockIdx.y * 128;
    const int colBase = blockIdx.x * 128;

    const int chunk0 = w * 64 + lane;
    const int r0 = chunk0 >> 2;
    const int c0 = (chunk0 & 3) ^ ((r0 >> 1) & 3);
    const int chunk1 = 256 + chunk0;
    const int r1 = chunk1 >> 2;
    const int c1 = (chunk1 & 3) ^ ((r1 >> 1) & 3);
    const size_t aOff0 = (size_t)(rowBase + r0) * Kd + c0 * 8;
    const size_t aOff1 = (size_t)(rowBase + r1) * Kd + c1 * 8;
    const size_t bOff0 = (size_t)(colBase + r0) * Kd + c0 * 8;
    const size_t bOff1 = (size_t)(colBase + r1) * Kd + c1 * 8;
    const int ldsOff0 = (w * 64) * 8;
    const int ldsOff1 = (256 + w * 64) * 8;

    f32x4 acc[4][4];
    #pragma unroll
    for (int m = 0; m < 4; ++m)
        #pragma unroll
        for (int n = 0; n < 4; ++n)
            acc[m][n] = (f32x4){0.f, 0.f, 0.f, 0.f};

    #define STAGE(buf, kt) do {                                                   \
        const int k0_ = (kt) << 5;                                                \
        __builtin_amdgcn_global_load_lds(                                         \
            (const __attribute__((address_space(1))) void*)(A + aOff0 + k0_),     \
            (__attribute__((address_space(3))) void*)(&As[buf][ldsOff0]), 16, 0, 0);\
        __builtin_amdgcn_global_load_lds(                                         \
            (const __attribute__((address_space(1))) void*)(A + aOff1 + k0_),     \
            (__attribute__((address_space(3))) void*)(&As[buf][ldsOff1]), 16, 0, 0);\
        __builtin_amdgcn_global_load_lds(                                         \
            (const __attribute__((address_space(1))) void*)(Bt + bOff0 + k0_),    \
            (__attribute__((address_space(3))) void*)(&Bs[buf][ldsOff0]), 16, 0, 0);\
        __builtin_amdgcn_global_load_lds(                                         \
            (const __attribute__((address_space(1))) void*)(Bt + bOff1 + k0_),    \
            (__attribute__((address_space(3))) void*)(&Bs[buf][ldsOff1]), 16, 0, 0);\
    } while (0)

    const int NT = Kd >> 5;
    STAGE(0, 0);

    const int kb = lane >> 4;
    const int s = kb ^ ((lane >> 1) & 3);
    const int rA = wr * 64 + (lane & 15);
    const int rB = wc * 64 + (lane & 15);

    for (int t = 0; t < NT; ++t) {
        __syncthreads();
        if (t + 1 < NT) STAGE((t + 1) & 1, t + 1);
        const unsigned short* as = As[t & 1];
        const unsigned short* bs = Bs[t & 1];
        short8 a[4], b[4];
        #pragma unroll
        for (int m = 0; m < 4; ++m)
            a[m] = *(const short8*)&as[(rA + m * 16) * 32 + s * 8];
        #pragma unroll
        for (int n = 0; n < 4; ++n)
            b[n] = *(const short8*)&bs[(rB + n * 16) * 32 + s * 8];
        #pragma unroll
        for (int m = 0; m < 4; ++m)
            #pragma unroll
            for (int n = 0; n < 4; ++n)
                acc[m][n] = __builtin_amdgcn_mfma_f32_16x16x32_bf16(
                    a[m], b[n], acc[m][n], 0, 0, 0);
    }
    #undef STAGE

    const int cRow0 = rowBase + wr * 64 + (lane >> 4) * 4;
    const int cCol0 = colBase + wc * 64 + (lane & 15);
    #pragma unroll
    for (int n = 0; n < 4; ++n) {
        const int col = cCol0 + n * 16;
        const float* bp = (col < 1024) ? b0 : (col < 2048) ? b1 : b2;
        const float bv = bp[col & 1023];
        #pragma unroll
        for (int m = 0; m < 4; ++m)
            #pragma unroll
            for (int r = 0; r < 4; ++r) {
                const int row = cRow0 + m * 16 + r;
                const float v = fmaxf(acc[m][n][r] + bv, 0.0f);
                Cout[(size_t)row * N + col] = f2bf(v);
            }
    }
}

// ---------------------------------------------------------------------------
// bf16 MFMA GEMM, 64x128 tile, BK=32, 4 waves (2x2, wave-tile 32x64), 24KB LDS.
// Doubles block count for N=1024 shapes (512 blocks = 2/CU) to hide the
// barrier drain that 1 block/CU cannot. K-accum order identical to 128-tile.
// MODE 0: C = bf16(relu(A@Bt^T + bias))             (FFN1)
// MODE 1: S = relu(..)+resid; bf16 + channel stats  (FFN2)
// MODE 2: S = A@Bt^T; bf16 + channel stats          (embed)
// ---------------------------------------------------------------------------
template<int MODE>
__global__ __launch_bounds__(256)
void gemm64_bf16_kernel(const unsigned short* __restrict__ A,
                        const unsigned short* __restrict__ Bt,
                        const float* __restrict__ bias,
                        unsigned short* __restrict__ Cout,
                        const unsigned short* __restrict__ resid,
                        float* __restrict__ accp, int N, int Kd) {
    __shared__ unsigned short As[2][64 * 32];
    __shared__ unsigned short Bs[2][128 * 32];
    const int tid = threadIdx.x;
    const int lane = tid & 63;
    const int w = tid >> 6;
    const int wr = w >> 1, wc = w & 1;
    const int rowBase = blockIdx.y * 64;
    const int colBase = blockIdx.x * 128;

    // A: 256 chunks (64 rows x 4 k-chunks), one per thread
    const int ra = tid >> 2;
    const int ca = (tid & 3) ^ ((ra >> 1) & 3);
    const size_t aOff = (size_t)(rowBase + ra) * Kd + ca * 8;
    // B: 512 chunks, two per thread (same mapping as 128-tile kernel)
    const int chunk0 = w * 64 + lane;
    const int r0 = chunk0 >> 2;
    const int c0 = (chunk0 & 3) ^ ((r0 >> 1) & 3);
    const int chunk1 = 256 + chunk0;
    const int r1 = chunk1 >> 2;
    const int c1 = (chunk1 & 3) ^ ((r1 >> 1) & 3);
    const size_t bOff0 = (size_t)(colBase + r0) * Kd + c0 * 8;
    const size_t bOff1 = (size_t)(colBase + r1) * Kd + c1 * 8;
    const int ldsA = (w * 64) * 8;
    const int ldsB0 = (w * 64) * 8;
    const int ldsB1 = (256 + w * 64) * 8;

    f32x4 acc[2][4];
    #pragma unroll
    for (int m = 0; m < 2; ++m)
        #pragma unroll
        for (int n = 0; n < 4; ++n)
            acc[m][n] = (f32x4){0.f, 0.f, 0.f, 0.f};

    #define STAGE(buf, kt) do {                                                   \
        const int k0_ = (kt) << 5;                                                \
        __builtin_amdgcn_global_load_lds(                                         \
            (const __attribute__((address_space(1))) void*)(A + aOff + k0_),      \
            (__attribute__((address_space(3))) void*)(&As[buf][ldsA]), 16, 0, 0); \
        __builtin_amdgcn_global_load_lds(                                         \
            (const __attribute__((address_space(1))) void*)(Bt + bOff0 + k0_),    \
            (__attribute__((address_space(3))) void*)(&Bs[buf][ldsB0]), 16, 0, 0);\
        __builtin_amdgcn_global_load_lds(                                         \
            (const __attribute__((address_space(1))) void*)(Bt + bOff1 + k0_),    \
            (__attribute__((address_space(3))) void*)(&Bs[buf][ldsB1]), 16, 0, 0);\
    } while (0)

    const int NT = Kd >> 5;
    STAGE(0, 0);

    const int kb = lane >> 4;
    const int s = kb ^ ((lane >> 1) & 3);   // wr*32, wc*64 contribute 0 mod 4 after >>1
    const int rA = wr * 32 + (lane & 15);
    const int rB = wc * 64 + (lane & 15);

    for (int t = 0; t < NT; ++t) {
        __syncthreads();
        if (t + 1 < NT) STAGE((t + 1) & 1, t + 1);
        const unsigned short* as = As[t & 1];
        const unsigned short* bs = Bs[t & 1];
        short8 a[2], b[4];
        #pragma unroll
        for (int m = 0; m < 2; ++m)
            a[m] = *(const short8*)&as[(rA + m * 16) * 32 + s * 8];
        #pragma unroll
        for (int n = 0; n < 4; ++n)
            b[n] = *(const short8*)&bs[(rB + n * 16) * 32 + s * 8];
        #pragma unroll
        for (int m = 0; m < 2; ++m)
            #pragma unroll
            for (int n = 0; n < 4; ++n)
                acc[m][n] = __builtin_amdgcn_mfma_f32_16x16x32_bf16(
                    a[m], b[n], acc[m][n], 0, 0, 0);
    }
    #undef STAGE

    const int cRow0 = rowBase + wr * 32 + (lane >> 4) * 4;
    const int cCol0 = colBase + wc * 64 + (lane & 15);
    float cs[4] = {}, cq[4] = {};
    #pragma unroll
    for (int n = 0; n < 4; ++n) {
        const int col = cCol0 + n * 16;
        float bv = 0.0f;
        if (MODE != 2) bv = bias[col & 1023];
        #pragma unroll
        for (int m = 0; m < 2; ++m)
            #pragma unroll
            for (int r = 0; r < 4; ++r) {
                const int row = cRow0 + m * 16 + r;
                float v = acc[m][n][r];
                if (MODE != 2) v = fmaxf(v + bv, 0.0f);
                if (MODE == 1) v += bf2f(resid[(size_t)row * N + col]);
                if (MODE != 0) { cs[n] += v; cq[n] += v * v; }
                Cout[(size_t)row * N + col] = f2bf(v);
            }
    }
    if (MODE != 0) {
        #pragma unroll
        for (int n = 0; n < 4; ++n) {
            cs[n] += __shfl_xor(cs[n], 16); cs[n] += __shfl_xor(cs[n], 32);
            cq[n] += __shfl_xor(cq[n], 16); cq[n] += __shfl_xor(cq[n], 32);
        }
        if (lane < 16) {
            #pragma unroll
            for (int n = 0; n < 4; ++n) {
                const int col = colBase + wc * 64 + lane + n * 16;
                atomicAdd(&accp[col], cs[n]);
                atomicAdd(&accp[D_MODEL + col], cq[n]);
            }
        }
    }
}

// ---------------------------------------------------------------------------
// prep (single launch): z<8 -> weight transpose+cvt (2 layers x {Wq,Wk,Wv,Wc1});
// z==8 -> x cvt (b<128), W_embed^T (b in 128..143), zero accum (b==144)
// ---------------------------------------------------------------------------
__global__ __launch_bounds__(256)
void prep_kernel(const float* __restrict__ Wq, const float* __restrict__ Wk,
                 const float* __restrict__ Wv, const float* __restrict__ Wc1,
                 const float* __restrict__ x, const float* __restrict__ Wemb,
                 unsigned short* __restrict__ Wtqkv, unsigned short* __restrict__ Wtc1,
                 unsigned short* __restrict__ xbf, unsigned short* __restrict__ Wembt,
                 float* __restrict__ accum) {
    const int z = blockIdx.z;
    const int tid = threadIdx.x;
    if (z < 8) {
        const int layer = z >> 2, typ = z & 3;
        const size_t wo = (size_t)layer * 1048576;
        const float* src;
        unsigned short* dst;
        if (typ == 0)      { src = Wq + wo;  dst = Wtqkv + layer * 3145728; }
        else if (typ == 1) { src = Wk + wo;  dst = Wtqkv + layer * 3145728 + 1048576; }
        else if (typ == 2) { src = Wv + wo;  dst = Wtqkv + layer * 3145728 + 2097152; }
        else               { src = Wc1 + wo; dst = Wtc1 + layer * 1048576; }
        __shared__ float T[64][65];
        const int kBase = blockIdx.y * 64;
        const int nBase = blockIdx.x * 64;
        const int rr = tid >> 4;
        const int c4 = (tid & 15) * 4;
        #pragma unroll
        for (int i = 0; i < 4; ++i) {
            const int k = i * 16 + rr;
            const float4 v = *reinterpret_cast<const float4*>(
                &src[(size_t)(kBase + k) * 1024 + nBase + c4]);
            T[k][c4] = v.x; T[k][c4 + 1] = v.y; T[k][c4 + 2] = v.z; T[k][c4 + 3] = v.w;
        }
        __syncthreads();
        #pragma unroll
        for (int i = 0; i < 4; ++i) {
            const int n = i * 16 + rr;
            ushort4 o;
            o.x = f2bf(T[c4 + 0][n]); o.y = f2bf(T[c4 + 1][n]);
            o.z = f2bf(T[c4 + 2][n]); o.w = f2bf(T[c4 + 3][n]);
            *reinterpret_cast<ushort4*>(&dst[(size_t)(nBase + n) * 1024 + kBase + c4]) = o;
        }
        return;
    }
    const int b = blockIdx.y * 16 + blockIdx.x;
    if (b < 128) {
        const size_t base = (size_t)b * 2048 + tid * 8;
        const float4 v0 = *reinterpret_cast<const float4*>(&x[base]);
        const float4 v1 = *reinterpret_cast<const float4*>(&x[base + 4]);
        ushortx8 o;
        o[0] = f2bf(v0.x); o[1] = f2bf(v0.y); o[2] = f2bf(v0.z); o[3] = f2bf(v0.w);
        o[4] = f2bf(v1.x); o[5] = f2bf(v1.y); o[6] = f2bf(v1.z); o[7] = f2bf(v1.w);
        *reinterpret_cast<ushortx8*>(&xbf[base]) = o;
    } else if (b < 144) {
        __shared__ float T[64][65];
        const int nBase = (b - 128) * 64;
        const int rr = tid >> 4;
        const int c4 = (tid & 15) * 4;
        #pragma unroll
        for (int i = 0; i < 4; ++i) {
            const int k = i * 16 + rr;
            const float4 v = *reinterpret_cast<const float4*>(
                &Wemb[(size_t)k * 1024 + nBase + c4]);
            T[k][c4] = v.x; T[k][c4 + 1] = v.y; T[k][c4 + 2] = v.z; T[k][c4 + 3] = v.w;
        }
        __syncthreads();
        #pragma unroll
        for (int i = 0; i < 4; ++i) {
            const int n = i * 16 + rr;
            ushort4 o;
            o.x = f2bf(T[c4 + 0][n]); o.y = f2bf(T[c4 + 1][n]);
            o.z = f2bf(T[c4 + 2][n]); o.w = f2bf(T[c4 + 3][n]);
            *reinterpret_cast<ushort4*>(&Wembt[(size_t)(nBase + n) * 64 + c4]) = o;
        }
    } else if (b == 144) {
        for (int j = tid; j < 5 * 2048; j += 256) accum[j] = 0.0f;
    }
}

// ---------------------------------------------------------------------------
// MFMA flash attention + fused residual + BN stats. (unchanged, proven)
// ---------------------------------------------------------------------------
__global__ __launch_bounds__(256)
void attn_kernel(const unsigned short* __restrict__ QKV,
                 const unsigned short* __restrict__ Ebf,
                 unsigned short* __restrict__ Sbf,
                 float* __restrict__ accp) {
    __shared__ unsigned short Qs[128 * 64];
    __shared__ unsigned short Ks[2][64 * 64];
    __shared__ unsigned short Vt[2][64 * 72];

    const int tid = threadIdx.x;
    const int lane = tid & 63;
    const int w = tid >> 6;
    const int m = lane & 15;
    const int g = lane >> 4;
    const int l7 = lane & 7;
    const int qt = blockIdx.x, hh = blockIdx.y, bb = blockIdx.z;
    const int colB = hh * 64;
    const size_t rowQ = (size_t)bb * 512 + qt * 128;
    const size_t rowKV = (size_t)bb * 512;

    const int vk0 = (tid & 31) * 2;
    const int vcv = tid >> 5;

    #define STAGE_K(buf, kt) do {                                                  \
        const size_t kb_ = rowKV + (size_t)(kt) * 64;                              \
        _Pragma("unroll")                                                          \
        for (int i_ = 0; i_ < 2; ++i_) {                                           \
            const int c_ = w * 128 + i_ * 64 + lane;                               \
            const int r_ = c_ >> 3;                                                \
            const int gc_ = (c_ & 7) ^ (r_ & 7);                                   \
            __builtin_amdgcn_global_load_lds(                                      \
                (const __attribute__((address_space(1))) void*)                    \
                    (QKV + (kb_ + r_) * 3072 + 1024 + colB + gc_ * 8),             \
                (__attribute__((address_space(3))) void*)                          \
                    (&Ks[buf][(w * 128 + i_ * 64) * 8]), 16, 0, 0);                \
        }                                                                          \
    } while (0)

    #define LOAD_V(kt) do {                                                        \
        const size_t kb_ = rowKV + (size_t)(kt) * 64;                              \
        vst0 = *(const ushortx8*)(QKV + (kb_ + vk0) * 3072 + 2048 + colB + vcv * 8);\
        vst1 = *(const ushortx8*)(QKV + (kb_ + vk0 + 1) * 3072 + 2048 + colB + vcv * 8);\
    } while (0)

    #define WRITE_V(buf) do {                                                      \
        _Pragma("unroll")                                                          \
        for (int j_ = 0; j_ < 8; ++j_) {                                           \
            const int d_ = vcv * 8 + j_;                                           \
            unsigned int pk_ = (unsigned int)(unsigned short)vst0[j_] |            \
                               ((unsigned int)(unsigned short)vst1[j_] << 16);     \
            *(unsigned int*)&Vt[buf][d_ * 72 + vk0] = pk_;                         \
        }                                                                          \
    } while (0)

    ushortx8 vst0, vst1;

    #pragma unroll
    for (int i = 0; i < 4; ++i) {
        const int c = w * 256 + i * 64 + lane;
        const int r = c >> 3;
        const int gc = (c & 7) ^ (r & 7);
        __builtin_amdgcn_global_load_lds(
            (const __attribute__((address_space(1))) void*)
                (QKV + (rowQ + r) * 3072 + colB + gc * 8),
            (__attribute__((address_space(3))) void*)
                (&Qs[(w * 256 + i * 64) * 8]), 16, 0, 0);
    }
    STAGE_K(0, 0);
    LOAD_V(0);
    WRITE_V(0);
    __syncthreads();

    short8 qb[2][2];
    #pragma unroll
    for (int nf = 0; nf < 2; ++nf)
        #pragma unroll
        for (int ks = 0; ks < 2; ++ks)
            qb[nf][ks] = *(const short8*)&Qs[(w * 32 + 16 * nf + m) * 64 +
                                             ((g + 4 * ks) ^ l7) * 8];

    f32x4 o[2][4];
    #pragma unroll
    for (int nf = 0; nf < 2; ++nf)
        #pragma unroll
        for (int dn = 0; dn < 4; ++dn)
            o[nf][dn] = (f32x4){0.f, 0.f, 0.f, 0.f};
    float mr[2] = {-1e30f, -1e30f};
    float lsm[2] = {0.f, 0.f};

    for (int kt = 0; kt < 8; ++kt) {
        const int cur = kt & 1, nxt = cur ^ 1;
        if (kt < 7) { STAGE_K(nxt, kt + 1); LOAD_V(kt + 1); }

        f32x4 st[4][2];
        #pragma unroll
        for (int mf = 0; mf < 4; ++mf)
            #pragma unroll
            for (int nf = 0; nf < 2; ++nf)
                st[mf][nf] = (f32x4){0.f, 0.f, 0.f, 0.f};
        #pragma unroll
        for (int ks = 0; ks < 2; ++ks) {
            short8 a[4];
            #pragma unroll
            for (int mf = 0; mf < 4; ++mf)
                a[mf] = *(const short8*)&Ks[cur][(m + 16 * mf) * 64 +
                                                 ((g + 4 * ks) ^ l7) * 8];
            __builtin_amdgcn_s_setprio(1);
            #pragma unroll
            for (int mf = 0; mf < 4; ++mf)
                #pragma unroll
                for (int nf = 0; nf < 2; ++nf)
                    st[mf][nf] = __builtin_amdgcn_mfma_f32_16x16x32_bf16(
                        a[mf], qb[nf][ks], st[mf][nf], 0, 0, 0);
            __builtin_amdgcn_s_setprio(0);
        }

        float pmax[2];
        #pragma unroll
        for (int nf = 0; nf < 2; ++nf) {
            float a0 = fmaxf(fmaxf(st[0][nf][0], st[0][nf][1]),
                             fmaxf(st[0][nf][2], st[0][nf][3]));
            float a1 = fmaxf(fmaxf(st[1][nf][0], st[1][nf][1]),
                             fmaxf(st[1][nf][2], st[1][nf][3]));
            float a2 = fmaxf(fmaxf(st[2][nf][0], st[2][nf][1]),
                             fmaxf(st[2][nf][2], st[2][nf][3]));
            float a3 = fmaxf(fmaxf(st[3][nf][0], st[3][nf][1]),
                             fmaxf(st[3][nf][2], st[3][nf][3]));
            float mx = fmaxf(fmaxf(a0, a1), fmaxf(a2, a3));
            mx = fmaxf(mx, __shfl_xor(mx, 16));
            mx = fmaxf(mx, __shfl_xor(mx, 32));
            pmax[nf] = mx;
        }
        const int need = (pmax[0] - mr[0] > 64.f) || (pmax[1] - mr[1] > 64.f);
        if (__any(need)) {
            float al[2];
            #pragma unroll
            for (int nf = 0; nf < 2; ++nf) {
                const float mn = fmaxf(mr[nf], pmax[nf]);
                al[nf] = exp2f((mr[nf] - mn) * C_EXP2);
                lsm[nf] *= al[nf];
                mr[nf] = mn;
            }
            #pragma unroll
            for (int nf = 0; nf < 2; ++nf)
                #pragma unroll
                for (int r = 0; r < 4; ++r) {
                    const float av = __shfl(al[nf], 4 * g + r);
                    #pragma unroll
                    for (int dn = 0; dn < 4; ++dn)
                        o[nf][dn][r] *= av;
                }
        }

        float pf[2][4][4];
        #pragma unroll
        for (int nf = 0; nf < 2; ++nf) {
            const float mc = mr[nf] * C_EXP2;
            float s0 = 0.f, s1 = 0.f, s2 = 0.f, s3 = 0.f;
            #pragma unroll
            for (int mf = 0; mf < 4; ++mf) {
                float p0 = exp2f(fmaf(st[mf][nf][0], C_EXP2, -mc));
                float p1 = exp2f(fmaf(st[mf][nf][1], C_EXP2, -mc));
                float p2 = exp2f(fmaf(st[mf][nf][2], C_EXP2, -mc));
                float p3 = exp2f(fmaf(st[mf][nf][3], C_EXP2, -mc));
                pf[nf][mf][0] = p0; pf[nf][mf][1] = p1;
                pf[nf][mf][2] = p2; pf[nf][mf][3] = p3;
                s0 += p0; s1 += p1; s2 += p2; s3 += p3;
            }
            float ls = (s0 + s1) + (s2 + s3);
            ls += __shfl_xor(ls, 16);
            ls += __shfl_xor(ls, 32);
            lsm[nf] += ls;
        }

        if (kt < 7) WRITE_V(nxt);

        short8 pb[2][2];
        #pragma unroll
        for (int nf = 0; nf < 2; ++nf)
            #pragma unroll
            for (int ks = 0; ks < 2; ++ks) {
                union { unsigned int u[4]; short8 s; } cv;
                cv.u[0] = cvt_pk_bf16(pf[nf][2 * ks][0], pf[nf][2 * ks][1]);
                cv.u[1] = cvt_pk_bf16(pf[nf][2 * ks][2], pf[nf][2 * ks][3]);
                cv.u[2] = cvt_pk_bf16(pf[nf][2 * ks + 1][0], pf[nf][2 * ks + 1][1]);
                cv.u[3] = cvt_pk_bf16(pf[nf][2 * ks + 1][2], pf[nf][2 * ks + 1][3]);
                pb[nf][ks] = cv.s;
            }

        #pragma unroll
        for (int ks = 0; ks < 2; ++ks) {
            short8 vb[4];
            #pragma unroll
            for (int dn = 0; dn < 4; ++dn) {
                const int d = m + 16 * dn;
                const short4v lo = *(const short4v*)&Vt[cur][d * 72 + 4 * g + 32 * ks];
                const short4v hi = *(const short4v*)&Vt[cur][d * 72 + 4 * g + 16 + 32 * ks];
                vb[dn] = __builtin_shufflevector(lo, hi, 0, 1, 2, 3, 4, 5, 6, 7);
            }
            __builtin_amdgcn_s_setprio(1);
            #pragma unroll
            for (int nf = 0; nf < 2; ++nf)
                #pragma unroll
                for (int dn = 0; dn < 4; ++dn)
                    o[nf][dn] = __builtin_amdgcn_mfma_f32_16x16x32_bf16(
                        pb[nf][ks], vb[dn], o[nf][dn], 0, 0, 0);
            __builtin_amdgcn_s_setprio(0);
        }
        __syncthreads();
    }

    float cs[4] = {}, cq[4] = {};
    #pragma unroll
    for (int nf = 0; nf < 2; ++nf) {
        const float inv = 1.0f / lsm[nf];
        #pragma unroll
        for (int r = 0; r < 4; ++r) {
            const float sc = __shfl(inv, 4 * g + r);
            const size_t row = rowQ + w * 32 + 16 * nf + 4 * g + r;
            #pragma unroll
            for (int dn = 0; dn < 4; ++dn) {
                const int ch = colB + 16 * dn + m;
                const float sv = o[nf][dn][r] * sc + bf2f(Ebf[row * D_MODEL + ch]);
                Sbf[row * D_MODEL + ch] = f2bf(sv);
                cs[dn] += sv; cq[dn] += sv * sv;
            }
        }
    }
    #pragma unroll
    for (int dn = 0; dn < 4; ++dn) {
        cs[dn] += __shfl_xor(cs[dn], 16); cs[dn] += __shfl_xor(cs[dn], 32);
        cq[dn] += __shfl_xor(cq[dn], 16); cq[dn] += __shfl_xor(cq[dn], 32);
    }
    if (lane < 16) {
        #pragma unroll
        for (int dn = 0; dn < 4; ++dn) {
            atomicAdd(&accp[colB + 16 * dn + lane], cs[dn]);
            atomicAdd(&accp[D_MODEL + colB + 16 * dn + lane], cq[dn]);
        }
    }
    #undef STAGE_K
    #undef LOAD_V
    #undef WRITE_V
}

// ---------------------------------------------------------------------------
// BN apply with inlined stats->coef (unchanged, proven)
// ---------------------------------------------------------------------------
template<bool FINAL>
__global__ __launch_bounds__(256)
void bn_apply_kernel(const unsigned short* __restrict__ S,
                     const float* __restrict__ accum,
                     const float* __restrict__ gamma,
                     const float* __restrict__ beta,
                     unsigned short* __restrict__ Ebf,
                     float* __restrict__ outF) {
    const int idx = blockIdx.x * 256 + threadIdx.x;
    const int c8 = (idx & 127) << 3;
    const ushortx8 sv = *(const ushortx8*)&S[(size_t)idx * 8];
    const float4 s0 = *(const float4*)&accum[c8];
    const float4 s1 = *(const float4*)&accum[c8 + 4];
    const float4 q0 = *(const float4*)&accum[D_MODEL + c8];
    const float4 q1 = *(const float4*)&accum[D_MODEL + c8 + 4];
    const float4 g0 = *(const float4*)&gamma[c8];
    const float4 g1 = *(const float4*)&gamma[c8 + 4];
    const float4 t0 = *(const float4*)&beta[c8];
    const float4 t1 = *(const float4*)&beta[c8 + 4];
    const float ss[8] = {s0.x, s0.y, s0.z, s0.w, s1.x, s1.y, s1.z, s1.w};
    const float qq[8] = {q0.x, q0.y, q0.z, q0.w, q1.x, q1.y, q1.z, q1.w};
    const float gg[8] = {g0.x, g0.y, g0.z, g0.w, g1.x, g1.y, g1.z, g1.w};
    const float tt[8] = {t0.x, t0.y, t0.z, t0.w, t1.x, t1.y, t1.z, t1.w};
    float o[8];
    #pragma unroll
    for (int j = 0; j < 8; ++j) {
        const float mean = ss[j] * INV_N;
        const float var = qq[j] * INV_N - mean * mean;
        const float a = gg[j] * rsqrtf(var + BN_EPS);
        o[j] = fmaf(bf2f(sv[j]), a, tt[j] - mean * a);
    }
    if (FINAL) {
        *reinterpret_cast<float4*>(&outF[(size_t)idx * 8]) =
            make_float4(o[0], o[1], o[2], o[3]);
        *reinterpret_cast<float4*>(&outF[(size_t)idx * 8 + 4]) =
            make_float4(o[4], o[5], o[6], o[7]);
    } else {
        union { unsigned int u[4]; ushortx8 s; } cv;
        cv.u[0] = cvt_pk_bf16(o[0], o[1]);
        cv.u[1] = cvt_pk_bf16(o[2], o[3]);
        cv.u[2] = cvt_pk_bf16(o[4], o[5]);
        cv.u[3] = cvt_pk_bf16(o[6], o[7]);
        *reinterpret_cast<ushortx8*>(&Ebf[(size_t)idx * 8]) = cv.s;
    }
}

// ---------------------------------------------------------------------------
extern "C" void kernel_launch(void* const* d_in, const int* in_sizes, int n_in,
                              void* d_out, int out_size, void* d_ws, size_t ws_size,
                              hipStream_t stream) {
    const float* x       = (const float*)d_in[0];
    const float* W_embed = (const float*)d_in[1];
    const float* bn1_g   = (const float*)d_in[2];
    const float* bn1_b   = (const float*)d_in[3];
    const float* Wq      = (const float*)d_in[4];
    const float* bq      = (const float*)d_in[5];
    const float* Wk      = (const float*)d_in[6];
    const float* bk      = (const float*)d_in[7];
    const float* Wv      = (const float*)d_in[8];
    const float* bv      = (const float*)d_in[9];
    const float* bng     = (const float*)d_in[10];
    const float* bnb     = (const float*)d_in[11];
    const float* Wc1     = (const float*)d_in[12];
    const float* bc1     = (const float*)d_in[13];
    const float* bn2g    = (const float*)d_in[14];
    const float* bn2b    = (const float*)d_in[15];

    const size_t NBUF = (size_t)M_ROWS * D_MODEL;
    char* ws = (char*)d_ws;
    float* accum = (float*)ws;                                   // 5*2048 f
    unsigned short* xbf   = (unsigned short*)(accum + 5 * 2048); // 262144 us
    unsigned short* Wembt = xbf + 262144;                        // 65536 us
    unsigned short* Ebf   = Wembt + 65536;                       // 4M us
    unsigned short* Sbf   = Ebf + NBUF;                          // 4M us
    unsigned short* QKVbf = Sbf + NBUF;                          // 12M us
    unsigned short* F1bf  = QKVbf;                               // alias (QKV dead)
    unsigned short* Wtqkv = QKVbf + (size_t)M_ROWS * 3072;       // 2 x 3M us
    unsigned short* Wtc1  = Wtqkv + 2 * (size_t)3145728;         // 2 x 1M us
    float* outF = (float*)d_out;

    prep_kernel<<<dim3(16, 16, 9), 256, 0, stream>>>(
        Wq, Wk, Wv, Wc1, x, W_embed, Wtqkv, Wtc1, xbf, Wembt, accum);

    // embed (bf16 MFMA, K=64, 64x128 tile -> 512 blocks) + BN1
    gemm64_bf16_kernel<2><<<dim3(8, 64), 256, 0, stream>>>(
        xbf, Wembt, nullptr, Sbf, nullptr, accum, 1024, 64);
    bn_apply_kernel<false><<<2048, 256, 0, stream>>>(Sbf, accum, bn1_g, bn1_b,
                                                     Ebf, nullptr);

    for (int i = 0; i < 2; ++i) {
        const size_t bo = (size_t)i * D_MODEL;
        float* accA = accum + (1 + 2 * i) * 2048;
        float* accF = accum + (2 + 2 * i) * 2048;
        const unsigned short* WtqkvL = Wtqkv + (size_t)i * 3145728;
        const unsigned short* Wtc1L  = Wtc1 + (size_t)i * 1048576;

        gemm_bf16_kernel<0><<<dim3(24, 32), 256, 0, stream>>>(
            Ebf, WtqkvL, bq + bo, bk + bo, bv + bo, QKVbf, nullptr, nullptr,
            3072, 1024);
        attn_kernel<<<dim3(4, 16, 8), 256, 0, stream>>>(QKVbf, Ebf, Sbf, accA);
        bn_apply_kernel<false><<<2048, 256, 0, stream>>>(Sbf, accA, bng + bo,
                                                         bnb + bo, Ebf, nullptr);

        // FFN (64x128 tiles -> 512 blocks = 2/CU)
        gemm64_bf16_kernel<0><<<dim3(8, 64), 256, 0, stream>>>(
            Ebf, Wtc1L, bc1 + bo, F1bf, nullptr, nullptr, 1024, 1024);
        gemm64_bf16_kernel<1><<<dim3(8, 64), 256, 0, stream>>>(
            F1bf, Wtc1L, bc1 + bo, Sbf, Ebf, accF, 1024, 1024);
        if (i == 0)
            bn_apply_kernel<false><<<2048, 256, 0, stream>>>(Sbf, accF, bn2g + bo,
                                                             bn2b + bo, Ebf, nullptr);
        else
            bn_apply_kernel<true><<<2048, 256, 0, stream>>>(Sbf, accF, bn2g + bo,
                                                            bn2b + bo, nullptr, outF);
    }
}